// Round 1
// baseline (13297.345 us; speedup 1.0000x reference)
//
#include <hip/hip_runtime.h>

#define BB 32
#define LL 512
#define HH 1024
#define PRED 32
#define LN_EPS 1e-5f

// ---------------------------------------------------------------------------
// Transpose Whh[k][j] -> WT[j][k]  (H x H)
// ---------------------------------------------------------------------------
__global__ __launch_bounds__(256) void transpose_k(const float* __restrict__ in,
                                                   float* __restrict__ out) {
    __shared__ float tile[32][33];
    int bx = blockIdx.x * 32, by = blockIdx.y * 32;
    int tx = threadIdx.x, ty = threadIdx.y;
    #pragma unroll
    for (int i = 0; i < 32; i += 8)
        tile[ty + i][tx] = in[(size_t)(by + ty + i) * HH + bx + tx];
    __syncthreads();
    #pragma unroll
    for (int i = 0; i < 32; i += 8)
        out[(size_t)(bx + ty + i) * HH + by + tx] = tile[tx][ty + i];
}

// ---------------------------------------------------------------------------
// C[m][n] = sum_k A[m][k] * Bt[n][k]   (A: [M,K] row-major, Bt: [N,K] row-major)
// M = B*L = 16384, N = H = 1024, K = H = 1024
// 64x64 tile, BK=16, 256 threads, 4x4 microtile. fp32.
// ---------------------------------------------------------------------------
__global__ __launch_bounds__(256) void gemm_xw(const float* __restrict__ A,
                                               const float* __restrict__ Bt,
                                               float* __restrict__ C) {
    const int K = HH, N = HH;
    __shared__ float As[16][64];
    __shared__ float Bs[16][64];
    int tid = threadIdx.x;
    int m0 = blockIdx.y * 64, n0 = blockIdx.x * 64;
    int tn = (tid & 15) * 4;
    int tm = (tid >> 4) * 4;
    int lr = tid >> 2;         // 0..63 : row within tile
    int lk = (tid & 3) * 4;    // 0,4,8,12 : k within K-slice
    float acc[4][4] = {};
    const float* Ap = A + (size_t)(m0 + lr) * K + lk;
    const float* Bp = Bt + (size_t)(n0 + lr) * K + lk;
    for (int kt = 0; kt < K; kt += 16) {
        float4 av = *(const float4*)(Ap + kt);
        float4 bv = *(const float4*)(Bp + kt);
        As[lk + 0][lr] = av.x; As[lk + 1][lr] = av.y;
        As[lk + 2][lr] = av.z; As[lk + 3][lr] = av.w;
        Bs[lk + 0][lr] = bv.x; Bs[lk + 1][lr] = bv.y;
        Bs[lk + 2][lr] = bv.z; Bs[lk + 3][lr] = bv.w;
        __syncthreads();
        #pragma unroll
        for (int k = 0; k < 16; ++k) {
            float4 a = *(const float4*)&As[k][tm];
            float4 b = *(const float4*)&Bs[k][tn];
            float ar[4] = {a.x, a.y, a.z, a.w};
            float br[4] = {b.x, b.y, b.z, b.w};
            #pragma unroll
            for (int i = 0; i < 4; ++i)
                #pragma unroll
                for (int j = 0; j < 4; ++j)
                    acc[i][j] = fmaf(ar[i], br[j], acc[i][j]);
        }
        __syncthreads();
    }
    #pragma unroll
    for (int i = 0; i < 4; ++i) {
        float4 o = {acc[i][0], acc[i][1], acc[i][2], acc[i][3]};
        *(float4*)&C[(size_t)(m0 + tm + i) * N + n0 + tn] = o;
    }
}

// ---------------------------------------------------------------------------
// One recurrence step: hout[b][k] (+)= sum_j hin[b][j] * WT[j][k]
// hin/hout point at the t-slice start; b-rows are in_bs/out_bs floats apart.
// grid: x = 32 k-chunks of 32, y = 4 b-chunks of 8. block = 256.
// ---------------------------------------------------------------------------
__global__ __launch_bounds__(256) void rnn_step(const float* __restrict__ hin,
                                                float* __restrict__ hout,
                                                const float* __restrict__ WT,
                                                long in_bs, long out_bs,
                                                int add_existing) {
    __shared__ float hs[8][64];
    int tk = threadIdx.x & 31;
    int tb = threadIdx.x >> 5;
    int k = blockIdx.x * 32 + tk;
    int b = blockIdx.y * 8 + tb;
    float acc = 0.f;
    const float* hrow = hin + (size_t)b * in_bs;
    for (int jt = 0; jt < HH; jt += 64) {
        float2 hv = *(const float2*)(hrow + jt + 2 * tk);
        *(float2*)&hs[tb][2 * tk] = hv;
        __syncthreads();
        #pragma unroll 16
        for (int j = 0; j < 64; ++j)
            acc = fmaf(hs[tb][j], WT[(size_t)(jt + j) * HH + k], acc);
        __syncthreads();
    }
    float* op = hout + (size_t)b * out_bs + k;
    if (add_existing) *op = *op + acc;
    else              *op = acc;
}

// ---------------------------------------------------------------------------
// LayerNorm in place over last dim H for B*PRED rows. block=256, 4 elems/thread
// ---------------------------------------------------------------------------
__global__ __launch_bounds__(256) void ln_k(float* __restrict__ y,
                                            const float* __restrict__ w,
                                            const float* __restrict__ bia) {
    __shared__ float red[8];
    int row = blockIdx.x;
    float* p = y + (size_t)row * HH;
    int i4 = threadIdx.x * 4;
    float4 v = *(const float4*)&p[i4];
    float s = v.x + v.y + v.z + v.w;
    #pragma unroll
    for (int o = 32; o > 0; o >>= 1) s += __shfl_down(s, o, 64);
    int wid = threadIdx.x >> 6;
    if ((threadIdx.x & 63) == 0) red[wid] = s;
    __syncthreads();
    if (threadIdx.x == 0) red[4] = (red[0] + red[1] + red[2] + red[3]) * (1.f / HH);
    __syncthreads();
    float mu = red[4];
    float dx = v.x - mu, dy = v.y - mu, dz = v.z - mu, dw = v.w - mu;
    float q = dx * dx + dy * dy + dz * dz + dw * dw;
    #pragma unroll
    for (int o = 32; o > 0; o >>= 1) q += __shfl_down(q, o, 64);
    if ((threadIdx.x & 63) == 0) red[wid] = q;
    __syncthreads();
    if (threadIdx.x == 0) red[5] = (red[0] + red[1] + red[2] + red[3]) * (1.f / HH);
    __syncthreads();
    float rs = rsqrtf(red[5] + LN_EPS);
    float4 o4;
    o4.x = dx * rs * w[i4 + 0] + bia[i4 + 0];
    o4.y = dy * rs * w[i4 + 1] + bia[i4 + 1];
    o4.z = dz * rs * w[i4 + 2] + bia[i4 + 2];
    o4.w = dw * rs * w[i4 + 3] + bia[i4 + 3];
    *(float4*)&p[i4] = o4;
}

// ---------------------------------------------------------------------------
extern "C" void kernel_launch(void* const* d_in, const int* in_sizes, int n_in,
                              void* d_out, int out_size, void* d_ws, size_t ws_size,
                              hipStream_t stream) {
    const float* x    = (const float*)d_in[0];  // [B,L,H]
    const float* Wxh  = (const float*)d_in[1];  // [H,H]
    const float* Whh  = (const float*)d_in[2];  // [H,H]
    const float* ln_w = (const float*)d_in[3];  // [H]
    const float* ln_b = (const float*)d_in[4];  // [H]

    float* rec  = (float*)d_out;                       // [B,L,H]
    float* outp = rec + (size_t)BB * LL * HH;          // [B,PRED,H]
    float* WT   = (float*)d_ws;                        // [H,H] transposed Whh

    // WT[j][k] = Whh[k][j]
    transpose_k<<<dim3(HH / 32, HH / 32), dim3(32, 8), 0, stream>>>(Whh, WT);

    // rec[b][l][k] = sum_h x[b][l][h] * Wxh[k][h]
    gemm_xw<<<dim3(HH / 64, BB * LL / 64), 256, 0, stream>>>(x, Wxh, rec);

    // recurrence: rec[:,t,:] = rec[:,t,:](=xw_t) + rec[:,t-1,:] @ WT
    for (int t = 1; t < LL; ++t)
        rnn_step<<<dim3(32, 4), 256, 0, stream>>>(
            rec + (size_t)(t - 1) * HH, rec + (size_t)t * HH, WT,
            (long)LL * HH, (long)LL * HH, 1);

    // prediction: outs[:,0,:] = h_last @ WT ; outs[:,t,:] = outs[:,t-1,:] @ WT
    rnn_step<<<dim3(32, 4), 256, 0, stream>>>(
        rec + (size_t)(LL - 1) * HH, outp, WT,
        (long)LL * HH, (long)PRED * HH, 0);
    for (int t = 1; t < PRED; ++t)
        rnn_step<<<dim3(32, 4), 256, 0, stream>>>(
            outp + (size_t)(t - 1) * HH, outp + (size_t)t * HH, WT,
            (long)PRED * HH, (long)PRED * HH, 0);

    // LayerNorm the prediction rows in place
    ln_k<<<BB * PRED, 256, 0, stream>>>(outp, ln_w, ln_b);
}

// Round 2
// 5414.537 us; speedup vs baseline: 2.4559x; 2.4559x over previous
//
#include <hip/hip_runtime.h>

#define BB 32
#define LL 512
#define HH 1024
#define PRED 32
#define CC 32            // chunk length
#define NC (LL / CC)     // 16 chunks
#define LN_EPS 1e-5f

// ---------------------------------------------------------------------------
// Transpose Whh[k][j] -> WT[j][k]  (H x H).  WT = M where h_t = u_t + h_{t-1}M
// ---------------------------------------------------------------------------
__global__ __launch_bounds__(256) void transpose_k(const float* __restrict__ in,
                                                   float* __restrict__ out) {
    __shared__ float tile[32][33];
    int bx = blockIdx.x * 32, by = blockIdx.y * 32;
    int tx = threadIdx.x, ty = threadIdx.y;
    #pragma unroll
    for (int i = 0; i < 32; i += 8)
        tile[ty + i][tx] = in[(size_t)(by + ty + i) * HH + bx + tx];
    __syncthreads();
    #pragma unroll
    for (int i = 0; i < 32; i += 8)
        out[(size_t)(bx + ty + i) * HH + by + tx] = tile[tx][ty + i];
}

// ---------------------------------------------------------------------------
// C[m][n] = sum_k A[m][k] * Bt[n][k]   (A: [M,K], Bt: [N,K] row-major)
// Used for xw = x @ Wxh^T.  64x64 tile, BK=16, 256 thr, 4x4 microtile.
// ---------------------------------------------------------------------------
__global__ __launch_bounds__(256) void gemm_xw(const float* __restrict__ A,
                                               const float* __restrict__ Bt,
                                               float* __restrict__ C) {
    const int K = HH, N = HH;
    __shared__ float As[16][64];
    __shared__ float Bs[16][64];
    int tid = threadIdx.x;
    int m0 = blockIdx.y * 64, n0 = blockIdx.x * 64;
    int tn = (tid & 15) * 4;
    int tm = (tid >> 4) * 4;
    int lr = tid >> 2;
    int lk = (tid & 3) * 4;
    float acc[4][4] = {};
    const float* Ap = A + (size_t)(m0 + lr) * K + lk;
    const float* Bp = Bt + (size_t)(n0 + lr) * K + lk;
    for (int kt = 0; kt < K; kt += 16) {
        float4 av = *(const float4*)(Ap + kt);
        float4 bv = *(const float4*)(Bp + kt);
        As[lk + 0][lr] = av.x; As[lk + 1][lr] = av.y;
        As[lk + 2][lr] = av.z; As[lk + 3][lr] = av.w;
        Bs[lk + 0][lr] = bv.x; Bs[lk + 1][lr] = bv.y;
        Bs[lk + 2][lr] = bv.z; Bs[lk + 3][lr] = bv.w;
        __syncthreads();
        #pragma unroll
        for (int k = 0; k < 16; ++k) {
            float4 a = *(const float4*)&As[k][tm];
            float4 b = *(const float4*)&Bs[k][tn];
            float ar[4] = {a.x, a.y, a.z, a.w};
            float br[4] = {b.x, b.y, b.z, b.w};
            #pragma unroll
            for (int i = 0; i < 4; ++i)
                #pragma unroll
                for (int j = 0; j < 4; ++j)
                    acc[i][j] = fmaf(ar[i], br[j], acc[i][j]);
        }
        __syncthreads();
    }
    #pragma unroll
    for (int i = 0; i < 4; ++i) {
        float4 o = {acc[i][0], acc[i][1], acc[i][2], acc[i][3]};
        *(float4*)&C[(size_t)(m0 + tm + i) * N + n0 + tn] = o;
    }
}

// ---------------------------------------------------------------------------
// Generic strided-row GEMM:  acc(r,n) = sum_k Arow(r)[k] * Bm[k][n]
//   row r -> A + (r&31)*sAb + (r>>5)*sAc          (b inner, chunk outer)
//   O1(r,n) = acc (+ O1 if add1);  optional O2(r,n) += acc.
// RT = row-tile (32 or 64), N-tile 64, BK=16, 256 threads.
// All row/col counts divide tiles exactly (no guards needed).
// ---------------------------------------------------------------------------
template<int RT>
__global__ __launch_bounds__(256) void rnn_gemm(
    const float* __restrict__ A, long sAb, long sAc,
    const float* __restrict__ Bm,
    float* __restrict__ O1, long sO1b, long sO1c, int add1,
    float* __restrict__ O2, long sO2b, long sO2c) {
    constexpr int MT = (RT == 64) ? 4 : 2;
    __shared__ float As[16][RT];
    __shared__ float Bs[16][64];
    const int tid = threadIdx.x;
    const int n0 = blockIdx.x * 64;
    const int m0 = blockIdx.y * RT;
    // B staging: 16 k-rows x 64 cols, float4 per thread
    const int bkr = tid >> 4;
    const int bnc = (tid & 15) * 4;
    // A staging
    const int alr = (RT == 64) ? (tid >> 2) : (tid >> 3);
    const int alk = (RT == 64) ? ((tid & 3) * 4) : ((tid & 7) * 2);
    const int agr = m0 + alr;
    const float* Arow = A + (long)(agr & 31) * sAb + (long)(agr >> 5) * sAc;
    // microtile
    const int tm = (tid >> 4) * MT;
    const int tn = (tid & 15) * 4;
    float acc[MT][4] = {};

    for (int kt = 0; kt < HH; kt += 16) {
        if (RT == 64) {
            float4 av = *(const float4*)(Arow + kt + alk);
            As[alk + 0][alr] = av.x; As[alk + 1][alr] = av.y;
            As[alk + 2][alr] = av.z; As[alk + 3][alr] = av.w;
        } else {
            float2 av = *(const float2*)(Arow + kt + alk);
            As[alk + 0][alr] = av.x; As[alk + 1][alr] = av.y;
        }
        *(float4*)&Bs[bkr][bnc] = *(const float4*)(Bm + (size_t)(kt + bkr) * HH + n0 + bnc);
        __syncthreads();
        #pragma unroll
        for (int k = 0; k < 16; ++k) {
            float4 b4 = *(const float4*)&Bs[k][tn];
            float br[4] = {b4.x, b4.y, b4.z, b4.w};
            float ar[MT];
            if (RT == 64) {
                float4 a4 = *(const float4*)&As[k][tm];
                ar[0] = a4.x; ar[1] = a4.y; ar[2] = a4.z; ar[3] = a4.w;
            } else {
                float2 a2 = *(const float2*)&As[k][tm];
                ar[0] = a2.x; ar[1] = a2.y;
            }
            #pragma unroll
            for (int i = 0; i < MT; ++i)
                #pragma unroll
                for (int j = 0; j < 4; ++j)
                    acc[i][j] = fmaf(ar[i], br[j], acc[i][j]);
        }
        __syncthreads();
    }
    #pragma unroll
    for (int i = 0; i < MT; ++i) {
        int r = m0 + tm + i;
        float* p1 = O1 + (long)(r & 31) * sO1b + (long)(r >> 5) * sO1c + n0 + tn;
        float4 v = {acc[i][0], acc[i][1], acc[i][2], acc[i][3]};
        if (add1) {
            float4 e = *(const float4*)p1;
            v.x += e.x; v.y += e.y; v.z += e.z; v.w += e.w;
        }
        *(float4*)p1 = v;
        if (O2) {
            float* p2 = O2 + (long)(r & 31) * sO2b + (long)(r >> 5) * sO2c + n0 + tn;
            float4 e = *(const float4*)p2;
            e.x += acc[i][0]; e.y += acc[i][1]; e.z += acc[i][2]; e.w += acc[i][3];
            *(float4*)p2 = e;
        }
    }
}

// ---------------------------------------------------------------------------
// LayerNorm in place over last dim H for B*PRED rows. block=256, 4 elems/thread
// ---------------------------------------------------------------------------
__global__ __launch_bounds__(256) void ln_k(float* __restrict__ y,
                                            const float* __restrict__ w,
                                            const float* __restrict__ bia) {
    __shared__ float red[8];
    int row = blockIdx.x;
    float* p = y + (size_t)row * HH;
    int i4 = threadIdx.x * 4;
    float4 v = *(const float4*)&p[i4];
    float s = v.x + v.y + v.z + v.w;
    #pragma unroll
    for (int o = 32; o > 0; o >>= 1) s += __shfl_down(s, o, 64);
    int wid = threadIdx.x >> 6;
    if ((threadIdx.x & 63) == 0) red[wid] = s;
    __syncthreads();
    if (threadIdx.x == 0) red[4] = (red[0] + red[1] + red[2] + red[3]) * (1.f / HH);
    __syncthreads();
    float mu = red[4];
    float dx = v.x - mu, dy = v.y - mu, dz = v.z - mu, dw = v.w - mu;
    float q = dx * dx + dy * dy + dz * dz + dw * dw;
    #pragma unroll
    for (int o = 32; o > 0; o >>= 1) q += __shfl_down(q, o, 64);
    if ((threadIdx.x & 63) == 0) red[wid] = q;
    __syncthreads();
    if (threadIdx.x == 0) red[5] = (red[0] + red[1] + red[2] + red[3]) * (1.f / HH);
    __syncthreads();
    float rs = rsqrtf(red[5] + LN_EPS);
    float4 o4;
    o4.x = dx * rs * w[i4 + 0] + bia[i4 + 0];
    o4.y = dy * rs * w[i4 + 1] + bia[i4 + 1];
    o4.z = dz * rs * w[i4 + 2] + bia[i4 + 2];
    o4.w = dw * rs * w[i4 + 3] + bia[i4 + 3];
    *(float4*)&p[i4] = o4;
}

// ---------------------------------------------------------------------------
extern "C" void kernel_launch(void* const* d_in, const int* in_sizes, int n_in,
                              void* d_out, int out_size, void* d_ws, size_t ws_size,
                              hipStream_t stream) {
    const float* x    = (const float*)d_in[0];
    const float* Wxh  = (const float*)d_in[1];
    const float* Whh  = (const float*)d_in[2];
    const float* ln_w = (const float*)d_in[3];
    const float* ln_b = (const float*)d_in[4];

    float* rec  = (float*)d_out;                 // [B,L,H]
    float* outp = rec + (size_t)BB * LL * HH;    // [B,PRED,H] (also Z scratch pre-pred)
    float* WT   = (float*)d_ws;                  // M = Whh^T  [H,H]
    float* T1   = WT + (size_t)HH * HH;          // power temps
    float* T2   = T1 + (size_t)HH * HH;
    // Z ping-pong lives in the (not yet written) prediction region: 2 x 480x1024 <= 1M floats
    float* Z0   = outp;
    float* Z1   = outp + (size_t)480 * HH;

    const long LH = (long)LL * HH;   // b-stride in rec
    const long CH = (long)CC * HH;   // chunk-stride in rec
    float* nul = (float*)nullptr;

    // M = Whh^T
    transpose_k<<<dim3(HH / 32, HH / 32), dim3(32, 8), 0, stream>>>(Whh, WT);

    // rec[b][l][k] = sum_h x[b][l][h] * Wxh[k][h]
    gemm_xw<<<dim3(HH / 64, BB * LL / 64), 256, 0, stream>>>(x, Wxh, rec);

    // M^32 by repeated squaring: T1=M2, T2=M4, T1=M8, T2=M16, T1=M32
    rnn_gemm<64><<<dim3(16, 16), 256, 0, stream>>>(WT, HH, 32L * HH, WT, T1, HH, 32L * HH, 0, nul, 0, 0);
    rnn_gemm<64><<<dim3(16, 16), 256, 0, stream>>>(T1, HH, 32L * HH, T1, T2, HH, 32L * HH, 0, nul, 0, 0);
    rnn_gemm<64><<<dim3(16, 16), 256, 0, stream>>>(T2, HH, 32L * HH, T2, T1, HH, 32L * HH, 0, nul, 0, 0);
    rnn_gemm<64><<<dim3(16, 16), 256, 0, stream>>>(T1, HH, 32L * HH, T1, T2, HH, 32L * HH, 0, nul, 0, 0);
    rnn_gemm<64><<<dim3(16, 16), 256, 0, stream>>>(T2, HH, 32L * HH, T2, T1, HH, 32L * HH, 0, nul, 0, 0);
    float* MC = T1;  // M^32

    // Stage 1: local chunk scans. 31 sequential steps over 512 rows (b,c).
    //   rec[:, c*C+o, :] += rec[:, c*C+o-1, :] @ M
    for (int o = 1; o < CC; ++o)
        rnn_gemm<32><<<dim3(16, 16), 256, 0, stream>>>(
            rec + (size_t)(o - 1) * HH, LH, CH, WT,
            rec + (size_t)o * HH, LH, CH, 1, nul, 0, 0);

    // Stage 2: chunk-boundary carries (15 tiny sequential steps, 32 rows).
    //   rec[:, c*C+31, :] += rec[:, (c-1)*C+31, :] @ M^32
    for (int c = 1; c < NC; ++c)
        rnn_gemm<32><<<dim3(16, 1), 256, 0, stream>>>(
            rec + (size_t)((c - 1) * CC + CC - 1) * HH, LH, 0, MC,
            rec + (size_t)(c * CC + CC - 1) * HH, LH, 0, 1, nul, 0, 0);

    // Stage 3: carry fix-up, 31 sequential steps over 480 rows (b, c=0..14).
    //   Z_o = Z_{o-1} @ M  (Z_{-1} = h_end of chunk c), rec[:, (c+1)*C+o, :] += Z_o
    rnn_gemm<32><<<dim3(16, 15), 256, 0, stream>>>(
        rec + (size_t)(CC - 1) * HH, LH, CH, WT,
        Z0, HH, 32L * HH, 0,
        rec + (size_t)CC * HH, LH, CH);
    for (int o = 1; o < CC - 1; ++o) {
        float* Zs = (o & 1) ? Z0 : Z1;
        float* Zd = (o & 1) ? Z1 : Z0;
        rnn_gemm<32><<<dim3(16, 15), 256, 0, stream>>>(
            Zs, HH, 32L * HH, WT,
            Zd, HH, 32L * HH, 0,
            rec + (size_t)(CC + o) * HH, LH, CH);
    }

    // Prediction: 32 tiny sequential steps (overwrites the Z scratch region).
    rnn_gemm<32><<<dim3(16, 1), 256, 0, stream>>>(
        rec + (size_t)(LL - 1) * HH, LH, 0, WT,
        outp, (long)PRED * HH, 0, 0, nul, 0, 0);
    for (int t = 1; t < PRED; ++t)
        rnn_gemm<32><<<dim3(16, 1), 256, 0, stream>>>(
            outp + (size_t)(t - 1) * HH, (long)PRED * HH, 0, WT,
            outp + (size_t)t * HH, (long)PRED * HH, 0, 0, nul, 0, 0);

    // LayerNorm the prediction rows in place
    ln_k<<<BB * PRED, 256, 0, stream>>>(outp, ln_w, ln_b);
}

// Round 3
// 4196.175 us; speedup vs baseline: 3.1689x; 1.2904x over previous
//
#include <hip/hip_runtime.h>

#define BB 32
#define LL 512
#define HH 1024
#define PRED 32
#define CC 16            // chunk length
#define NC (LL / CC)     // 32 chunks
#define LN_EPS 1e-5f

// ---------------------------------------------------------------------------
// Transpose Whh[k][j] -> WT[j][k]  (H x H).  WT = M where h_t = u_t + h_{t-1}M
// ---------------------------------------------------------------------------
__global__ __launch_bounds__(256) void transpose_k(const float* __restrict__ in,
                                                   float* __restrict__ out) {
    __shared__ float tile[32][33];
    int bx = blockIdx.x * 32, by = blockIdx.y * 32;
    int tx = threadIdx.x, ty = threadIdx.y;
    #pragma unroll
    for (int i = 0; i < 32; i += 8)
        tile[ty + i][tx] = in[(size_t)(by + ty + i) * HH + bx + tx];
    __syncthreads();
    #pragma unroll
    for (int i = 0; i < 32; i += 8)
        out[(size_t)(bx + ty + i) * HH + by + tx] = tile[tx][ty + i];
}

// ---------------------------------------------------------------------------
// xw GEMM:  C[m][n] = sum_k A[m][k] * Bt[n][k]   (Bt row-major [N][K])
// 64x64 tile, BK=16, 256 thr, 4x4 microtile. LDS stride 68 (2-way max alias).
// ---------------------------------------------------------------------------
__global__ __launch_bounds__(256) void gemm_xw(const float* __restrict__ A,
                                               const float* __restrict__ Bt,
                                               float* __restrict__ C) {
    const int K = HH, N = HH;
    __shared__ float As[16][68];
    __shared__ float Bs[16][68];
    int tid = threadIdx.x;
    int m0 = blockIdx.y * 64, n0 = blockIdx.x * 64;
    int tn = (tid & 15) * 4;
    int tm = (tid >> 4) * 4;
    int lr = tid >> 2;
    int lk = (tid & 3) * 4;
    float acc[4][4] = {};
    const float* Ap = A + (size_t)(m0 + lr) * K + lk;
    const float* Bp = Bt + (size_t)(n0 + lr) * K + lk;
    for (int kt = 0; kt < K; kt += 16) {
        float4 av = *(const float4*)(Ap + kt);
        float4 bv = *(const float4*)(Bp + kt);
        As[lk + 0][lr] = av.x; As[lk + 1][lr] = av.y;
        As[lk + 2][lr] = av.z; As[lk + 3][lr] = av.w;
        Bs[lk + 0][lr] = bv.x; Bs[lk + 1][lr] = bv.y;
        Bs[lk + 2][lr] = bv.z; Bs[lk + 3][lr] = bv.w;
        __syncthreads();
        #pragma unroll
        for (int k = 0; k < 16; ++k) {
            float4 a = *(const float4*)&As[k][tm];
            float4 b = *(const float4*)&Bs[k][tn];
            float ar[4] = {a.x, a.y, a.z, a.w};
            float br[4] = {b.x, b.y, b.z, b.w};
            #pragma unroll
            for (int i = 0; i < 4; ++i)
                #pragma unroll
                for (int j = 0; j < 4; ++j)
                    acc[i][j] = fmaf(ar[i], br[j], acc[i][j]);
        }
        __syncthreads();
    }
    #pragma unroll
    for (int i = 0; i < 4; ++i) {
        float4 o = {acc[i][0], acc[i][1], acc[i][2], acc[i][3]};
        *(float4*)&C[(size_t)(m0 + tm + i) * N + n0 + tn] = o;
    }
}

// ---------------------------------------------------------------------------
// step_k: dual-descriptor strided-row GEMM vs k-major B.
//   acc(r,n) = sum_k Arow(r)[k] * Bm[k][n]
//   row r -> base + (r&31)*sb + (r>>5)*sc
//   O = acc (+O if add);  optional P += acc.
// Tile 32x64, 128 threads, 4x4 microtile, BK=32, register double-buffer.
// Blocks with blockIdx.y < ySplit use descriptor set 1, else set 2 (y-rebased).
// ---------------------------------------------------------------------------
__global__ __launch_bounds__(128) void step_k(
    const float* __restrict__ Bm, int ySplit,
    const float* A1, long s1ab, long s1ac,
    float* O1, long s1ob, long s1oc, int add1,
    float* P1, long s1pb, long s1pc,
    const float* A2, long s2ab, long s2ac,
    float* O2, long s2ob, long s2oc, int add2,
    float* P2, long s2pb, long s2pc) {
    __shared__ float As[32][34];   // [k][r], stride 34 -> <=2-way bank alias
    __shared__ float Bs[32][68];   // [k][n], stride 68 -> <=2-way bank alias
    const int tid = threadIdx.x;
    const int n0 = blockIdx.x * 64;
    int yy = blockIdx.y;
    const float* A; float* O; float* P;
    long sab, sac, sob, soc, spb, spc; int addf;
    if (yy < ySplit) {
        A = A1; sab = s1ab; sac = s1ac;
        O = O1; sob = s1ob; soc = s1oc; addf = add1;
        P = P1; spb = s1pb; spc = s1pc;
    } else {
        yy -= ySplit;
        A = A2; sab = s2ab; sac = s2ac;
        O = O2; sob = s2ob; soc = s2oc; addf = add2;
        P = P2; spb = s2pb; spc = s2pc;
    }
    const int m0 = yy * 32;
    // A staging: 32 rows x 32 k, 2 float4/thread; 4 threads cover one row's 128B
    const int ar = tid >> 2;            // 0..31
    const int ak = (tid & 3) * 8;       // 0,8,16,24
    const int agr = m0 + ar;
    const float* Arow = A + (long)(agr & 31) * sab + (long)(agr >> 5) * sac + ak;
    // B staging: 32 k-rows x 64 cols, 4 float4/thread
    const int bk = tid >> 4;            // 0..7
    const int bn = (tid & 15) * 4;
    const float* Bp = Bm + (size_t)bk * HH + n0 + bn;
    // compute microtile
    const int tm = (tid & 7) * 4;
    const int tn = (tid >> 3) * 4;
    float acc[4][4] = {};

    float4 a0 = *(const float4*)(Arow);
    float4 a1 = *(const float4*)(Arow + 4);
    float4 b0 = *(const float4*)(Bp);
    float4 b1 = *(const float4*)(Bp + 8 * HH);
    float4 b2 = *(const float4*)(Bp + 16 * HH);
    float4 b3 = *(const float4*)(Bp + 24 * HH);

    for (int kt = 0; kt < HH; kt += 32) {
        As[ak + 0][ar] = a0.x; As[ak + 1][ar] = a0.y;
        As[ak + 2][ar] = a0.z; As[ak + 3][ar] = a0.w;
        As[ak + 4][ar] = a1.x; As[ak + 5][ar] = a1.y;
        As[ak + 6][ar] = a1.z; As[ak + 7][ar] = a1.w;
        *(float4*)&Bs[bk][bn]      = b0;
        *(float4*)&Bs[bk + 8][bn]  = b1;
        *(float4*)&Bs[bk + 16][bn] = b2;
        *(float4*)&Bs[bk + 24][bn] = b3;
        __syncthreads();
        if (kt + 32 < HH) {
            a0 = *(const float4*)(Arow + kt + 32);
            a1 = *(const float4*)(Arow + kt + 36);
            const float* Bpn = Bp + (size_t)(kt + 32) * HH;
            b0 = *(const float4*)(Bpn);
            b1 = *(const float4*)(Bpn + 8 * HH);
            b2 = *(const float4*)(Bpn + 16 * HH);
            b3 = *(const float4*)(Bpn + 24 * HH);
        }
        #pragma unroll
        for (int k = 0; k < 32; ++k) {
            float2 av0 = *(const float2*)&As[k][tm];
            float2 av1 = *(const float2*)&As[k][tm + 2];
            float4 bv  = *(const float4*)&Bs[k][tn];
            float ar4[4] = {av0.x, av0.y, av1.x, av1.y};
            float br[4]  = {bv.x, bv.y, bv.z, bv.w};
            #pragma unroll
            for (int i = 0; i < 4; ++i)
                #pragma unroll
                for (int j = 0; j < 4; ++j)
                    acc[i][j] = fmaf(ar4[i], br[j], acc[i][j]);
        }
        __syncthreads();
    }
    #pragma unroll
    for (int i = 0; i < 4; ++i) {
        int r = m0 + tm + i;
        float* p = O + (long)(r & 31) * sob + (long)(r >> 5) * soc + n0 + tn;
        float4 v = {acc[i][0], acc[i][1], acc[i][2], acc[i][3]};
        if (addf) {
            float4 e = *(const float4*)p;
            v.x += e.x; v.y += e.y; v.z += e.z; v.w += e.w;
        }
        *(float4*)p = v;
        if (P) {
            float* q = P + (long)(r & 31) * spb + (long)(r >> 5) * spc + n0 + tn;
            float4 e = *(const float4*)q;
            e.x += acc[i][0]; e.y += acc[i][1]; e.z += acc[i][2]; e.w += acc[i][3];
            *(float4*)q = e;
        }
    }
}

// ---------------------------------------------------------------------------
// LayerNorm in place over last dim H for B*PRED rows. block=256, 4 elems/thread
// ---------------------------------------------------------------------------
__global__ __launch_bounds__(256) void ln_k(float* __restrict__ y,
                                            const float* __restrict__ w,
                                            const float* __restrict__ bia) {
    __shared__ float red[8];
    int row = blockIdx.x;
    float* p = y + (size_t)row * HH;
    int i4 = threadIdx.x * 4;
    float4 v = *(const float4*)&p[i4];
    float s = v.x + v.y + v.z + v.w;
    #pragma unroll
    for (int o = 32; o > 0; o >>= 1) s += __shfl_down(s, o, 64);
    int wid = threadIdx.x >> 6;
    if ((threadIdx.x & 63) == 0) red[wid] = s;
    __syncthreads();
    if (threadIdx.x == 0) red[4] = (red[0] + red[1] + red[2] + red[3]) * (1.f / HH);
    __syncthreads();
    float mu = red[4];
    float dx = v.x - mu, dy = v.y - mu, dz = v.z - mu, dw = v.w - mu;
    float q = dx * dx + dy * dy + dz * dz + dw * dw;
    #pragma unroll
    for (int o = 32; o > 0; o >>= 1) q += __shfl_down(q, o, 64);
    if ((threadIdx.x & 63) == 0) red[wid] = q;
    __syncthreads();
    if (threadIdx.x == 0) red[5] = (red[0] + red[1] + red[2] + red[3]) * (1.f / HH);
    __syncthreads();
    float rs = rsqrtf(red[5] + LN_EPS);
    float4 o4;
    o4.x = dx * rs * w[i4 + 0] + bia[i4 + 0];
    o4.y = dy * rs * w[i4 + 1] + bia[i4 + 1];
    o4.z = dz * rs * w[i4 + 2] + bia[i4 + 2];
    o4.w = dw * rs * w[i4 + 3] + bia[i4 + 3];
    *(float4*)&p[i4] = o4;
}

// ---------------------------------------------------------------------------
extern "C" void kernel_launch(void* const* d_in, const int* in_sizes, int n_in,
                              void* d_out, int out_size, void* d_ws, size_t ws_size,
                              hipStream_t stream) {
    const float* x    = (const float*)d_in[0];
    const float* Wxh  = (const float*)d_in[1];
    const float* Whh  = (const float*)d_in[2];
    const float* ln_w = (const float*)d_in[3];
    const float* ln_b = (const float*)d_in[4];

    float* rec  = (float*)d_out;                 // [B,L,H]
    float* outp = rec + (size_t)BB * LL * HH;    // [B,PRED,H]
    float* WT   = (float*)d_ws;                  // M = Whh^T  [H,H]
    float* T1   = WT + (size_t)HH * HH;          // M^2 -> M^8 -> Z ping
    float* T2   = T1 + (size_t)HH * HH;          // M^4 -> M^16 -> Z pong

    const long LH   = (long)LL * HH;   // b-stride in rec
    const long CH   = (long)CC * HH;   // chunk-stride in rec
    const long ZB   = (long)HH;        // Z row strides (flat [992][H])
    const long ZC   = 32L * HH;
    const long PB   = (long)PRED * HH; // b-stride in outp
    float* nul = (float*)nullptr;
    const float* nulc = (const float*)nullptr;

    // M = Whh^T
    transpose_k<<<dim3(HH / 32, HH / 32), dim3(32, 8), 0, stream>>>(Whh, WT);

    // rec = x @ Wxh^T
    gemm_xw<<<dim3(HH / 64, BB * LL / 64), 256, 0, stream>>>(x, Wxh, rec);

    // Powers: T1=M^2, T2=M^4, T1=M^8, T2=M^16   (step_k, M=1024 -> grid (16,32))
    #define POW(SRC, DST) \
        step_k<<<dim3(16, 32), 128, 0, stream>>>(SRC, 32, \
            SRC, (long)HH, 32L * HH, DST, (long)HH, 32L * HH, 0, nul, 0, 0, \
            nulc, 0, 0, nul, 0, 0, 0, nul, 0, 0)
    POW(WT, T1);
    POW(T1, T2);
    POW(T2, T1);
    POW(T1, T2);   // T2 = M^16
    #undef POW

    // Stage 1: local chunk scans. 15 steps, M = 1024 rows (b inner, chunk outer).
    for (int o = 1; o < CC; ++o)
        step_k<<<dim3(16, 32), 128, 0, stream>>>(WT, 32,
            rec + (size_t)(o - 1) * HH, LH, CH,
            rec + (size_t)o * HH, LH, CH, 1, nul, 0, 0,
            nulc, 0, 0, nul, 0, 0, 0, nul, 0, 0);

    // Stage 2: chunk-boundary carries, 31 tiny steps with M^16 (=T2).
    for (int c = 1; c < NC; ++c)
        step_k<<<dim3(16, 1), 128, 0, stream>>>(T2, 1,
            rec + (size_t)((c - 1) * CC + CC - 1) * HH, LH, 0,
            rec + (size_t)(c * CC + CC - 1) * HH, LH, 0, 1, nul, 0, 0,
            nulc, 0, 0, nul, 0, 0, 0, nul, 0, 0);

    // pred step 0: outp[:,0] = h_last @ M
    step_k<<<dim3(16, 1), 128, 0, stream>>>(WT, 1,
        rec + (size_t)(LL - 1) * HH, LH, 0,
        outp, PB, 0, 0, nul, 0, 0,
        nulc, 0, 0, nul, 0, 0, 0, nul, 0, 0);

    // Stage 3 fused with pred t=1..15. 15 steps, grid (16, 31+1).
    //   set1 (y<31): Z_o = Z_{o-1}@M (Z_{-1}=chunk boundaries), rec[:,(c+1)*CC+o] += Z_o
    //   set2 (y==31): outp[:,t] = outp[:,t-1] @ M
    for (int o = 0; o < CC - 1; ++o) {
        const float* Zs; long zsb, zsc;
        if (o == 0) { Zs = rec + (size_t)(CC - 1) * HH; zsb = LH; zsc = CH; }
        else        { Zs = (o & 1) ? T1 : T2; zsb = ZB; zsc = ZC; }
        float* Zd = (o & 1) ? T2 : T1;
        step_k<<<dim3(16, 32), 128, 0, stream>>>(WT, 31,
            Zs, zsb, zsc,
            Zd, ZB, ZC, 0,
            rec + (size_t)(CC + o) * HH, LH, CH,
            outp + (size_t)o * HH, PB, 0,
            outp + (size_t)(o + 1) * HH, PB, 0, 0,
            nul, 0, 0);
    }

    // pred tail t = 16..31
    for (int t = CC; t < PRED; ++t)
        step_k<<<dim3(16, 1), 128, 0, stream>>>(WT, 1,
            outp + (size_t)(t - 1) * HH, PB, 0,
            outp + (size_t)t * HH, PB, 0, 0, nul, 0, 0,
            nulc, 0, 0, nul, 0, 0, 0, nul, 0, 0);

    // LayerNorm the prediction rows in place
    ln_k<<<BB * PRED, 256, 0, stream>>>(outp, ln_w, ln_b);
}

// Round 5
// 3573.531 us; speedup vs baseline: 3.7211x; 1.1742x over previous
//
#include <hip/hip_runtime.h>

#define BB 32
#define LL 512
#define HH 1024
#define PRED 32
#define CC 16            // chunk length
#define NC (LL / CC)     // 32 chunks
#define LN_EPS 1e-5f

typedef short bf16x8 __attribute__((ext_vector_type(8)));
typedef float f32x4 __attribute__((ext_vector_type(4)));

static __device__ __forceinline__ void split3(float x, short& h, short& m, short& l) {
    unsigned u = __float_as_uint(x);
    unsigned rh = (u + 0x7fffu + ((u >> 16) & 1u)) & 0xffff0000u;
    h = (short)(rh >> 16);
    float x1 = x - __uint_as_float(rh);
    unsigned u1 = __float_as_uint(x1);
    unsigned rm = (u1 + 0x7fffu + ((u1 >> 16) & 1u)) & 0xffff0000u;
    m = (short)(rm >> 16);
    float x2 = x1 - __uint_as_float(rm);
    unsigned u2 = __float_as_uint(x2);
    unsigned rl = (u2 + 0x7fffu + ((u2 >> 16) & 1u)) & 0xffff0000u;
    l = (short)(rl >> 16);
}

// ---------------------------------------------------------------------------
// Transpose Whh[k][j] -> WT[j][k]  (H x H).  WT = M where h_t = u_t + h_{t-1}M
// ---------------------------------------------------------------------------
__global__ __launch_bounds__(256) void transpose_k(const float* __restrict__ in,
                                                   float* __restrict__ out) {
    __shared__ float tile[32][33];
    int bx = blockIdx.x * 32, by = blockIdx.y * 32;
    int tx = threadIdx.x, ty = threadIdx.y;
    #pragma unroll
    for (int i = 0; i < 32; i += 8)
        tile[ty + i][tx] = in[(size_t)(by + ty + i) * HH + bx + tx];
    __syncthreads();
    #pragma unroll
    for (int i = 0; i < 32; i += 8)
        out[(size_t)(bx + ty + i) * HH + by + tx] = tile[tx][ty + i];
}

// ---------------------------------------------------------------------------
// split_t: fp32 P[k][n] -> 3 transposed bf16 matrices out[s][n][k] (s=hi,mid,lo)
// ---------------------------------------------------------------------------
__global__ __launch_bounds__(256) void split_t(const float* __restrict__ in,
                                               short* __restrict__ out) {
    const size_t HM = (size_t)HH * HH;
    __shared__ float tile[32][33];
    int n0 = blockIdx.x * 32, k0 = blockIdx.y * 32;
    int tx = threadIdx.x, ty = threadIdx.y;
    #pragma unroll
    for (int i = 0; i < 32; i += 8)
        tile[ty + i][tx] = in[(size_t)(k0 + ty + i) * HH + n0 + tx];  // [k_local][n_local]
    __syncthreads();
    #pragma unroll
    for (int i = 0; i < 32; i += 8) {
        float v = tile[tx][ty + i];           // k = k0+tx, n = n0+ty+i
        short h, m, l;
        split3(v, h, m, l);
        size_t o = (size_t)(n0 + ty + i) * HH + k0 + tx;
        out[o] = h; out[HM + o] = m; out[2 * HM + o] = l;
    }
}

// ---------------------------------------------------------------------------
// xw GEMM (fp32):  C[m][n] = sum_k A[m][k] * Bt[n][k]
// ---------------------------------------------------------------------------
__global__ __launch_bounds__(256) void gemm_xw(const float* __restrict__ A,
                                               const float* __restrict__ Bt,
                                               float* __restrict__ C) {
    const int K = HH, N = HH;
    __shared__ float As[16][68];
    __shared__ float Bs[16][68];
    int tid = threadIdx.x;
    int m0 = blockIdx.y * 64, n0 = blockIdx.x * 64;
    int tn = (tid & 15) * 4;
    int tm = (tid >> 4) * 4;
    int lr = tid >> 2;
    int lk = (tid & 3) * 4;
    float acc[4][4] = {};
    const float* Ap = A + (size_t)(m0 + lr) * K + lk;
    const float* Bp = Bt + (size_t)(n0 + lr) * K + lk;
    for (int kt = 0; kt < K; kt += 16) {
        float4 av = *(const float4*)(Ap + kt);
        float4 bv = *(const float4*)(Bp + kt);
        As[lk + 0][lr] = av.x; As[lk + 1][lr] = av.y;
        As[lk + 2][lr] = av.z; As[lk + 3][lr] = av.w;
        Bs[lk + 0][lr] = bv.x; Bs[lk + 1][lr] = bv.y;
        Bs[lk + 2][lr] = bv.z; Bs[lk + 3][lr] = bv.w;
        __syncthreads();
        #pragma unroll
        for (int k = 0; k < 16; ++k) {
            float4 a = *(const float4*)&As[k][tm];
            float4 b = *(const float4*)&Bs[k][tn];
            float ar[4] = {a.x, a.y, a.z, a.w};
            float br[4] = {b.x, b.y, b.z, b.w};
            #pragma unroll
            for (int i = 0; i < 4; ++i)
                #pragma unroll
                for (int j = 0; j < 4; ++j)
                    acc[i][j] = fmaf(ar[i], br[j], acc[i][j]);
        }
        __syncthreads();
    }
    #pragma unroll
    for (int i = 0; i < 4; ++i) {
        float4 o = {acc[i][0], acc[i][1], acc[i][2], acc[i][3]};
        *(float4*)&C[(size_t)(m0 + tm + i) * N + n0 + tn] = o;
    }
}

// ---------------------------------------------------------------------------
// step_m: MFMA bf16x6 strided-row GEMM.  acc(r,n) = sum_k Arow(r)[k] * B[k][n]
//   A: fp32, split 3-way on the fly.  Bsp: pre-split pre-transposed bf16,
//   3 matrices [n][k] concatenated (hi, mid, lo).
//   row r -> base + (r&31)*sb + (r>>5)*sc.   O = acc (+O if add);  P += acc.
// Tile 32(M)x64(N), 128 threads (2 waves, one 32-col half each), BK=32.
// ---------------------------------------------------------------------------
__global__ __launch_bounds__(128) void step_m(
    const short* __restrict__ Bsp,
    const float* __restrict__ A, long sab, long sac,
    float* __restrict__ O, long sob, long soc, int add,
    float* __restrict__ P, long spb, long spc) {
    const size_t HM = (size_t)HH * HH;
    __shared__ __align__(16) short As[3][32][40];
    __shared__ __align__(16) short Bs[3][64][40];
    const int tid = threadIdx.x;
    const int lane = tid & 63;
    const int w = tid >> 6;
    const int n0 = blockIdx.x * 64;
    const int m0 = blockIdx.y * 32;
    // A staging: row ar = tid>>2 (0..31), k-chunk (tid&3)*8  -> covers k 0..31
    const int ar = tid >> 2;
    const int akc = (tid & 3) * 8;
    const int agr = m0 + ar;
    const float* Arow = A + (long)(agr & 31) * sab + (long)(agr >> 5) * sac + akc;
    // B staging: n-row = tid&63 (0..63), k-half = (tid>>6)*16 -> 2 x bf16x8 each
    // covers full 64 n x 32 k per split  (R4 bug: only k 0..15 was covered)
    const int bnr = tid & 63;
    const int bkh = (tid >> 6) * 16;
    const size_t bbase = (size_t)(n0 + bnr) * HH + bkh;
    // fragment read offsets
    const int fr = lane & 15;          // row (A) / col (B) within fragment
    const int fk = (lane >> 4) * 8;    // k offset within BK=32

    f32x4 acc00 = 0, acc01 = 0, acc10 = 0, acc11 = 0;

    for (int kt = 0; kt < HH; kt += 32) {
        // ---- stage A: load 8 f32, 3-way split, store to LDS
        float4 av0 = *(const float4*)(Arow + kt);
        float4 av1 = *(const float4*)(Arow + kt + 4);
        float xs[8] = {av0.x, av0.y, av0.z, av0.w, av1.x, av1.y, av1.z, av1.w};
        bf16x8 vh, vm, vl;
        #pragma unroll
        for (int j = 0; j < 8; ++j) {
            short h, m, l;
            split3(xs[j], h, m, l);
            vh[j] = h; vm[j] = m; vl[j] = l;
        }
        *(bf16x8*)&As[0][ar][akc] = vh;
        *(bf16x8*)&As[1][ar][akc] = vm;
        *(bf16x8*)&As[2][ar][akc] = vl;
        // ---- stage B: 3 splits x 2 bf16x8 per thread
        #pragma unroll
        for (int s = 0; s < 3; ++s) {
            const short* src = Bsp + s * HM + bbase + kt;
            *(bf16x8*)&Bs[s][bnr][bkh]     = *(const bf16x8*)(src);
            *(bf16x8*)&Bs[s][bnr][bkh + 8] = *(const bf16x8*)(src + 8);
        }
        __syncthreads();
        // ---- fragments
        bf16x8 a00 = *(const bf16x8*)&As[0][fr][fk];
        bf16x8 a01 = *(const bf16x8*)&As[0][16 + fr][fk];
        bf16x8 a10 = *(const bf16x8*)&As[1][fr][fk];
        bf16x8 a11 = *(const bf16x8*)&As[1][16 + fr][fk];
        bf16x8 a20 = *(const bf16x8*)&As[2][fr][fk];
        bf16x8 a21 = *(const bf16x8*)&As[2][16 + fr][fk];
        bf16x8 b00 = *(const bf16x8*)&Bs[0][w * 32 + fr][fk];
        bf16x8 b01 = *(const bf16x8*)&Bs[0][w * 32 + 16 + fr][fk];
        bf16x8 b10 = *(const bf16x8*)&Bs[1][w * 32 + fr][fk];
        bf16x8 b11 = *(const bf16x8*)&Bs[1][w * 32 + 16 + fr][fk];
        bf16x8 b20 = *(const bf16x8*)&Bs[2][w * 32 + fr][fk];
        bf16x8 b21 = *(const bf16x8*)&Bs[2][w * 32 + 16 + fr][fk];
        #define MFMA6(ACC, AH, AM, AL, BH, BM, BL) \
            ACC = __builtin_amdgcn_mfma_f32_16x16x32_bf16(AL, BH, ACC, 0, 0, 0); \
            ACC = __builtin_amdgcn_mfma_f32_16x16x32_bf16(AH, BL, ACC, 0, 0, 0); \
            ACC = __builtin_amdgcn_mfma_f32_16x16x32_bf16(AM, BM, ACC, 0, 0, 0); \
            ACC = __builtin_amdgcn_mfma_f32_16x16x32_bf16(AM, BH, ACC, 0, 0, 0); \
            ACC = __builtin_amdgcn_mfma_f32_16x16x32_bf16(AH, BM, ACC, 0, 0, 0); \
            ACC = __builtin_amdgcn_mfma_f32_16x16x32_bf16(AH, BH, ACC, 0, 0, 0);
        MFMA6(acc00, a00, a10, a20, b00, b10, b20)
        MFMA6(acc01, a00, a10, a20, b01, b11, b21)
        MFMA6(acc10, a01, a11, a21, b00, b10, b20)
        MFMA6(acc11, a01, a11, a21, b01, b11, b21)
        #undef MFMA6
        __syncthreads();
    }
    // ---- epilogue: C/D layout col=lane&15, row=(lane>>4)*4+reg (m89-verified)
    const int orow = (lane >> 4) * 4;
    #pragma unroll
    for (int mf = 0; mf < 2; ++mf) {
        #pragma unroll
        for (int nf = 0; nf < 2; ++nf) {
            f32x4 v = mf == 0 ? (nf == 0 ? acc00 : acc01) : (nf == 0 ? acc10 : acc11);
            int c = n0 + w * 32 + nf * 16 + fr;
            #pragma unroll
            for (int reg = 0; reg < 4; ++reg) {
                int r = m0 + mf * 16 + orow + reg;
                float* p = O + (long)(r & 31) * sob + (long)(r >> 5) * soc + c;
                float val = v[reg];
                if (add) val += *p;
                *p = val;
                if (P) {
                    float* q = P + (long)(r & 31) * spb + (long)(r >> 5) * spc + c;
                    *q += v[reg];
                }
            }
        }
    }
}

// ---------------------------------------------------------------------------
// step_k (fp32 fallback path, dual descriptor) — proven R3 kernel
// ---------------------------------------------------------------------------
__global__ __launch_bounds__(128) void step_k(
    const float* __restrict__ Bm, int ySplit,
    const float* A1, long s1ab, long s1ac,
    float* O1, long s1ob, long s1oc, int add1,
    float* P1, long s1pb, long s1pc,
    const float* A2, long s2ab, long s2ac,
    float* O2, long s2ob, long s2oc, int add2,
    float* P2, long s2pb, long s2pc) {
    __shared__ float As[32][34];
    __shared__ float Bs[32][68];
    const int tid = threadIdx.x;
    const int n0 = blockIdx.x * 64;
    int yy = blockIdx.y;
    const float* A; float* O; float* P;
    long sab, sac, sob, soc, spb, spc; int addf;
    if (yy < ySplit) {
        A = A1; sab = s1ab; sac = s1ac;
        O = O1; sob = s1ob; soc = s1oc; addf = add1;
        P = P1; spb = s1pb; spc = s1pc;
    } else {
        yy -= ySplit;
        A = A2; sab = s2ab; sac = s2ac;
        O = O2; sob = s2ob; soc = s2oc; addf = add2;
        P = P2; spb = s2pb; spc = s2pc;
    }
    const int m0 = yy * 32;
    const int ar = tid >> 2;
    const int ak = (tid & 3) * 8;
    const int agr = m0 + ar;
    const float* Arow = A + (long)(agr & 31) * sab + (long)(agr >> 5) * sac + ak;
    const int bk = tid >> 4;
    const int bn = (tid & 15) * 4;
    const float* Bp = Bm + (size_t)bk * HH + n0 + bn;
    const int tm = (tid & 7) * 4;
    const int tn = (tid >> 3) * 4;
    float acc[4][4] = {};
    float4 a0 = *(const float4*)(Arow);
    float4 a1 = *(const float4*)(Arow + 4);
    float4 b0 = *(const float4*)(Bp);
    float4 b1 = *(const float4*)(Bp + 8 * HH);
    float4 b2 = *(const float4*)(Bp + 16 * HH);
    float4 b3 = *(const float4*)(Bp + 24 * HH);
    for (int kt = 0; kt < HH; kt += 32) {
        As[ak + 0][ar] = a0.x; As[ak + 1][ar] = a0.y;
        As[ak + 2][ar] = a0.z; As[ak + 3][ar] = a0.w;
        As[ak + 4][ar] = a1.x; As[ak + 5][ar] = a1.y;
        As[ak + 6][ar] = a1.z; As[ak + 7][ar] = a1.w;
        *(float4*)&Bs[bk][bn]      = b0;
        *(float4*)&Bs[bk + 8][bn]  = b1;
        *(float4*)&Bs[bk + 16][bn] = b2;
        *(float4*)&Bs[bk + 24][bn] = b3;
        __syncthreads();
        if (kt + 32 < HH) {
            a0 = *(const float4*)(Arow + kt + 32);
            a1 = *(const float4*)(Arow + kt + 36);
            const float* Bpn = Bp + (size_t)(kt + 32) * HH;
            b0 = *(const float4*)(Bpn);
            b1 = *(const float4*)(Bpn + 8 * HH);
            b2 = *(const float4*)(Bpn + 16 * HH);
            b3 = *(const float4*)(Bpn + 24 * HH);
        }
        #pragma unroll
        for (int k = 0; k < 32; ++k) {
            float2 av0 = *(const float2*)&As[k][tm];
            float2 av1 = *(const float2*)&As[k][tm + 2];
            float4 bv  = *(const float4*)&Bs[k][tn];
            float ar4[4] = {av0.x, av0.y, av1.x, av1.y};
            float br[4]  = {bv.x, bv.y, bv.z, bv.w};
            #pragma unroll
            for (int i = 0; i < 4; ++i)
                #pragma unroll
                for (int j = 0; j < 4; ++j)
                    acc[i][j] = fmaf(ar4[i], br[j], acc[i][j]);
        }
        __syncthreads();
    }
    #pragma unroll
    for (int i = 0; i < 4; ++i) {
        int r = m0 + tm + i;
        float* p = O + (long)(r & 31) * sob + (long)(r >> 5) * soc + n0 + tn;
        float4 v = {acc[i][0], acc[i][1], acc[i][2], acc[i][3]};
        if (addf) {
            float4 e = *(const float4*)p;
            v.x += e.x; v.y += e.y; v.z += e.z; v.w += e.w;
        }
        *(float4*)p = v;
        if (P) {
            float* q = P + (long)(r & 31) * spb + (long)(r >> 5) * spc + n0 + tn;
            float4 e = *(const float4*)q;
            e.x += acc[i][0]; e.y += acc[i][1]; e.z += acc[i][2]; e.w += acc[i][3];
            *(float4*)q = e;
        }
    }
}

// ---------------------------------------------------------------------------
// LayerNorm in place over last dim H for B*PRED rows.
// ---------------------------------------------------------------------------
__global__ __launch_bounds__(256) void ln_k(float* __restrict__ y,
                                            const float* __restrict__ w,
                                            const float* __restrict__ bia) {
    __shared__ float red[8];
    int row = blockIdx.x;
    float* p = y + (size_t)row * HH;
    int i4 = threadIdx.x * 4;
    float4 v = *(const float4*)&p[i4];
    float s = v.x + v.y + v.z + v.w;
    #pragma unroll
    for (int o = 32; o > 0; o >>= 1) s += __shfl_down(s, o, 64);
    int wid = threadIdx.x >> 6;
    if ((threadIdx.x & 63) == 0) red[wid] = s;
    __syncthreads();
    if (threadIdx.x == 0) red[4] = (red[0] + red[1] + red[2] + red[3]) * (1.f / HH);
    __syncthreads();
    float mu = red[4];
    float dx = v.x - mu, dy = v.y - mu, dz = v.z - mu, dw = v.w - mu;
    float q = dx * dx + dy * dy + dz * dz + dw * dw;
    #pragma unroll
    for (int o = 32; o > 0; o >>= 1) q += __shfl_down(q, o, 64);
    if ((threadIdx.x & 63) == 0) red[wid] = q;
    __syncthreads();
    if (threadIdx.x == 0) red[5] = (red[0] + red[1] + red[2] + red[3]) * (1.f / HH);
    __syncthreads();
    float rs = rsqrtf(red[5] + LN_EPS);
    float4 o4;
    o4.x = dx * rs * w[i4 + 0] + bia[i4 + 0];
    o4.y = dy * rs * w[i4 + 1] + bia[i4 + 1];
    o4.z = dz * rs * w[i4 + 2] + bia[i4 + 2];
    o4.w = dw * rs * w[i4 + 3] + bia[i4 + 3];
    *(float4*)&p[i4] = o4;
}

// ---------------------------------------------------------------------------
extern "C" void kernel_launch(void* const* d_in, const int* in_sizes, int n_in,
                              void* d_out, int out_size, void* d_ws, size_t ws_size,
                              hipStream_t stream) {
    const float* x    = (const float*)d_in[0];
    const float* Wxh  = (const float*)d_in[1];
    const float* Whh  = (const float*)d_in[2];
    const float* ln_w = (const float*)d_in[3];
    const float* ln_b = (const float*)d_in[4];

    const size_t HM = (size_t)HH * HH;
    float* rec  = (float*)d_out;                 // [B,L,H]
    float* outp = rec + (size_t)BB * LL * HH;    // [B,PRED,H]
    float* WT   = (float*)d_ws;                  // M = Whh^T (fp32)
    float* T1   = WT + HM;                       // fp32 temp / Z ping
    float* T2   = T1 + HM;                       // fp32 temp / Z pong

    const long LH = (long)LL * HH;   // b-stride in rec
    const long CH = (long)CC * HH;   // chunk-stride in rec
    const long ZB = (long)HH;        // Z strides (flat [992][H] in T1/T2)
    const long ZC = 32L * HH;
    const long PB = (long)PRED * HH; // b-stride in outp
    float* nul = (float*)nullptr;
    const float* nulc = (const float*)nullptr;

    const size_t need = 3 * HM * sizeof(float) + 2 * (3 * HM * sizeof(short));  // 24 MiB
    if (ws_size >= need) {
        // ===================== MFMA bf16x6 path =====================
        short* SBM = (short*)(T2 + HM);          // splits of M      (3 x [n][k] bf16)
        short* SBP = SBM + 3 * HM;               // splits of powers (volatile)

        transpose_k<<<dim3(HH / 32, HH / 32), dim3(32, 8), 0, stream>>>(Whh, WT);
        gemm_xw<<<dim3(HH / 64, BB * LL / 64), 256, 0, stream>>>(x, Wxh, rec);
        split_t<<<dim3(32, 32), dim3(32, 8), 0, stream>>>(WT, SBM);

        // squaring chain to M^16 (splits end in SBP)
        #define SQ(BS, AF, OF) \
            step_m<<<dim3(16, 32), 128, 0, stream>>>(BS, AF, (long)HH, 32L * HH, \
                OF, (long)HH, 32L * HH, 0, nul, 0, 0)
        SQ(SBM, WT, T1);                                              // T1 = M^2
        split_t<<<dim3(32, 32), dim3(32, 8), 0, stream>>>(T1, SBP);
        SQ(SBP, T1, T2);                                              // T2 = M^4
        split_t<<<dim3(32, 32), dim3(32, 8), 0, stream>>>(T2, SBP);
        SQ(SBP, T2, T1);                                              // T1 = M^8
        split_t<<<dim3(32, 32), dim3(32, 8), 0, stream>>>(T1, SBP);
        SQ(SBP, T1, T2);                                              // T2 = M^16
        split_t<<<dim3(32, 32), dim3(32, 8), 0, stream>>>(T2, SBP);

        // Stage 1: local chunk scans, 15 steps of 1024 rows
        for (int o = 1; o < CC; ++o)
            step_m<<<dim3(16, 32), 128, 0, stream>>>(SBM,
                rec + (size_t)(o - 1) * HH, LH, CH,
                rec + (size_t)o * HH, LH, CH, 1, nul, 0, 0);

        // Stage 2: chunk-boundary carries, 31 tiny steps with M^16 splits
        for (int c = 1; c < NC; ++c)
            step_m<<<dim3(16, 1), 128, 0, stream>>>(SBP,
                rec + (size_t)((c - 1) * CC + CC - 1) * HH, LH, 0,
                rec + (size_t)(c * CC + CC - 1) * HH, LH, 0, 1, nul, 0, 0);

        // Stage 3: carry fix-up, 15 steps of 992 rows (Z ping-pong in T1/T2)
        step_m<<<dim3(16, 31), 128, 0, stream>>>(SBM,
            rec + (size_t)(CC - 1) * HH, LH, CH,
            T1, ZB, ZC, 0,
            rec + (size_t)CC * HH, LH, CH);
        for (int o = 1; o < CC - 1; ++o) {
            float* Zs = (o & 1) ? T1 : T2;
            float* Zd = (o & 1) ? T2 : T1;
            step_m<<<dim3(16, 31), 128, 0, stream>>>(SBM,
                Zs, ZB, ZC,
                Zd, ZB, ZC, 0,
                rec + (size_t)(CC + o) * HH, LH, CH);
        }

        // Prediction via doubling: P1, P2, then P_{k+1..2k} = P_{1..k} @ M^k
        step_m<<<dim3(16, 1), 128, 0, stream>>>(SBM,
            rec + (size_t)(LL - 1) * HH, LH, 0,
            outp, PB, 0, 0, nul, 0, 0);                               // P1
        step_m<<<dim3(16, 1), 128, 0, stream>>>(SBM,
            outp, PB, 0,
            outp + HH, PB, 0, 0, nul, 0, 0);                          // P2
        SQ(SBM, WT, T1);                                              // T1 = M^2
        split_t<<<dim3(32, 32), dim3(32, 8), 0, stream>>>(T1, SBP);
        step_m<<<dim3(16, 2), 128, 0, stream>>>(SBP,
            outp, PB, (long)HH,
            outp + 2 * HH, PB, (long)HH, 0, nul, 0, 0);               // P3:4
        SQ(SBP, T1, T2);                                              // T2 = M^4
        split_t<<<dim3(32, 32), dim3(32, 8), 0, stream>>>(T2, SBP);
        step_m<<<dim3(16, 4), 128, 0, stream>>>(SBP,
            outp, PB, (long)HH,
            outp + 4 * HH, PB, (long)HH, 0, nul, 0, 0);               // P5:8
        SQ(SBP, T2, T1);                                              // T1 = M^8
        split_t<<<dim3(32, 32), dim3(32, 8), 0, stream>>>(T1, SBP);
        step_m<<<dim3(16, 8), 128, 0, stream>>>(SBP,
            outp, PB, (long)HH,
            outp + 8 * HH, PB, (long)HH, 0, nul, 0, 0);               // P9:16
        SQ(SBP, T1, T2);                                              // T2 = M^16
        split_t<<<dim3(32, 32), dim3(32, 8), 0, stream>>>(T2, SBP);
        step_m<<<dim3(16, 16), 128, 0, stream>>>(SBP,
            outp, PB, (long)HH,
            outp + 16 * HH, PB, (long)HH, 0, nul, 0, 0);              // P17:32
        #undef SQ

        ln_k<<<BB * PRED, 256, 0, stream>>>(outp, ln_w, ln_b);
        return;
    }

    // ===================== fp32 fallback path (proven R3) =====================
    transpose_k<<<dim3(HH / 32, HH / 32), dim3(32, 8), 0, stream>>>(Whh, WT);
    gemm_xw<<<dim3(HH / 64, BB * LL / 64), 256, 0, stream>>>(x, Wxh, rec);
    #define POW(SRC, DST) \
        step_k<<<dim3(16, 32), 128, 0, stream>>>(SRC, 32, \
            SRC, (long)HH, 32L * HH, DST, (long)HH, 32L * HH, 0, nul, 0, 0, \
            nulc, 0, 0, nul, 0, 0, 0, nul, 0, 0)
    POW(WT, T1);
    POW(T1, T2);
    POW(T2, T1);
    POW(T1, T2);   // T2 = M^16
    #undef POW
    for (int o = 1; o < CC; ++o)
        step_k<<<dim3(16, 32), 128, 0, stream>>>(WT, 32,
            rec + (size_t)(o - 1) * HH, LH, CH,
            rec + (size_t)o * HH, LH, CH, 1, nul, 0, 0,
            nulc, 0, 0, nul, 0, 0, 0, nul, 0, 0);
    for (int c = 1; c < NC; ++c)
        step_k<<<dim3(16, 1), 128, 0, stream>>>(T2, 1,
            rec + (size_t)((c - 1) * CC + CC - 1) * HH, LH, 0,
            rec + (size_t)(c * CC + CC - 1) * HH, LH, 0, 1, nul, 0, 0,
            nulc, 0, 0, nul, 0, 0, 0, nul, 0, 0);
    step_k<<<dim3(16, 1), 128, 0, stream>>>(WT, 1,
        rec + (size_t)(LL - 1) * HH, LH, 0,
        outp, PB, 0, 0, nul, 0, 0,
        nulc, 0, 0, nul, 0, 0, 0, nul, 0, 0);
    for (int o = 0; o < CC - 1; ++o) {
        const float* Zs; long zsb, zsc;
        if (o == 0) { Zs = rec + (size_t)(CC - 1) * HH; zsb = LH; zsc = CH; }
        else        { Zs = (o & 1) ? T1 : T2; zsb = ZB; zsc = ZC; }
        float* Zd = (o & 1) ? T2 : T1;
        step_k<<<dim3(16, 32), 128, 0, stream>>>(WT, 31,
            Zs, zsb, zsc,
            Zd, ZB, ZC, 0,
            rec + (size_t)(CC + o) * HH, LH, CH,
            outp + (size_t)o * HH, PB, 0,
            outp + (size_t)(o + 1) * HH, PB, 0, 0,
            nul, 0, 0);
    }
    for (int t = CC; t < PRED; ++t)
        step_k<<<dim3(16, 1), 128, 0, stream>>>(WT, 1,
            outp + (size_t)(t - 1) * HH, PB, 0,
            outp + (size_t)t * HH, PB, 0, 0, nul, 0, 0,
            nulc, 0, 0, nul, 0, 0, 0, nul, 0, 0);
    ln_k<<<BB * PRED, 256, 0, stream>>>(outp, ln_w, ln_b);
}

// Round 6
// 2794.487 us; speedup vs baseline: 4.7584x; 1.2788x over previous
//
#include <hip/hip_runtime.h>

#define BB 32
#define LL 512
#define HH 1024
#define PRED 32
#define CC 16            // chunk length
#define NC (LL / CC)     // 32 chunks
#define LN_EPS 1e-5f

typedef short bf16x8 __attribute__((ext_vector_type(8)));
typedef short s16x4  __attribute__((ext_vector_type(4)));
typedef float f32x4  __attribute__((ext_vector_type(4)));

static __device__ __forceinline__ void split3(float x, short& h, short& m, short& l) {
    unsigned u = __float_as_uint(x);
    unsigned rh = (u + 0x7fffu + ((u >> 16) & 1u)) & 0xffff0000u;
    h = (short)(rh >> 16);
    float x1 = x - __uint_as_float(rh);
    unsigned u1 = __float_as_uint(x1);
    unsigned rm = (u1 + 0x7fffu + ((u1 >> 16) & 1u)) & 0xffff0000u;
    m = (short)(rm >> 16);
    float x2 = x1 - __uint_as_float(rm);
    unsigned u2 = __float_as_uint(x2);
    unsigned rl = (u2 + 0x7fffu + ((u2 >> 16) & 1u)) & 0xffff0000u;
    l = (short)(rl >> 16);
}

// ---------------------------------------------------------------------------
// Transpose Whh[k][j] -> out[j][k]  (H x H).  out = M where h_t = u_t + h_{t-1}M
// ---------------------------------------------------------------------------
__global__ __launch_bounds__(256) void transpose_k(const float* __restrict__ in,
                                                   float* __restrict__ out) {
    __shared__ float tile[32][33];
    int bx = blockIdx.x * 32, by = blockIdx.y * 32;
    int tx = threadIdx.x, ty = threadIdx.y;
    #pragma unroll
    for (int i = 0; i < 32; i += 8)
        tile[ty + i][tx] = in[(size_t)(by + ty + i) * HH + bx + tx];
    __syncthreads();
    #pragma unroll
    for (int i = 0; i < 32; i += 8)
        out[(size_t)(bx + ty + i) * HH + by + tx] = tile[tx][ty + i];
}

// ---------------------------------------------------------------------------
// split_a: strided fp32 rows -> A-layout 3-plane bf16 splits [row][k]
// grid (1, nrows), block 256; thread handles 4 contiguous k.
// ---------------------------------------------------------------------------
__global__ __launch_bounds__(256) void split_a(const float* __restrict__ src, long sb, long sc,
                                               short* __restrict__ dst, long dsb, long dsc) {
    const size_t HM = (size_t)HH * HH;
    int r = blockIdx.y;
    const float* s = src + (long)(r & 31) * sb + (long)(r >> 5) * sc + threadIdx.x * 4;
    short* d = dst + (long)(r & 31) * dsb + (long)(r >> 5) * dsc + threadIdx.x * 4;
    float4 v = *(const float4*)s;
    float xs[4] = {v.x, v.y, v.z, v.w};
    s16x4 vh, vm, vl;
    #pragma unroll
    for (int j = 0; j < 4; ++j) {
        short h, m, l;
        split3(xs[j], h, m, l);
        vh[j] = h; vm[j] = m; vl[j] = l;
    }
    *(s16x4*)(d) = vh;
    *(s16x4*)(d + HM) = vm;
    *(s16x4*)(d + 2 * HM) = vl;
}

// ---------------------------------------------------------------------------
// split_t: fp32 P[k][n] -> B-layout 3-plane transposed bf16 splits [n][k]
// ---------------------------------------------------------------------------
__global__ __launch_bounds__(256) void split_t(const float* __restrict__ in,
                                               short* __restrict__ out) {
    const size_t HM = (size_t)HH * HH;
    __shared__ float tile[32][33];
    int n0 = blockIdx.x * 32, k0 = blockIdx.y * 32;
    int tx = threadIdx.x, ty = threadIdx.y;
    #pragma unroll
    for (int i = 0; i < 32; i += 8)
        tile[ty + i][tx] = in[(size_t)(k0 + ty + i) * HH + n0 + tx];
    __syncthreads();
    #pragma unroll
    for (int i = 0; i < 32; i += 8) {
        float v = tile[tx][ty + i];           // k = k0+tx, n = n0+ty+i
        short h, m, l;
        split3(v, h, m, l);
        size_t o = (size_t)(n0 + ty + i) * HH + k0 + tx;
        out[o] = h; out[HM + o] = m; out[2 * HM + o] = l;
    }
}

// ---------------------------------------------------------------------------
// tr_splits: B-layout splits [p][n][k] -> A-layout splits [p][k][n] (transpose)
// grid (32, 32, 3), block (32, 8)
// ---------------------------------------------------------------------------
__global__ __launch_bounds__(256) void tr_splits(const short* __restrict__ in,
                                                 short* __restrict__ out) {
    const size_t HM = (size_t)HH * HH;
    __shared__ short tile[32][33];
    int p = blockIdx.z;
    int k0 = blockIdx.x * 32, n0 = blockIdx.y * 32;
    int tx = threadIdx.x, ty = threadIdx.y;
    #pragma unroll
    for (int i = 0; i < 32; i += 8)
        tile[ty + i][tx] = in[p * HM + (size_t)(n0 + ty + i) * HH + k0 + tx];
    __syncthreads();
    #pragma unroll
    for (int i = 0; i < 32; i += 8)
        out[p * HM + (size_t)(k0 + ty + i) * HH + n0 + tx] = tile[tx][ty + i];
}

// ---------------------------------------------------------------------------
// xw GEMM (fp32):  C[m][n] = sum_k A[m][k] * Bt[n][k]
// ---------------------------------------------------------------------------
__global__ __launch_bounds__(256) void gemm_xw(const float* __restrict__ A,
                                               const float* __restrict__ Bt,
                                               float* __restrict__ C) {
    const int K = HH, N = HH;
    __shared__ float As[16][68];
    __shared__ float Bs[16][68];
    int tid = threadIdx.x;
    int m0 = blockIdx.y * 64, n0 = blockIdx.x * 64;
    int tn = (tid & 15) * 4;
    int tm = (tid >> 4) * 4;
    int lr = tid >> 2;
    int lk = (tid & 3) * 4;
    float acc[4][4] = {};
    const float* Ap = A + (size_t)(m0 + lr) * K + lk;
    const float* Bp = Bt + (size_t)(n0 + lr) * K + lk;
    for (int kt = 0; kt < K; kt += 16) {
        float4 av = *(const float4*)(Ap + kt);
        float4 bv = *(const float4*)(Bp + kt);
        As[lk + 0][lr] = av.x; As[lk + 1][lr] = av.y;
        As[lk + 2][lr] = av.z; As[lk + 3][lr] = av.w;
        Bs[lk + 0][lr] = bv.x; Bs[lk + 1][lr] = bv.y;
        Bs[lk + 2][lr] = bv.z; Bs[lk + 3][lr] = bv.w;
        __syncthreads();
        #pragma unroll
        for (int k = 0; k < 16; ++k) {
            float4 a = *(const float4*)&As[k][tm];
            float4 b = *(const float4*)&Bs[k][tn];
            float ar[4] = {a.x, a.y, a.z, a.w};
            float br[4] = {b.x, b.y, b.z, b.w};
            #pragma unroll
            for (int i = 0; i < 4; ++i)
                #pragma unroll
                for (int j = 0; j < 4; ++j)
                    acc[i][j] = fmaf(ar[i], br[j], acc[i][j]);
        }
        __syncthreads();
    }
    #pragma unroll
    for (int i = 0; i < 4; ++i) {
        float4 o = {acc[i][0], acc[i][1], acc[i][2], acc[i][3]};
        *(float4*)&C[(size_t)(m0 + tm + i) * N + n0 + tn] = o;
    }
}

// ---------------------------------------------------------------------------
// step_p: MFMA bf16x6 GEMM, PRE-SPLIT A and B.
//   acc(r,n) = sum_k A(r)[k] * B[k][n]
//   SA: 3-plane bf16 [row][k], row r -> (r&31)*sab + (r>>5)*sac (shorts)
//   SB: 3-plane bf16 [n][k]
//   O (fp32, optional): = acc (+O if add).   P (fp32, optional): += acc.
//   S (bf16 splits, optional): 3-plane split of final value (post-add).
// Tile 32(M)x64(N), 128 thr (2 waves, 32-col half each), BK=32, reg prefetch.
// ---------------------------------------------------------------------------
__global__ __launch_bounds__(128) void step_p(
    const short* __restrict__ SA, long sab, long sac,
    const short* __restrict__ SB,
    float* __restrict__ O, long sob, long soc, int add,
    float* __restrict__ P, long spb, long spc,
    short* __restrict__ S, long ssb, long ssc) {
    const size_t HM = (size_t)HH * HH;
    __shared__ __align__(16) short As[3][32][40];
    __shared__ __align__(16) short Bs[3][64][40];
    const int tid = threadIdx.x;
    const int lane = tid & 63;
    const int w = tid >> 6;
    const int n0 = blockIdx.x * 64;
    const int m0 = blockIdx.y * 32;
    // A staging: row ar = tid>>2 (0..31), k-chunk (tid&3)*8
    const int ar = tid >> 2;
    const int akc = (tid & 3) * 8;
    const int agr = m0 + ar;
    const short* Arow = SA + (long)(agr & 31) * sab + (long)(agr >> 5) * sac + akc;
    // B staging: n-row = tid&63, k-half = (tid>>6)*16
    const int bnr = tid & 63;
    const int bkh = (tid >> 6) * 16;
    const short* Brow = SB + (size_t)(n0 + bnr) * HH + bkh;
    // fragment read offsets
    const int fr = lane & 15;
    const int fk = (lane >> 4) * 8;

    f32x4 acc00 = 0, acc01 = 0, acc10 = 0, acc11 = 0;

    bf16x8 ra0 = *(const bf16x8*)(Arow);
    bf16x8 ra1 = *(const bf16x8*)(Arow + HM);
    bf16x8 ra2 = *(const bf16x8*)(Arow + 2 * HM);
    bf16x8 rb0 = *(const bf16x8*)(Brow);
    bf16x8 rb1 = *(const bf16x8*)(Brow + 8);
    bf16x8 rb2 = *(const bf16x8*)(Brow + HM);
    bf16x8 rb3 = *(const bf16x8*)(Brow + HM + 8);
    bf16x8 rb4 = *(const bf16x8*)(Brow + 2 * HM);
    bf16x8 rb5 = *(const bf16x8*)(Brow + 2 * HM + 8);

    for (int kt = 0; kt < HH; kt += 32) {
        *(bf16x8*)&As[0][ar][akc] = ra0;
        *(bf16x8*)&As[1][ar][akc] = ra1;
        *(bf16x8*)&As[2][ar][akc] = ra2;
        *(bf16x8*)&Bs[0][bnr][bkh] = rb0;
        *(bf16x8*)&Bs[0][bnr][bkh + 8] = rb1;
        *(bf16x8*)&Bs[1][bnr][bkh] = rb2;
        *(bf16x8*)&Bs[1][bnr][bkh + 8] = rb3;
        *(bf16x8*)&Bs[2][bnr][bkh] = rb4;
        *(bf16x8*)&Bs[2][bnr][bkh + 8] = rb5;
        __syncthreads();
        if (kt + 32 < HH) {
            const short* An = Arow + kt + 32;
            const short* Bn = Brow + kt + 32;
            ra0 = *(const bf16x8*)(An);
            ra1 = *(const bf16x8*)(An + HM);
            ra2 = *(const bf16x8*)(An + 2 * HM);
            rb0 = *(const bf16x8*)(Bn);
            rb1 = *(const bf16x8*)(Bn + 8);
            rb2 = *(const bf16x8*)(Bn + HM);
            rb3 = *(const bf16x8*)(Bn + HM + 8);
            rb4 = *(const bf16x8*)(Bn + 2 * HM);
            rb5 = *(const bf16x8*)(Bn + 2 * HM + 8);
        }
        bf16x8 a00 = *(const bf16x8*)&As[0][fr][fk];
        bf16x8 a01 = *(const bf16x8*)&As[0][16 + fr][fk];
        bf16x8 a10 = *(const bf16x8*)&As[1][fr][fk];
        bf16x8 a11 = *(const bf16x8*)&As[1][16 + fr][fk];
        bf16x8 a20 = *(const bf16x8*)&As[2][fr][fk];
        bf16x8 a21 = *(const bf16x8*)&As[2][16 + fr][fk];
        bf16x8 b00 = *(const bf16x8*)&Bs[0][w * 32 + fr][fk];
        bf16x8 b01 = *(const bf16x8*)&Bs[0][w * 32 + 16 + fr][fk];
        bf16x8 b10 = *(const bf16x8*)&Bs[1][w * 32 + fr][fk];
        bf16x8 b11 = *(const bf16x8*)&Bs[1][w * 32 + 16 + fr][fk];
        bf16x8 b20 = *(const bf16x8*)&Bs[2][w * 32 + fr][fk];
        bf16x8 b21 = *(const bf16x8*)&Bs[2][w * 32 + 16 + fr][fk];
        #define MFMA6(ACC, AH, AM, AL, BH, BM, BL) \
            ACC = __builtin_amdgcn_mfma_f32_16x16x32_bf16(AL, BH, ACC, 0, 0, 0); \
            ACC = __builtin_amdgcn_mfma_f32_16x16x32_bf16(AH, BL, ACC, 0, 0, 0); \
            ACC = __builtin_amdgcn_mfma_f32_16x16x32_bf16(AM, BM, ACC, 0, 0, 0); \
            ACC = __builtin_amdgcn_mfma_f32_16x16x32_bf16(AM, BH, ACC, 0, 0, 0); \
            ACC = __builtin_amdgcn_mfma_f32_16x16x32_bf16(AH, BM, ACC, 0, 0, 0); \
            ACC = __builtin_amdgcn_mfma_f32_16x16x32_bf16(AH, BH, ACC, 0, 0, 0);
        MFMA6(acc00, a00, a10, a20, b00, b10, b20)
        MFMA6(acc01, a00, a10, a20, b01, b11, b21)
        MFMA6(acc10, a01, a11, a21, b00, b10, b20)
        MFMA6(acc11, a01, a11, a21, b01, b11, b21)
        #undef MFMA6
        __syncthreads();
    }
    // epilogue: C/D layout col=lane&15, row=(lane>>4)*4+reg (m89-verified)
    const int orow = (lane >> 4) * 4;
    #pragma unroll
    for (int mf = 0; mf < 2; ++mf) {
        #pragma unroll
        for (int nf = 0; nf < 2; ++nf) {
            f32x4 v = mf == 0 ? (nf == 0 ? acc00 : acc01) : (nf == 0 ? acc10 : acc11);
            int c = n0 + w * 32 + nf * 16 + fr;
            #pragma unroll
            for (int reg = 0; reg < 4; ++reg) {
                int r = m0 + mf * 16 + orow + reg;
                long rb = (long)(r & 31), rc = (long)(r >> 5);
                float val = v[reg];
                if (O) {
                    float* p = O + rb * sob + rc * soc + c;
                    if (add) val += *p;
                    *p = val;
                }
                if (P) {
                    float* q = P + rb * spb + rc * spc + c;
                    *q += val;
                }
                if (S) {
                    short h, m, l;
                    split3(val, h, m, l);
                    short* s = S + rb * ssb + rc * ssc + c;
                    s[0] = h; s[HM] = m; s[2 * HM] = l;
                }
            }
        }
    }
}

// ---------------------------------------------------------------------------
// step_m (R5 fallback): on-the-fly A split, pre-split B.
// ---------------------------------------------------------------------------
__global__ __launch_bounds__(128) void step_m(
    const short* __restrict__ Bsp,
    const float* __restrict__ A, long sab, long sac,
    float* __restrict__ O, long sob, long soc, int add,
    float* __restrict__ P, long spb, long spc) {
    const size_t HM = (size_t)HH * HH;
    __shared__ __align__(16) short As[3][32][40];
    __shared__ __align__(16) short Bs[3][64][40];
    const int tid = threadIdx.x;
    const int lane = tid & 63;
    const int w = tid >> 6;
    const int n0 = blockIdx.x * 64;
    const int m0 = blockIdx.y * 32;
    const int ar = tid >> 2;
    const int akc = (tid & 3) * 8;
    const int agr = m0 + ar;
    const float* Arow = A + (long)(agr & 31) * sab + (long)(agr >> 5) * sac + akc;
    const int bnr = tid & 63;
    const int bkh = (tid >> 6) * 16;
    const size_t bbase = (size_t)(n0 + bnr) * HH + bkh;
    const int fr = lane & 15;
    const int fk = (lane >> 4) * 8;
    f32x4 acc00 = 0, acc01 = 0, acc10 = 0, acc11 = 0;
    for (int kt = 0; kt < HH; kt += 32) {
        float4 av0 = *(const float4*)(Arow + kt);
        float4 av1 = *(const float4*)(Arow + kt + 4);
        float xs[8] = {av0.x, av0.y, av0.z, av0.w, av1.x, av1.y, av1.z, av1.w};
        bf16x8 vh, vm, vl;
        #pragma unroll
        for (int j = 0; j < 8; ++j) {
            short h, m, l;
            split3(xs[j], h, m, l);
            vh[j] = h; vm[j] = m; vl[j] = l;
        }
        *(bf16x8*)&As[0][ar][akc] = vh;
        *(bf16x8*)&As[1][ar][akc] = vm;
        *(bf16x8*)&As[2][ar][akc] = vl;
        #pragma unroll
        for (int s = 0; s < 3; ++s) {
            const short* src = Bsp + s * HM + bbase + kt;
            *(bf16x8*)&Bs[s][bnr][bkh]     = *(const bf16x8*)(src);
            *(bf16x8*)&Bs[s][bnr][bkh + 8] = *(const bf16x8*)(src + 8);
        }
        __syncthreads();
        bf16x8 a00 = *(const bf16x8*)&As[0][fr][fk];
        bf16x8 a01 = *(const bf16x8*)&As[0][16 + fr][fk];
        bf16x8 a10 = *(const bf16x8*)&As[1][fr][fk];
        bf16x8 a11 = *(const bf16x8*)&As[1][16 + fr][fk];
        bf16x8 a20 = *(const bf16x8*)&As[2][fr][fk];
        bf16x8 a21 = *(const bf16x8*)&As[2][16 + fr][fk];
        bf16x8 b00 = *(const bf16x8*)&Bs[0][w * 32 + fr][fk];
        bf16x8 b01 = *(const bf16x8*)&Bs[0][w * 32 + 16 + fr][fk];
        bf16x8 b10 = *(const bf16x8*)&Bs[1][w * 32 + fr][fk];
        bf16x8 b11 = *(const bf16x8*)&Bs[1][w * 32 + 16 + fr][fk];
        bf16x8 b20 = *(const bf16x8*)&Bs[2][w * 32 + fr][fk];
        bf16x8 b21 = *(const bf16x8*)&Bs[2][w * 32 + 16 + fr][fk];
        #define MFMA6(ACC, AH, AM, AL, BH, BM, BL) \
            ACC = __builtin_amdgcn_mfma_f32_16x16x32_bf16(AL, BH, ACC, 0, 0, 0); \
            ACC = __builtin_amdgcn_mfma_f32_16x16x32_bf16(AH, BL, ACC, 0, 0, 0); \
            ACC = __builtin_amdgcn_mfma_f32_16x16x32_bf16(AM, BM, ACC, 0, 0, 0); \
            ACC = __builtin_amdgcn_mfma_f32_16x16x32_bf16(AM, BH, ACC, 0, 0, 0); \
            ACC = __builtin_amdgcn_mfma_f32_16x16x32_bf16(AH, BM, ACC, 0, 0, 0); \
            ACC = __builtin_amdgcn_mfma_f32_16x16x32_bf16(AH, BH, ACC, 0, 0, 0);
        MFMA6(acc00, a00, a10, a20, b00, b10, b20)
        MFMA6(acc01, a00, a10, a20, b01, b11, b21)
        MFMA6(acc10, a01, a11, a21, b00, b10, b20)
        MFMA6(acc11, a01, a11, a21, b01, b11, b21)
        #undef MFMA6
        __syncthreads();
    }
    const int orow = (lane >> 4) * 4;
    #pragma unroll
    for (int mf = 0; mf < 2; ++mf) {
        #pragma unroll
        for (int nf = 0; nf < 2; ++nf) {
            f32x4 v = mf == 0 ? (nf == 0 ? acc00 : acc01) : (nf == 0 ? acc10 : acc11);
            int c = n0 + w * 32 + nf * 16 + fr;
            #pragma unroll
            for (int reg = 0; reg < 4; ++reg) {
                int r = m0 + mf * 16 + orow + reg;
                float* p = O + (long)(r & 31) * sob + (long)(r >> 5) * soc + c;
                float val = v[reg];
                if (add) val += *p;
                *p = val;
                if (P) {
                    float* q = P + (long)(r & 31) * spb + (long)(r >> 5) * spc + c;
                    *q += v[reg];
                }
            }
        }
    }
}

// ---------------------------------------------------------------------------
// LayerNorm in place over last dim H for B*PRED rows.
// ---------------------------------------------------------------------------
__global__ __launch_bounds__(256) void ln_k(float* __restrict__ y,
                                            const float* __restrict__ w,
                                            const float* __restrict__ bia) {
    __shared__ float red[8];
    int row = blockIdx.x;
    float* p = y + (size_t)row * HH;
    int i4 = threadIdx.x * 4;
    float4 v = *(const float4*)&p[i4];
    float s = v.x + v.y + v.z + v.w;
    #pragma unroll
    for (int o = 32; o > 0; o >>= 1) s += __shfl_down(s, o, 64);
    int wid = threadIdx.x >> 6;
    if ((threadIdx.x & 63) == 0) red[wid] = s;
    __syncthreads();
    if (threadIdx.x == 0) red[4] = (red[0] + red[1] + red[2] + red[3]) * (1.f / HH);
    __syncthreads();
    float mu = red[4];
    float dx = v.x - mu, dy = v.y - mu, dz = v.z - mu, dw = v.w - mu;
    float q = dx * dx + dy * dy + dz * dz + dw * dw;
    #pragma unroll
    for (int o = 32; o > 0; o >>= 1) q += __shfl_down(q, o, 64);
    if ((threadIdx.x & 63) == 0) red[wid] = q;
    __syncthreads();
    if (threadIdx.x == 0) red[5] = (red[0] + red[1] + red[2] + red[3]) * (1.f / HH);
    __syncthreads();
    float rs = rsqrtf(red[5] + LN_EPS);
    float4 o4;
    o4.x = dx * rs * w[i4 + 0] + bia[i4 + 0];
    o4.y = dy * rs * w[i4 + 1] + bia[i4 + 1];
    o4.z = dz * rs * w[i4 + 2] + bia[i4 + 2];
    o4.w = dw * rs * w[i4 + 3] + bia[i4 + 3];
    *(float4*)&p[i4] = o4;
}

// ---------------------------------------------------------------------------
extern "C" void kernel_launch(void* const* d_in, const int* in_sizes, int n_in,
                              void* d_out, int out_size, void* d_ws, size_t ws_size,
                              hipStream_t stream) {
    const float* x    = (const float*)d_in[0];
    const float* Wxh  = (const float*)d_in[1];
    const float* Whh  = (const float*)d_in[2];
    const float* ln_w = (const float*)d_in[3];
    const float* ln_b = (const float*)d_in[4];

    const size_t HM = (size_t)HH * HH;
    float* rec  = (float*)d_out;
    float* outp = rec + (size_t)BB * LL * HH;

    const long LH = (long)LL * HH;
    const long CH = (long)CC * HH;
    const long PB = (long)PRED * HH;
    const long RS = (long)HH;        // split row stride (shorts)
    const long RC = 32L * HH;        // split chunk stride (shorts)
    float* nulf = (float*)nullptr;
    short* nuls = (short*)nullptr;

    if (ws_size >= (size_t)34 * 1024 * 1024) {
        // ===================== pre-split MFMA path =====================
        char* wsb = (char*)d_ws;
        float* TP   = (float*)(wsb);                          // 4 MiB fp32 power
        short* SA_P = (short*)(wsb + (size_t)4  * 1024 * 1024);  // 6 MiB A-splits
        short* SA0  = (short*)(wsb + (size_t)10 * 1024 * 1024);  // 6 MiB
        short* SA1  = (short*)(wsb + (size_t)16 * 1024 * 1024);  // 6 MiB
        short* SB_M = (short*)(wsb + (size_t)22 * 1024 * 1024);  // 6 MiB B-splits of M
        short* SB_P = (short*)(wsb + (size_t)28 * 1024 * 1024);  // 6 MiB B-splits (power)

        #define STEP(SAx, sab, sac, SBx, Ox, sob, soc, addx, Px, spb, spc, Sx, ssb, ssc, MG) \
            step_p<<<dim3(16, MG), 128, 0, stream>>>(SAx, sab, sac, SBx, \
                Ox, sob, soc, addx, Px, spb, spc, Sx, ssb, ssc)

        // M = Whh^T -> TP ; splits of M
        transpose_k<<<dim3(HH / 32, HH / 32), dim3(32, 8), 0, stream>>>(Whh, TP);
        gemm_xw<<<dim3(HH / 64, BB * LL / 64), 256, 0, stream>>>(x, Wxh, rec);
        split_a<<<dim3(1, HH), 256, 0, stream>>>(TP, (long)HH, 32L * HH, SA_P, RS, RC);
        split_t<<<dim3(32, 32), dim3(32, 8), 0, stream>>>(TP, SB_M);

        // chain1: M^2, M^4, M^8, M^16  (SB_P ends = M^16)
        STEP(SA_P, RS, RC, SB_M, TP, (long)HH, 32L * HH, 0, nulf, 0, 0, SA0, RS, RC, 32);
        split_t<<<dim3(32, 32), dim3(32, 8), 0, stream>>>(TP, SB_P);
        STEP(SA0, RS, RC, SB_P, TP, (long)HH, 32L * HH, 0, nulf, 0, 0, SA_P, RS, RC, 32);
        split_t<<<dim3(32, 32), dim3(32, 8), 0, stream>>>(TP, SB_P);
        STEP(SA_P, RS, RC, SB_P, TP, (long)HH, 32L * HH, 0, nulf, 0, 0, SA0, RS, RC, 32);
        split_t<<<dim3(32, 32), dim3(32, 8), 0, stream>>>(TP, SB_P);
        STEP(SA0, RS, RC, SB_P, TP, (long)HH, 32L * HH, 0, nulf, 0, 0, nuls, 0, 0, 32);
        split_t<<<dim3(32, 32), dim3(32, 8), 0, stream>>>(TP, SB_P);   // SB_P = M^16

        // stage1 seed: splits of xw offset-0 rows -> SA0
        split_a<<<dim3(1, HH), 256, 0, stream>>>(rec, LH, CH, SA0, RS, RC);

        // stage1: 15 steps of 1024 rows, splits chained SA0<->SA1
        for (int o = 1; o < CC; ++o) {
            short* Ain = (o & 1) ? SA0 : SA1;
            short* Sot = (o & 1) ? SA1 : SA0;
            STEP(Ain, RS, RC, SB_M,
                 rec + (size_t)o * HH, LH, CH, 1, nulf, 0, 0,
                 Sot, RS, RC, 32);
        }

        // stage2: 31 sequential carries with M^16, splits in-place in SA1
        for (int c = 1; c < NC; ++c)
            STEP(SA1 + (size_t)(c - 1) * 32 * HH, RS, 0, SB_P,
                 rec + ((size_t)c * CC + CC - 1) * HH, LH, 0, 1, nulf, 0, 0,
                 SA1 + (size_t)c * 32 * HH, RS, 0, 1);

        // stage3: Z-chain, 15 steps of 992 rows; Z_o ping-pongs SA1<->SA0
        for (int o = 0; o < CC - 1; ++o) {
            short* Ain = (o & 1) ? SA0 : SA1;
            short* Sot = (o & 1) ? SA1 : SA0;
            STEP(Ain, RS, RC, SB_M,
                 nulf, 0, 0, 0,
                 rec + (size_t)(CC + o) * HH, LH, CH,
                 (o == CC - 2) ? nuls : Sot, RS, RC, 31);
        }

        // pred P1 (from chunk-31 end splits, preserved rows 992..1023 of SA1)
        STEP(SA1 + (size_t)992 * HH, RS, 0, SB_M,
             outp, PB, 0, 0, nulf, 0, 0,
             SA0, RS, 0, 1);
        // P2
        STEP(SA0, RS, 0, SB_M,
             outp + HH, PB, 0, 0, nulf, 0, 0,
             SA0 + (size_t)32 * HH, RS, 0, 1);
        // chain2 seed: A-splits of M from SB_M (transpose)
        tr_splits<<<dim3(32, 32, 3), dim3(32, 8), 0, stream>>>(SB_M, SA_P);
        // M^2
        STEP(SA_P, RS, RC, SB_M, TP, (long)HH, 32L * HH, 0, nulf, 0, 0, SA1, RS, RC, 32);
        split_t<<<dim3(32, 32), dim3(32, 8), 0, stream>>>(TP, SB_P);
        // P3:4
        STEP(SA0, RS, RC, SB_P,
             outp + 2 * HH, PB, (long)HH, 0, nulf, 0, 0,
             SA0 + (size_t)2 * 32 * HH, RS, RC, 2);
        // M^4
        STEP(SA1, RS, RC, SB_P, TP, (long)HH, 32L * HH, 0, nulf, 0, 0, SA_P, RS, RC, 32);
        split_t<<<dim3(32, 32), dim3(32, 8), 0, stream>>>(TP, SB_P);
        // P5:8
        STEP(SA0, RS, RC, SB_P,
             outp + 4 * HH, PB, (long)HH, 0, nulf, 0, 0,
             SA0 + (size_t)4 * 32 * HH, RS, RC, 4);
        // M^8
        STEP(SA_P, RS, RC, SB_P, TP, (long)HH, 32L * HH, 0, nulf, 0, 0, SA1, RS, RC, 32);
        split_t<<<dim3(32, 32), dim3(32, 8), 0, stream>>>(TP, SB_P);
        // P9:16
        STEP(SA0, RS, RC, SB_P,
             outp + 8 * HH, PB, (long)HH, 0, nulf, 0, 0,
             SA0 + (size_t)8 * 32 * HH, RS, RC, 8);
        // M^16
        STEP(SA1, RS, RC, SB_P, TP, (long)HH, 32L * HH, 0, nulf, 0, 0, nuls, 0, 0, 32);
        split_t<<<dim3(32, 32), dim3(32, 8), 0, stream>>>(TP, SB_P);
        // P17:32
        STEP(SA0, RS, RC, SB_P,
             outp + 16 * HH, PB, (long)HH, 0, nulf, 0, 0,
             nuls, 0, 0, 16);
        #undef STEP

        ln_k<<<BB * PRED, 256, 0, stream>>>(outp, ln_w, ln_b);
        return;
    }

    // ===================== R5 fallback (on-the-fly A split, 24 MiB) ==========
    {
        float* WT = (float*)d_ws;
        float* T1 = WT + HM;
        float* T2 = T1 + HM;
        short* SBM = (short*)(T2 + HM);
        short* SBP = SBM + 3 * HM;
        const long ZB = (long)HH;
        const long ZC = 32L * HH;

        transpose_k<<<dim3(HH / 32, HH / 32), dim3(32, 8), 0, stream>>>(Whh, WT);
        gemm_xw<<<dim3(HH / 64, BB * LL / 64), 256, 0, stream>>>(x, Wxh, rec);
        split_t<<<dim3(32, 32), dim3(32, 8), 0, stream>>>(WT, SBM);
        #define SQ(BS, AF, OF) \
            step_m<<<dim3(16, 32), 128, 0, stream>>>(BS, AF, (long)HH, 32L * HH, \
                OF, (long)HH, 32L * HH, 0, nulf, 0, 0)
        SQ(SBM, WT, T1);
        split_t<<<dim3(32, 32), dim3(32, 8), 0, stream>>>(T1, SBP);
        SQ(SBP, T1, T2);
        split_t<<<dim3(32, 32), dim3(32, 8), 0, stream>>>(T2, SBP);
        SQ(SBP, T2, T1);
        split_t<<<dim3(32, 32), dim3(32, 8), 0, stream>>>(T1, SBP);
        SQ(SBP, T1, T2);
        split_t<<<dim3(32, 32), dim3(32, 8), 0, stream>>>(T2, SBP);
        for (int o = 1; o < CC; ++o)
            step_m<<<dim3(16, 32), 128, 0, stream>>>(SBM,
                rec + (size_t)(o - 1) * HH, LH, CH,
                rec + (size_t)o * HH, LH, CH, 1, nulf, 0, 0);
        for (int c = 1; c < NC; ++c)
            step_m<<<dim3(16, 1), 128, 0, stream>>>(SBP,
                rec + (size_t)((c - 1) * CC + CC - 1) * HH, LH, 0,
                rec + (size_t)(c * CC + CC - 1) * HH, LH, 0, 1, nulf, 0, 0);
        step_m<<<dim3(16, 31), 128, 0, stream>>>(SBM,
            rec + (size_t)(CC - 1) * HH, LH, CH,
            T1, ZB, ZC, 0,
            rec + (size_t)CC * HH, LH, CH);
        for (int o = 1; o < CC - 1; ++o) {
            float* Zs = (o & 1) ? T1 : T2;
            float* Zd = (o & 1) ? T2 : T1;
            step_m<<<dim3(16, 31), 128, 0, stream>>>(SBM,
                Zs, ZB, ZC, Zd, ZB, ZC, 0,
                rec + (size_t)(CC + o) * HH, LH, CH);
        }
        step_m<<<dim3(16, 1), 128, 0, stream>>>(SBM,
            rec + (size_t)(LL - 1) * HH, LH, 0,
            outp, PB, 0, 0, nulf, 0, 0);
        step_m<<<dim3(16, 1), 128, 0, stream>>>(SBM,
            outp, PB, 0, outp + HH, PB, 0, 0, nulf, 0, 0);
        SQ(SBM, WT, T1);
        split_t<<<dim3(32, 32), dim3(32, 8), 0, stream>>>(T1, SBP);
        step_m<<<dim3(16, 2), 128, 0, stream>>>(SBP,
            outp, PB, (long)HH, outp + 2 * HH, PB, (long)HH, 0, nulf, 0, 0);
        SQ(SBP, T1, T2);
        split_t<<<dim3(32, 32), dim3(32, 8), 0, stream>>>(T2, SBP);
        step_m<<<dim3(16, 4), 128, 0, stream>>>(SBP,
            outp, PB, (long)HH, outp + 4 * HH, PB, (long)HH, 0, nulf, 0, 0);
        SQ(SBP, T2, T1);
        split_t<<<dim3(32, 32), dim3(32, 8), 0, stream>>>(T1, SBP);
        step_m<<<dim3(16, 8), 128, 0, stream>>>(SBP,
            outp, PB, (long)HH, outp + 8 * HH, PB, (long)HH, 0, nulf, 0, 0);
        SQ(SBP, T1, T2);
        split_t<<<dim3(32, 32), dim3(32, 8), 0, stream>>>(T2, SBP);
        step_m<<<dim3(16, 16), 128, 0, stream>>>(SBP,
            outp, PB, (long)HH, outp + 16 * HH, PB, (long)HH, 0, nulf, 0, 0);
        #undef SQ
        ln_k<<<BB * PRED, 256, 0, stream>>>(outp, ln_w, ln_b);
    }
}

// Round 7
// 2208.871 us; speedup vs baseline: 6.0200x; 1.2651x over previous
//
#include <hip/hip_runtime.h>

#define BB 32
#define LL 512
#define HH 1024
#define PRED 32
#define CC 16            // chunk length
#define NC (LL / CC)     // 32 chunks
#define LN_EPS 1e-5f

typedef short bf16x8 __attribute__((ext_vector_type(8)));
typedef short s16x4  __attribute__((ext_vector_type(4)));
typedef float f32x4  __attribute__((ext_vector_type(4)));

static __device__ __forceinline__ void split3(float x, short& h, short& m, short& l) {
    unsigned u = __float_as_uint(x);
    unsigned rh = (u + 0x7fffu + ((u >> 16) & 1u)) & 0xffff0000u;
    h = (short)(rh >> 16);
    float x1 = x - __uint_as_float(rh);
    unsigned u1 = __float_as_uint(x1);
    unsigned rm = (u1 + 0x7fffu + ((u1 >> 16) & 1u)) & 0xffff0000u;
    m = (short)(rm >> 16);
    float x2 = x1 - __uint_as_float(rm);
    unsigned u2 = __float_as_uint(x2);
    unsigned rl = (u2 + 0x7fffu + ((u2 >> 16) & 1u)) & 0xffff0000u;
    l = (short)(rl >> 16);
}

static __device__ __forceinline__ void split2(float x, short& h, short& m) {
    unsigned u = __float_as_uint(x);
    unsigned rh = (u + 0x7fffu + ((u >> 16) & 1u)) & 0xffff0000u;
    h = (short)(rh >> 16);
    float x1 = x - __uint_as_float(rh);
    unsigned u1 = __float_as_uint(x1);
    unsigned rm = (u1 + 0x7fffu + ((u1 >> 16) & 1u)) & 0xffff0000u;
    m = (short)(rm >> 16);
}

// ---------------------------------------------------------------------------
// Transpose Whh[k][j] -> out[j][k]  (H x H).
// ---------------------------------------------------------------------------
__global__ __launch_bounds__(256) void transpose_k(const float* __restrict__ in,
                                                   float* __restrict__ out) {
    __shared__ float tile[32][33];
    int bx = blockIdx.x * 32, by = blockIdx.y * 32;
    int tx = threadIdx.x, ty = threadIdx.y;
    #pragma unroll
    for (int i = 0; i < 32; i += 8)
        tile[ty + i][tx] = in[(size_t)(by + ty + i) * HH + bx + tx];
    __syncthreads();
    #pragma unroll
    for (int i = 0; i < 32; i += 8)
        out[(size_t)(bx + ty + i) * HH + by + tx] = tile[tx][ty + i];
}

// ---------------------------------------------------------------------------
// split_a: strided fp32 rows -> 3-plane bf16 splits [row][k]
// ---------------------------------------------------------------------------
__global__ __launch_bounds__(256) void split_a(const float* __restrict__ src, long sb, long sc,
                                               short* __restrict__ dst, long dsb, long dsc) {
    const size_t HM = (size_t)HH * HH;
    int r = blockIdx.y;
    const float* s = src + (long)(r & 31) * sb + (long)(r >> 5) * sc + threadIdx.x * 4;
    short* d = dst + (long)(r & 31) * dsb + (long)(r >> 5) * dsc + threadIdx.x * 4;
    float4 v = *(const float4*)s;
    float xs[4] = {v.x, v.y, v.z, v.w};
    s16x4 vh, vm, vl;
    #pragma unroll
    for (int j = 0; j < 4; ++j) {
        short h, m, l;
        split3(xs[j], h, m, l);
        vh[j] = h; vm[j] = m; vl[j] = l;
    }
    *(s16x4*)(d) = vh;
    *(s16x4*)(d + HM) = vm;
    *(s16x4*)(d + 2 * HM) = vl;
}

// ---------------------------------------------------------------------------
// split_t: fp32 P[k][n] -> B-layout 3-plane transposed bf16 splits [n][k]
// ---------------------------------------------------------------------------
__global__ __launch_bounds__(256) void split_t(const float* __restrict__ in,
                                               short* __restrict__ out) {
    const size_t HM = (size_t)HH * HH;
    __shared__ float tile[32][33];
    int n0 = blockIdx.x * 32, k0 = blockIdx.y * 32;
    int tx = threadIdx.x, ty = threadIdx.y;
    #pragma unroll
    for (int i = 0; i < 32; i += 8)
        tile[ty + i][tx] = in[(size_t)(k0 + ty + i) * HH + n0 + tx];
    __syncthreads();
    #pragma unroll
    for (int i = 0; i < 32; i += 8) {
        float v = tile[tx][ty + i];
        short h, m, l;
        split3(v, h, m, l);
        size_t o = (size_t)(n0 + ty + i) * HH + k0 + tx;
        out[o] = h; out[HM + o] = m; out[2 * HM + o] = l;
    }
}

// ---------------------------------------------------------------------------
// tr_splits: B-layout splits [p][n][k] -> A-layout splits [p][k][n]
// ---------------------------------------------------------------------------
__global__ __launch_bounds__(256) void tr_splits(const short* __restrict__ in,
                                                 short* __restrict__ out) {
    const size_t HM = (size_t)HH * HH;
    __shared__ short tile[32][33];
    int p = blockIdx.z;
    int k0 = blockIdx.x * 32, n0 = blockIdx.y * 32;
    int tx = threadIdx.x, ty = threadIdx.y;
    #pragma unroll
    for (int i = 0; i < 32; i += 8)
        tile[ty + i][tx] = in[p * HM + (size_t)(n0 + ty + i) * HH + k0 + tx];
    __syncthreads();
    #pragma unroll
    for (int i = 0; i < 32; i += 8)
        out[p * HM + (size_t)(k0 + ty + i) * HH + n0 + tx] = tile[tx][ty + i];
}

// ---------------------------------------------------------------------------
// gemm_mx: C[m][n] = sum_k x[m][k] * W[n][k]  via MFMA bf16 2x2 split (4 pass).
//   x fp32 (split 2-way on the fly), SB = 3-plane pre-split of W rows (uses
//   planes 0,1).  Tile 128(M)x64(N), 256 thr (4 waves, 32 rows each), BK=32.
// ---------------------------------------------------------------------------
__global__ __launch_bounds__(256) void gemm_mx(const float* __restrict__ A,
                                               const short* __restrict__ SB,
                                               float* __restrict__ C) {
    const size_t HM = (size_t)HH * HH;
    __shared__ __align__(16) short As2[2][128][40];
    __shared__ __align__(16) short Bs2[2][64][40];
    const int tid = threadIdx.x;
    const int lane = tid & 63;
    const int w = tid >> 6;
    const int n0 = blockIdx.x * 64;
    const int m0 = blockIdx.y * 128;
    // A staging: row ar=tid>>1 (0..127), k-chunk (tid&1)*16 (16 floats/thread)
    const int ar = tid >> 1;
    const int akc = (tid & 1) * 16;
    const float* Arow = A + (size_t)(m0 + ar) * HH + akc;
    // B staging: plane bp=tid>>7, n-row bnr=tid&63, k-half ((tid>>6)&1)*16
    const int bp = tid >> 7;
    const int bnr = tid & 63;
    const int bkh = ((tid >> 6) & 1) * 16;
    const short* Brow = SB + bp * HM + (size_t)(n0 + bnr) * HH + bkh;
    const int fr = lane & 15;
    const int fk = (lane >> 4) * 8;

    f32x4 acc[2][4] = {};

    float4 av0 = *(const float4*)(Arow);
    float4 av1 = *(const float4*)(Arow + 4);
    float4 av2 = *(const float4*)(Arow + 8);
    float4 av3 = *(const float4*)(Arow + 12);
    bf16x8 rb0 = *(const bf16x8*)(Brow);
    bf16x8 rb1 = *(const bf16x8*)(Brow + 8);

    for (int kt = 0; kt < HH; kt += 32) {
        float xs[16] = {av0.x, av0.y, av0.z, av0.w, av1.x, av1.y, av1.z, av1.w,
                        av2.x, av2.y, av2.z, av2.w, av3.x, av3.y, av3.z, av3.w};
        bf16x8 vh0, vm0, vh1, vm1;
        #pragma unroll
        for (int j = 0; j < 8; ++j) {
            short h, m;
            split2(xs[j], h, m);
            vh0[j] = h; vm0[j] = m;
            split2(xs[j + 8], h, m);
            vh1[j] = h; vm1[j] = m;
        }
        *(bf16x8*)&As2[0][ar][akc]     = vh0;
        *(bf16x8*)&As2[0][ar][akc + 8] = vh1;
        *(bf16x8*)&As2[1][ar][akc]     = vm0;
        *(bf16x8*)&As2[1][ar][akc + 8] = vm1;
        *(bf16x8*)&Bs2[bp][bnr][bkh]     = rb0;
        *(bf16x8*)&Bs2[bp][bnr][bkh + 8] = rb1;
        __syncthreads();
        if (kt + 32 < HH) {
            const float* An = Arow + kt + 32;
            av0 = *(const float4*)(An);
            av1 = *(const float4*)(An + 4);
            av2 = *(const float4*)(An + 8);
            av3 = *(const float4*)(An + 12);
            const short* Bn = Brow + kt + 32;
            rb0 = *(const bf16x8*)(Bn);
            rb1 = *(const bf16x8*)(Bn + 8);
        }
        bf16x8 ah[2], am[2];
        #pragma unroll
        for (int i = 0; i < 2; ++i) {
            ah[i] = *(const bf16x8*)&As2[0][w * 32 + i * 16 + fr][fk];
            am[i] = *(const bf16x8*)&As2[1][w * 32 + i * 16 + fr][fk];
        }
        #pragma unroll
        for (int j = 0; j < 4; ++j) {
            bf16x8 bh = *(const bf16x8*)&Bs2[0][j * 16 + fr][fk];
            bf16x8 bm = *(const bf16x8*)&Bs2[1][j * 16 + fr][fk];
            #pragma unroll
            for (int i = 0; i < 2; ++i) {
                f32x4 a = acc[i][j];
                a = __builtin_amdgcn_mfma_f32_16x16x32_bf16(am[i], bm, a, 0, 0, 0);
                a = __builtin_amdgcn_mfma_f32_16x16x32_bf16(am[i], bh, a, 0, 0, 0);
                a = __builtin_amdgcn_mfma_f32_16x16x32_bf16(ah[i], bm, a, 0, 0, 0);
                a = __builtin_amdgcn_mfma_f32_16x16x32_bf16(ah[i], bh, a, 0, 0, 0);
                acc[i][j] = a;
            }
        }
        __syncthreads();
    }
    const int orow = (lane >> 4) * 4;
    #pragma unroll
    for (int i = 0; i < 2; ++i)
        #pragma unroll
        for (int j = 0; j < 4; ++j) {
            int c = n0 + j * 16 + fr;
            #pragma unroll
            for (int reg = 0; reg < 4; ++reg) {
                int r = m0 + w * 32 + i * 16 + orow + reg;
                C[(size_t)r * HH + c] = acc[i][j][reg];
            }
        }
}

// ---------------------------------------------------------------------------
// step_p: MFMA bf16x6, pre-split A and B. 32(M)x64(N), 128 thr. (R6-proven)
// ---------------------------------------------------------------------------
__global__ __launch_bounds__(128) void step_p(
    const short* __restrict__ SA, long sab, long sac,
    const short* __restrict__ SB,
    float* __restrict__ O, long sob, long soc, int add,
    float* __restrict__ P, long spb, long spc,
    short* __restrict__ S, long ssb, long ssc) {
    const size_t HM = (size_t)HH * HH;
    __shared__ __align__(16) short As[3][32][40];
    __shared__ __align__(16) short Bs[3][64][40];
    const int tid = threadIdx.x;
    const int lane = tid & 63;
    const int w = tid >> 6;
    const int n0 = blockIdx.x * 64;
    const int m0 = blockIdx.y * 32;
    const int ar = tid >> 2;
    const int akc = (tid & 3) * 8;
    const int agr = m0 + ar;
    const short* Arow = SA + (long)(agr & 31) * sab + (long)(agr >> 5) * sac + akc;
    const int bnr = tid & 63;
    const int bkh = (tid >> 6) * 16;
    const short* Brow = SB + (size_t)(n0 + bnr) * HH + bkh;
    const int fr = lane & 15;
    const int fk = (lane >> 4) * 8;

    f32x4 acc00 = 0, acc01 = 0, acc10 = 0, acc11 = 0;

    bf16x8 ra0 = *(const bf16x8*)(Arow);
    bf16x8 ra1 = *(const bf16x8*)(Arow + HM);
    bf16x8 ra2 = *(const bf16x8*)(Arow + 2 * HM);
    bf16x8 rb0 = *(const bf16x8*)(Brow);
    bf16x8 rb1 = *(const bf16x8*)(Brow + 8);
    bf16x8 rb2 = *(const bf16x8*)(Brow + HM);
    bf16x8 rb3 = *(const bf16x8*)(Brow + HM + 8);
    bf16x8 rb4 = *(const bf16x8*)(Brow + 2 * HM);
    bf16x8 rb5 = *(const bf16x8*)(Brow + 2 * HM + 8);

    for (int kt = 0; kt < HH; kt += 32) {
        *(bf16x8*)&As[0][ar][akc] = ra0;
        *(bf16x8*)&As[1][ar][akc] = ra1;
        *(bf16x8*)&As[2][ar][akc] = ra2;
        *(bf16x8*)&Bs[0][bnr][bkh] = rb0;
        *(bf16x8*)&Bs[0][bnr][bkh + 8] = rb1;
        *(bf16x8*)&Bs[1][bnr][bkh] = rb2;
        *(bf16x8*)&Bs[1][bnr][bkh + 8] = rb3;
        *(bf16x8*)&Bs[2][bnr][bkh] = rb4;
        *(bf16x8*)&Bs[2][bnr][bkh + 8] = rb5;
        __syncthreads();
        if (kt + 32 < HH) {
            const short* An = Arow + kt + 32;
            const short* Bn = Brow + kt + 32;
            ra0 = *(const bf16x8*)(An);
            ra1 = *(const bf16x8*)(An + HM);
            ra2 = *(const bf16x8*)(An + 2 * HM);
            rb0 = *(const bf16x8*)(Bn);
            rb1 = *(const bf16x8*)(Bn + 8);
            rb2 = *(const bf16x8*)(Bn + HM);
            rb3 = *(const bf16x8*)(Bn + HM + 8);
            rb4 = *(const bf16x8*)(Bn + 2 * HM);
            rb5 = *(const bf16x8*)(Bn + 2 * HM + 8);
        }
        bf16x8 a00 = *(const bf16x8*)&As[0][fr][fk];
        bf16x8 a01 = *(const bf16x8*)&As[0][16 + fr][fk];
        bf16x8 a10 = *(const bf16x8*)&As[1][fr][fk];
        bf16x8 a11 = *(const bf16x8*)&As[1][16 + fr][fk];
        bf16x8 a20 = *(const bf16x8*)&As[2][fr][fk];
        bf16x8 a21 = *(const bf16x8*)&As[2][16 + fr][fk];
        bf16x8 b00 = *(const bf16x8*)&Bs[0][w * 32 + fr][fk];
        bf16x8 b01 = *(const bf16x8*)&Bs[0][w * 32 + 16 + fr][fk];
        bf16x8 b10 = *(const bf16x8*)&Bs[1][w * 32 + fr][fk];
        bf16x8 b11 = *(const bf16x8*)&Bs[1][w * 32 + 16 + fr][fk];
        bf16x8 b20 = *(const bf16x8*)&Bs[2][w * 32 + fr][fk];
        bf16x8 b21 = *(const bf16x8*)&Bs[2][w * 32 + 16 + fr][fk];
        #define MFMA6(ACC, AH, AM, AL, BH, BM, BL) \
            ACC = __builtin_amdgcn_mfma_f32_16x16x32_bf16(AL, BH, ACC, 0, 0, 0); \
            ACC = __builtin_amdgcn_mfma_f32_16x16x32_bf16(AH, BL, ACC, 0, 0, 0); \
            ACC = __builtin_amdgcn_mfma_f32_16x16x32_bf16(AM, BM, ACC, 0, 0, 0); \
            ACC = __builtin_amdgcn_mfma_f32_16x16x32_bf16(AM, BH, ACC, 0, 0, 0); \
            ACC = __builtin_amdgcn_mfma_f32_16x16x32_bf16(AH, BM, ACC, 0, 0, 0); \
            ACC = __builtin_amdgcn_mfma_f32_16x16x32_bf16(AH, BH, ACC, 0, 0, 0);
        MFMA6(acc00, a00, a10, a20, b00, b10, b20)
        MFMA6(acc01, a00, a10, a20, b01, b11, b21)
        MFMA6(acc10, a01, a11, a21, b00, b10, b20)
        MFMA6(acc11, a01, a11, a21, b01, b11, b21)
        __syncthreads();
    }
    const int orow = (lane >> 4) * 4;
    #pragma unroll
    for (int mf = 0; mf < 2; ++mf) {
        #pragma unroll
        for (int nf = 0; nf < 2; ++nf) {
            f32x4 v = mf == 0 ? (nf == 0 ? acc00 : acc01) : (nf == 0 ? acc10 : acc11);
            int c = n0 + w * 32 + nf * 16 + fr;
            #pragma unroll
            for (int reg = 0; reg < 4; ++reg) {
                int r = m0 + mf * 16 + orow + reg;
                long rb = (long)(r & 31), rc = (long)(r >> 5);
                float val = v[reg];
                if (O) {
                    float* p = O + rb * sob + rc * soc + c;
                    if (add) val += *p;
                    *p = val;
                }
                if (P) {
                    float* q = P + rb * spb + rc * spc + c;
                    *q += val;
                }
                if (S) {
                    short h, m, l;
                    split3(val, h, m, l);
                    short* s = S + rb * ssb + rc * ssc + c;
                    s[0] = h; s[HM] = m; s[2 * HM] = l;
                }
            }
        }
    }
}

// ---------------------------------------------------------------------------
// step_p64: MFMA bf16x6, pre-split A and B. 64(M)x64(N), 256 thr (4 waves,
// 2x2 wave grid of 32x32 subtiles). Row guard: stores only for r < nrows.
// ---------------------------------------------------------------------------
__global__ __launch_bounds__(256) void step_p64(
    const short* __restrict__ SA, long sab, long sac,
    const short* __restrict__ SB,
    float* __restrict__ O, long sob, long soc, int add,
    float* __restrict__ P, long spb, long spc,
    short* __restrict__ S, long ssb, long ssc,
    int nrows) {
    const size_t HM = (size_t)HH * HH;
    __shared__ __align__(16) short As[3][64][40];
    __shared__ __align__(16) short Bs[3][64][40];
    const int tid = threadIdx.x;
    const int lane = tid & 63;
    const int w = tid >> 6;
    const int wr = w & 1;        // row-group of wave
    const int wc = w >> 1;       // col-group of wave
    const int n0 = blockIdx.x * 64;
    const int m0 = blockIdx.y * 64;
    // A staging: row ar=tid>>2 (0..63), k-chunk (tid&3)*8
    const int ar = tid >> 2;
    const int akc = (tid & 3) * 8;
    const int agr = m0 + ar;
    const short* Arow = SA + (long)(agr & 31) * sab + (long)(agr >> 5) * sac + akc;
    // B staging: same pattern
    const short* Brow = SB + (size_t)(n0 + ar) * HH + akc;
    const int fr = lane & 15;
    const int fk = (lane >> 4) * 8;

    f32x4 acc00 = 0, acc01 = 0, acc10 = 0, acc11 = 0;

    bf16x8 ra0 = *(const bf16x8*)(Arow);
    bf16x8 ra1 = *(const bf16x8*)(Arow + HM);
    bf16x8 ra2 = *(const bf16x8*)(Arow + 2 * HM);
    bf16x8 rb0 = *(const bf16x8*)(Brow);
    bf16x8 rb1 = *(const bf16x8*)(Brow + HM);
    bf16x8 rb2 = *(const bf16x8*)(Brow + 2 * HM);

    for (int kt = 0; kt < HH; kt += 32) {
        *(bf16x8*)&As[0][ar][akc] = ra0;
        *(bf16x8*)&As[1][ar][akc] = ra1;
        *(bf16x8*)&As[2][ar][akc] = ra2;
        *(bf16x8*)&Bs[0][ar][akc] = rb0;
        *(bf16x8*)&Bs[1][ar][akc] = rb1;
        *(bf16x8*)&Bs[2][ar][akc] = rb2;
        __syncthreads();
        if (kt + 32 < HH) {
            const short* An = Arow + kt + 32;
            const short* Bn = Brow + kt + 32;
            ra0 = *(const bf16x8*)(An);
            ra1 = *(const bf16x8*)(An + HM);
            ra2 = *(const bf16x8*)(An + 2 * HM);
            rb0 = *(const bf16x8*)(Bn);
            rb1 = *(const bf16x8*)(Bn + HM);
            rb2 = *(const bf16x8*)(Bn + 2 * HM);
        }
        bf16x8 a00 = *(const bf16x8*)&As[0][wr * 32 + fr][fk];
        bf16x8 a01 = *(const bf16x8*)&As[0][wr * 32 + 16 + fr][fk];
        bf16x8 a10 = *(const bf16x8*)&As[1][wr * 32 + fr][fk];
        bf16x8 a11 = *(const bf16x8*)&As[1][wr * 32 + 16 + fr][fk];
        bf16x8 a20 = *(const bf16x8*)&As[2][wr * 32 + fr][fk];
        bf16x8 a21 = *(const bf16x8*)&As[2][wr * 32 + 16 + fr][fk];
        bf16x8 b00 = *(const bf16x8*)&Bs[0][wc * 32 + fr][fk];
        bf16x8 b01 = *(const bf16x8*)&Bs[0][wc * 32 + 16 + fr][fk];
        bf16x8 b10 = *(const bf16x8*)&Bs[1][wc * 32 + fr][fk];
        bf16x8 b11 = *(const bf16x8*)&Bs[1][wc * 32 + 16 + fr][fk];
        bf16x8 b20 = *(const bf16x8*)&Bs[2][wc * 32 + fr][fk];
        bf16x8 b21 = *(const bf16x8*)&Bs[2][wc * 32 + 16 + fr][fk];
        MFMA6(acc00, a00, a10, a20, b00, b10, b20)
        MFMA6(acc01, a00, a10, a20, b01, b11, b21)
        MFMA6(acc10, a01, a11, a21, b00, b10, b20)
        MFMA6(acc11, a01, a11, a21, b01, b11, b21)
        #undef MFMA6
        __syncthreads();
    }
    const int orow = (lane >> 4) * 4;
    #pragma unroll
    for (int mf = 0; mf < 2; ++mf) {
        #pragma unroll
        for (int nf = 0; nf < 2; ++nf) {
            f32x4 v = mf == 0 ? (nf == 0 ? acc00 : acc01) : (nf == 0 ? acc10 : acc11);
            int c = n0 + wc * 32 + nf * 16 + fr;
            #pragma unroll
            for (int reg = 0; reg < 4; ++reg) {
                int r = m0 + wr * 32 + mf * 16 + orow + reg;
                if (r >= nrows) continue;
                long rb = (long)(r & 31), rc = (long)(r >> 5);
                float val = v[reg];
                if (O) {
                    float* p = O + rb * sob + rc * soc + c;
                    if (add) val += *p;
                    *p = val;
                }
                if (P) {
                    float* q = P + rb * spb + rc * spc + c;
                    *q += val;
                }
                if (S) {
                    short h, m, l;
                    split3(val, h, m, l);
                    short* s = S + rb * ssb + rc * ssc + c;
                    s[0] = h; s[HM] = m; s[2 * HM] = l;
                }
            }
        }
    }
}

// ---------------------------------------------------------------------------
// LayerNorm in place over last dim H for B*PRED rows.
// ---------------------------------------------------------------------------
__global__ __launch_bounds__(256) void ln_k(float* __restrict__ y,
                                            const float* __restrict__ w,
                                            const float* __restrict__ bia) {
    __shared__ float red[8];
    int row = blockIdx.x;
    float* p = y + (size_t)row * HH;
    int i4 = threadIdx.x * 4;
    float4 v = *(const float4*)&p[i4];
    float s = v.x + v.y + v.z + v.w;
    #pragma unroll
    for (int o = 32; o > 0; o >>= 1) s += __shfl_down(s, o, 64);
    int wid = threadIdx.x >> 6;
    if ((threadIdx.x & 63) == 0) red[wid] = s;
    __syncthreads();
    if (threadIdx.x == 0) red[4] = (red[0] + red[1] + red[2] + red[3]) * (1.f / HH);
    __syncthreads();
    float mu = red[4];
    float dx = v.x - mu, dy = v.y - mu, dz = v.z - mu, dw = v.w - mu;
    float q = dx * dx + dy * dy + dz * dz + dw * dw;
    #pragma unroll
    for (int o = 32; o > 0; o >>= 1) q += __shfl_down(q, o, 64);
    if ((threadIdx.x & 63) == 0) red[wid] = q;
    __syncthreads();
    if (threadIdx.x == 0) red[5] = (red[0] + red[1] + red[2] + red[3]) * (1.f / HH);
    __syncthreads();
    float rs = rsqrtf(red[5] + LN_EPS);
    float4 o4;
    o4.x = dx * rs * w[i4 + 0] + bia[i4 + 0];
    o4.y = dy * rs * w[i4 + 1] + bia[i4 + 1];
    o4.z = dz * rs * w[i4 + 2] + bia[i4 + 2];
    o4.w = dw * rs * w[i4 + 3] + bia[i4 + 3];
    *(float4*)&p[i4] = o4;
}

// ---------------------------------------------------------------------------
extern "C" void kernel_launch(void* const* d_in, const int* in_sizes, int n_in,
                              void* d_out, int out_size, void* d_ws, size_t ws_size,
                              hipStream_t stream) {
    const float* x    = (const float*)d_in[0];
    const float* Wxh  = (const float*)d_in[1];
    const float* Whh  = (const float*)d_in[2];
    const float* ln_w = (const float*)d_in[3];
    const float* ln_b = (const float*)d_in[4];

    const size_t MiB = 1024 * 1024;
    float* rec  = (float*)d_out;
    float* outp = rec + (size_t)BB * LL * HH;

    const long LH = (long)LL * HH;
    const long CH = (long)CC * HH;
    const long PB = (long)PRED * HH;
    const long RS = (long)HH;
    const long RC = 32L * HH;
    float* nulf = (float*)nullptr;
    short* nuls = (short*)nullptr;

    char* wsb = (char*)d_ws;
    float* TP   = (float*)(wsb);                      // 4 MiB fp32 power
    short* SA_P = (short*)(wsb + 4  * MiB);           // 6 MiB A-splits
    short* SA0  = (short*)(wsb + 10 * MiB);           // 6 MiB
    short* SA1  = (short*)(wsb + 16 * MiB);           // 6 MiB
    short* SB_M = (short*)(wsb + 22 * MiB);           // 6 MiB B-splits of M
    short* SB_P = (short*)(wsb + 28 * MiB);           // 6 MiB B-splits rolling

    #define STEP64(SAx, sab, sac, SBx, Ox, sob, soc, addx, Px, spb, spc, Sx, ssb, ssc, MG, NR) \
        step_p64<<<dim3(16, MG), 256, 0, stream>>>(SAx, sab, sac, SBx, \
            Ox, sob, soc, addx, Px, spb, spc, Sx, ssb, ssc, NR)
    #define STEP32(SAx, sab, sac, SBx, Ox, sob, soc, addx, Px, spb, spc, Sx, ssb, ssc, MG) \
        step_p<<<dim3(16, MG), 128, 0, stream>>>(SAx, sab, sac, SBx, \
            Ox, sob, soc, addx, Px, spb, spc, Sx, ssb, ssc)

    if (ws_size >= 52 * MiB) {
        // ============ tier A: persisted power splits (52 MiB) ============
        short* SB_2 = (short*)(wsb + 34 * MiB);       // 6 MiB  (alias SB_X early)
        short* SB_4 = (short*)(wsb + 40 * MiB);       // 6 MiB
        short* SB_8 = (short*)(wsb + 46 * MiB);       // 6 MiB

        transpose_k<<<dim3(32, 32), dim3(32, 8), 0, stream>>>(Whh, TP);
        split_a<<<dim3(1, HH), 256, 0, stream>>>(Wxh, RS, RC, SB_2, RS, RC); // SB_X = splits of Wxh rows
        gemm_mx<<<dim3(16, 128), 256, 0, stream>>>(x, SB_2, rec);
        split_a<<<dim3(1, HH), 256, 0, stream>>>(TP, RS, RC, SA_P, RS, RC);
        split_t<<<dim3(32, 32), dim3(32, 8), 0, stream>>>(TP, SB_M);

        // chain1: M^2..M^16 (B-splits persisted in SB_2/4/8/P)
        STEP64(SA_P, RS, RC, SB_M, TP, RS, RC, 0, nulf, 0, 0, SA0, RS, RC, 16, 1024);
        split_t<<<dim3(32, 32), dim3(32, 8), 0, stream>>>(TP, SB_2);
        STEP64(SA0, RS, RC, SB_2, TP, RS, RC, 0, nulf, 0, 0, SA_P, RS, RC, 16, 1024);
        split_t<<<dim3(32, 32), dim3(32, 8), 0, stream>>>(TP, SB_4);
        STEP64(SA_P, RS, RC, SB_4, TP, RS, RC, 0, nulf, 0, 0, SA0, RS, RC, 16, 1024);
        split_t<<<dim3(32, 32), dim3(32, 8), 0, stream>>>(TP, SB_8);
        STEP64(SA0, RS, RC, SB_8, TP, RS, RC, 0, nulf, 0, 0, nuls, 0, 0, 16, 1024);
        split_t<<<dim3(32, 32), dim3(32, 8), 0, stream>>>(TP, SB_P);   // SB_P = M^16

        // stage1
        split_a<<<dim3(1, HH), 256, 0, stream>>>(rec, LH, CH, SA0, RS, RC);
        for (int o = 1; o < CC; ++o) {
            short* Ain = (o & 1) ? SA0 : SA1;
            short* Sot = (o & 1) ? SA1 : SA0;
            STEP64(Ain, RS, RC, SB_M,
                   rec + (size_t)o * HH, LH, CH, 1, nulf, 0, 0,
                   Sot, RS, RC, 16, 1024);
        }
        // stage2: 31 sequential carries with M^16
        for (int c = 1; c < NC; ++c)
            STEP32(SA1 + (size_t)(c - 1) * 32 * HH, RS, 0, SB_P,
                   rec + ((size_t)c * CC + CC - 1) * HH, LH, 0, 1, nulf, 0, 0,
                   SA1 + (size_t)c * 32 * HH, RS, 0, 1);
        // stage3: Z-chain, 15 steps of 992 rows
        for (int o = 0; o < CC - 1; ++o) {
            short* Ain = (o & 1) ? SA0 : SA1;
            short* Sot = (o & 1) ? SA1 : SA0;
            STEP64(Ain, RS, RC, SB_M,
                   nulf, 0, 0, 0,
                   rec + (size_t)(CC + o) * HH, LH, CH,
                   (o == CC - 2) ? nuls : Sot, RS, RC, 16, 992);
        }
        // pred (persisted powers; no recompute)
        STEP32(SA1 + (size_t)992 * HH, RS, 0, SB_M, outp, PB, 0, 0, nulf, 0, 0, SA0, RS, 0, 1);
        STEP32(SA0, RS, 0, SB_M, outp + HH, PB, 0, 0, nulf, 0, 0, SA0 + (size_t)32 * HH, RS, 0, 1);
        STEP32(SA0, RS, RC, SB_2, outp + 2 * HH, PB, RS, 0, nulf, 0, 0, SA0 + (size_t)2 * 32 * HH, RS, RC, 2);
        STEP32(SA0, RS, RC, SB_4, outp + 4 * HH, PB, RS, 0, nulf, 0, 0, SA0 + (size_t)4 * 32 * HH, RS, RC, 4);
        STEP32(SA0, RS, RC, SB_8, outp + 8 * HH, PB, RS, 0, nulf, 0, 0, SA0 + (size_t)8 * 32 * HH, RS, RC, 8);
        STEP64(SA0, RS, RC, SB_P, outp + 16 * HH, PB, RS, 0, nulf, 0, 0, nuls, 0, 0, 8, 512);

        ln_k<<<BB * PRED, 256, 0, stream>>>(outp, ln_w, ln_b);
        return;
    }

    // ============ tier B: R6 choreography (>=34 MiB, proven present) ============
    transpose_k<<<dim3(32, 32), dim3(32, 8), 0, stream>>>(Whh, TP);
    split_a<<<dim3(1, HH), 256, 0, stream>>>(Wxh, RS, RC, SB_P, RS, RC);  // SB_X = SB_P early
    gemm_mx<<<dim3(16, 128), 256, 0, stream>>>(x, SB_P, rec);
    split_a<<<dim3(1, HH), 256, 0, stream>>>(TP, RS, RC, SA_P, RS, RC);
    split_t<<<dim3(32, 32), dim3(32, 8), 0, stream>>>(TP, SB_M);

    // chain1: rolling SB_P
    STEP64(SA_P, RS, RC, SB_M, TP, RS, RC, 0, nulf, 0, 0, SA0, RS, RC, 16, 1024);
    split_t<<<dim3(32, 32), dim3(32, 8), 0, stream>>>(TP, SB_P);
    STEP64(SA0, RS, RC, SB_P, TP, RS, RC, 0, nulf, 0, 0, SA_P, RS, RC, 16, 1024);
    split_t<<<dim3(32, 32), dim3(32, 8), 0, stream>>>(TP, SB_P);
    STEP64(SA_P, RS, RC, SB_P, TP, RS, RC, 0, nulf, 0, 0, SA0, RS, RC, 16, 1024);
    split_t<<<dim3(32, 32), dim3(32, 8), 0, stream>>>(TP, SB_P);
    STEP64(SA0, RS, RC, SB_P, TP, RS, RC, 0, nulf, 0, 0, nuls, 0, 0, 16, 1024);
    split_t<<<dim3(32, 32), dim3(32, 8), 0, stream>>>(TP, SB_P);       // SB_P = M^16

    split_a<<<dim3(1, HH), 256, 0, stream>>>(rec, LH, CH, SA0, RS, RC);
    for (int o = 1; o < CC; ++o) {
        short* Ain = (o & 1) ? SA0 : SA1;
        short* Sot = (o & 1) ? SA1 : SA0;
        STEP64(Ain, RS, RC, SB_M,
               rec + (size_t)o * HH, LH, CH, 1, nulf, 0, 0,
               Sot, RS, RC, 16, 1024);
    }
    for (int c = 1; c < NC; ++c)
        STEP32(SA1 + (size_t)(c - 1) * 32 * HH, RS, 0, SB_P,
               rec + ((size_t)c * CC + CC - 1) * HH, LH, 0, 1, nulf, 0, 0,
               SA1 + (size_t)c * 32 * HH, RS, 0, 1);
    for (int o = 0; o < CC - 1; ++o) {
        short* Ain = (o & 1) ? SA0 : SA1;
        short* Sot = (o & 1) ? SA1 : SA0;
        STEP64(Ain, RS, RC, SB_M,
               nulf, 0, 0, 0,
               rec + (size_t)(CC + o) * HH, LH, CH,
               (o == CC - 2) ? nuls : Sot, RS, RC, 16, 992);
    }
    // pred with recomputed powers (R6 pattern)
    STEP32(SA1 + (size_t)992 * HH, RS, 0, SB_M, outp, PB, 0, 0, nulf, 0, 0, SA0, RS, 0, 1);
    STEP32(SA0, RS, 0, SB_M, outp + HH, PB, 0, 0, nulf, 0, 0, SA0 + (size_t)32 * HH, RS, 0, 1);
    tr_splits<<<dim3(32, 32, 3), dim3(32, 8), 0, stream>>>(SB_M, SA_P);
    STEP64(SA_P, RS, RC, SB_M, TP, RS, RC, 0, nulf, 0, 0, SA1, RS, RC, 16, 1024);
    split_t<<<dim3(32, 32), dim3(32, 8), 0, stream>>>(TP, SB_P);
    STEP32(SA0, RS, RC, SB_P, outp + 2 * HH, PB, RS, 0, nulf, 0, 0, SA0 + (size_t)2 * 32 * HH, RS, RC, 2);
    STEP64(SA1, RS, RC, SB_P, TP, RS, RC, 0, nulf, 0, 0, SA_P, RS, RC, 16, 1024);
    split_t<<<dim3(32, 32), dim3(32, 8), 0, stream>>>(TP, SB_P);
    STEP32(SA0, RS, RC, SB_P, outp + 4 * HH, PB, RS, 0, nulf, 0, 0, SA0 + (size_t)4 * 32 * HH, RS, RC, 4);
    STEP64(SA_P, RS, RC, SB_P, TP, RS, RC, 0, nulf, 0, 0, SA1, RS, RC, 16, 1024);
    split_t<<<dim3(32, 32), dim3(32, 8), 0, stream>>>(TP, SB_P);
    STEP32(SA0, RS, RC, SB_P, outp + 8 * HH, PB, RS, 0, nulf, 0, 0, SA0 + (size_t)8 * 32 * HH, RS, RC, 8);
    STEP64(SA1, RS, RC, SB_P, TP, RS, RC, 0, nulf, 0, 0, nuls, 0, 0, 16, 1024);
    split_t<<<dim3(32, 32), dim3(32, 8), 0, stream>>>(TP, SB_P);
    STEP64(SA0, RS, RC, SB_P, outp + 16 * HH, PB, RS, 0, nulf, 0, 0, nuls, 0, 0, 8, 512);

    ln_k<<<BB * PRED, 256, 0, stream>>>(outp, ln_w, ln_b);
    #undef STEP64
    #undef STEP32
}

// Round 8
// 1501.864 us; speedup vs baseline: 8.8539x; 1.4708x over previous
//
#include <hip/hip_runtime.h>

#define BB 32
#define LL 512
#define HH 1024
#define PRED 32
#define CC 16            // chunk length (tier B/C)
#define NC (LL / CC)
#define C8 8             // chunk length (tier A)
#define NC8 (LL / C8)    // 64 chunks
#define LN_EPS 1e-5f

typedef short bf16x8 __attribute__((ext_vector_type(8)));
typedef short s16x4  __attribute__((ext_vector_type(4)));
typedef float f32x4  __attribute__((ext_vector_type(4)));

static __device__ __forceinline__ void split3(float x, short& h, short& m, short& l) {
    unsigned u = __float_as_uint(x);
    unsigned rh = (u + 0x7fffu + ((u >> 16) & 1u)) & 0xffff0000u;
    h = (short)(rh >> 16);
    float x1 = x - __uint_as_float(rh);
    unsigned u1 = __float_as_uint(x1);
    unsigned rm = (u1 + 0x7fffu + ((u1 >> 16) & 1u)) & 0xffff0000u;
    m = (short)(rm >> 16);
    float x2 = x1 - __uint_as_float(rm);
    unsigned u2 = __float_as_uint(x2);
    unsigned rl = (u2 + 0x7fffu + ((u2 >> 16) & 1u)) & 0xffff0000u;
    l = (short)(rl >> 16);
}

static __device__ __forceinline__ void split2(float x, short& h, short& m) {
    unsigned u = __float_as_uint(x);
    unsigned rh = (u + 0x7fffu + ((u >> 16) & 1u)) & 0xffff0000u;
    h = (short)(rh >> 16);
    float x1 = x - __uint_as_float(rh);
    unsigned u1 = __float_as_uint(x1);
    unsigned rm = (u1 + 0x7fffu + ((u1 >> 16) & 1u)) & 0xffff0000u;
    m = (short)(rm >> 16);
}

#define MFMA6(ACC, AH, AM, AL, BH, BM, BL) \
    ACC = __builtin_amdgcn_mfma_f32_16x16x32_bf16(AL, BH, ACC, 0, 0, 0); \
    ACC = __builtin_amdgcn_mfma_f32_16x16x32_bf16(AH, BL, ACC, 0, 0, 0); \
    ACC = __builtin_amdgcn_mfma_f32_16x16x32_bf16(AM, BM, ACC, 0, 0, 0); \
    ACC = __builtin_amdgcn_mfma_f32_16x16x32_bf16(AM, BH, ACC, 0, 0, 0); \
    ACC = __builtin_amdgcn_mfma_f32_16x16x32_bf16(AH, BM, ACC, 0, 0, 0); \
    ACC = __builtin_amdgcn_mfma_f32_16x16x32_bf16(AH, BH, ACC, 0, 0, 0);

// ---------------------------------------------------------------------------
// Transpose Whh[k][j] -> out[j][k]
// ---------------------------------------------------------------------------
__global__ __launch_bounds__(256) void transpose_k(const float* __restrict__ in,
                                                   float* __restrict__ out) {
    __shared__ float tile[32][33];
    int bx = blockIdx.x * 32, by = blockIdx.y * 32;
    int tx = threadIdx.x, ty = threadIdx.y;
    #pragma unroll
    for (int i = 0; i < 32; i += 8)
        tile[ty + i][tx] = in[(size_t)(by + ty + i) * HH + bx + tx];
    __syncthreads();
    #pragma unroll
    for (int i = 0; i < 32; i += 8)
        out[(size_t)(bx + ty + i) * HH + by + tx] = tile[tx][ty + i];
}

// ---------------------------------------------------------------------------
// split_a: strided fp32 rows -> 3-plane bf16 splits [row][k], plane stride ps
// ---------------------------------------------------------------------------
__global__ __launch_bounds__(256) void split_a(const float* __restrict__ src, long sb, long sc,
                                               short* __restrict__ dst, long dsb, long dsc,
                                               long ps) {
    int r = blockIdx.y;
    const float* s = src + (long)(r & 31) * sb + (long)(r >> 5) * sc + threadIdx.x * 4;
    short* d = dst + (long)(r & 31) * dsb + (long)(r >> 5) * dsc + threadIdx.x * 4;
    float4 v = *(const float4*)s;
    float xs[4] = {v.x, v.y, v.z, v.w};
    s16x4 vh, vm, vl;
    #pragma unroll
    for (int j = 0; j < 4; ++j) {
        short h, m, l;
        split3(xs[j], h, m, l);
        vh[j] = h; vm[j] = m; vl[j] = l;
    }
    *(s16x4*)(d) = vh;
    *(s16x4*)(d + ps) = vm;
    *(s16x4*)(d + 2 * ps) = vl;
}

// ---------------------------------------------------------------------------
// split_t: fp32 P[k][n] -> B-layout 3-plane transposed splits [n][k] (ps=H*H)
// ---------------------------------------------------------------------------
__global__ __launch_bounds__(256) void split_t(const float* __restrict__ in,
                                               short* __restrict__ out) {
    const size_t HM = (size_t)HH * HH;
    __shared__ float tile[32][33];
    int n0 = blockIdx.x * 32, k0 = blockIdx.y * 32;
    int tx = threadIdx.x, ty = threadIdx.y;
    #pragma unroll
    for (int i = 0; i < 32; i += 8)
        tile[ty + i][tx] = in[(size_t)(k0 + ty + i) * HH + n0 + tx];
    __syncthreads();
    #pragma unroll
    for (int i = 0; i < 32; i += 8) {
        float v = tile[tx][ty + i];
        short h, m, l;
        split3(v, h, m, l);
        size_t o = (size_t)(n0 + ty + i) * HH + k0 + tx;
        out[o] = h; out[HM + o] = m; out[2 * HM + o] = l;
    }
}

// ---------------------------------------------------------------------------
// tr_splits: B-layout splits [p][n][k] -> A-layout splits [p][k][n]  (ps=H*H)
// ---------------------------------------------------------------------------
__global__ __launch_bounds__(256) void tr_splits(const short* __restrict__ in,
                                                 short* __restrict__ out) {
    const size_t HM = (size_t)HH * HH;
    __shared__ short tile[32][33];
    int p = blockIdx.z;
    int k0 = blockIdx.x * 32, n0 = blockIdx.y * 32;
    int tx = threadIdx.x, ty = threadIdx.y;
    #pragma unroll
    for (int i = 0; i < 32; i += 8)
        tile[ty + i][tx] = in[p * HM + (size_t)(n0 + ty + i) * HH + k0 + tx];
    __syncthreads();
    #pragma unroll
    for (int i = 0; i < 32; i += 8)
        out[p * HM + (size_t)(k0 + ty + i) * HH + n0 + tx] = tile[tx][ty + i];
}

// ---------------------------------------------------------------------------
// copy_splits: flat row copy of 3-plane split buffers (plane stride ps).
// grid.x = nrows, 256 thr, 4 shorts each.
// ---------------------------------------------------------------------------
__global__ __launch_bounds__(256) void copy_splits(const short* __restrict__ src,
                                                   short* __restrict__ dst, long ps) {
    size_t off = (size_t)blockIdx.x * HH + threadIdx.x * 4;
    *(s16x4*)(dst + off)          = *(const s16x4*)(src + off);
    *(s16x4*)(dst + ps + off)     = *(const s16x4*)(src + ps + off);
    *(s16x4*)(dst + 2 * ps + off) = *(const s16x4*)(src + 2 * ps + off);
}

// ---------------------------------------------------------------------------
// gemm_mx: C[m][n] = sum_k x[m][k]*W[n][k], MFMA bf16 2x2 split (proven R7).
// ---------------------------------------------------------------------------
__global__ __launch_bounds__(256) void gemm_mx(const float* __restrict__ A,
                                               const short* __restrict__ SB,
                                               float* __restrict__ C) {
    const size_t HM = (size_t)HH * HH;
    __shared__ __align__(16) short As2[2][128][40];
    __shared__ __align__(16) short Bs2[2][64][40];
    const int tid = threadIdx.x;
    const int lane = tid & 63;
    const int w = tid >> 6;
    const int n0 = blockIdx.x * 64;
    const int m0 = blockIdx.y * 128;
    const int ar = tid >> 1;
    const int akc = (tid & 1) * 16;
    const float* Arow = A + (size_t)(m0 + ar) * HH + akc;
    const int bp = tid >> 7;
    const int bnr = tid & 63;
    const int bkh = ((tid >> 6) & 1) * 16;
    const short* Brow = SB + bp * HM + (size_t)(n0 + bnr) * HH + bkh;
    const int fr = lane & 15;
    const int fk = (lane >> 4) * 8;

    f32x4 acc[2][4] = {};

    float4 av0 = *(const float4*)(Arow);
    float4 av1 = *(const float4*)(Arow + 4);
    float4 av2 = *(const float4*)(Arow + 8);
    float4 av3 = *(const float4*)(Arow + 12);
    bf16x8 rb0 = *(const bf16x8*)(Brow);
    bf16x8 rb1 = *(const bf16x8*)(Brow + 8);

    for (int kt = 0; kt < HH; kt += 32) {
        float xs[16] = {av0.x, av0.y, av0.z, av0.w, av1.x, av1.y, av1.z, av1.w,
                        av2.x, av2.y, av2.z, av2.w, av3.x, av3.y, av3.z, av3.w};
        bf16x8 vh0, vm0, vh1, vm1;
        #pragma unroll
        for (int j = 0; j < 8; ++j) {
            short h, m;
            split2(xs[j], h, m);
            vh0[j] = h; vm0[j] = m;
            split2(xs[j + 8], h, m);
            vh1[j] = h; vm1[j] = m;
        }
        *(bf16x8*)&As2[0][ar][akc]     = vh0;
        *(bf16x8*)&As2[0][ar][akc + 8] = vh1;
        *(bf16x8*)&As2[1][ar][akc]     = vm0;
        *(bf16x8*)&As2[1][ar][akc + 8] = vm1;
        *(bf16x8*)&Bs2[bp][bnr][bkh]     = rb0;
        *(bf16x8*)&Bs2[bp][bnr][bkh + 8] = rb1;
        __syncthreads();
        if (kt + 32 < HH) {
            const float* An = Arow + kt + 32;
            av0 = *(const float4*)(An);
            av1 = *(const float4*)(An + 4);
            av2 = *(const float4*)(An + 8);
            av3 = *(const float4*)(An + 12);
            const short* Bn = Brow + kt + 32;
            rb0 = *(const bf16x8*)(Bn);
            rb1 = *(const bf16x8*)(Bn + 8);
        }
        bf16x8 ah[2], am[2];
        #pragma unroll
        for (int i = 0; i < 2; ++i) {
            ah[i] = *(const bf16x8*)&As2[0][w * 32 + i * 16 + fr][fk];
            am[i] = *(const bf16x8*)&As2[1][w * 32 + i * 16 + fr][fk];
        }
        #pragma unroll
        for (int j = 0; j < 4; ++j) {
            bf16x8 bh = *(const bf16x8*)&Bs2[0][j * 16 + fr][fk];
            bf16x8 bm = *(const bf16x8*)&Bs2[1][j * 16 + fr][fk];
            #pragma unroll
            for (int i = 0; i < 2; ++i) {
                f32x4 a = acc[i][j];
                a = __builtin_amdgcn_mfma_f32_16x16x32_bf16(am[i], bm, a, 0, 0, 0);
                a = __builtin_amdgcn_mfma_f32_16x16x32_bf16(am[i], bh, a, 0, 0, 0);
                a = __builtin_amdgcn_mfma_f32_16x16x32_bf16(ah[i], bm, a, 0, 0, 0);
                a = __builtin_amdgcn_mfma_f32_16x16x32_bf16(ah[i], bh, a, 0, 0, 0);
                acc[i][j] = a;
            }
        }
        __syncthreads();
    }
    const int orow = (lane >> 4) * 4;
    #pragma unroll
    for (int i = 0; i < 2; ++i)
        #pragma unroll
        for (int j = 0; j < 4; ++j) {
            int c = n0 + j * 16 + fr;
            #pragma unroll
            for (int reg = 0; reg < 4; ++reg) {
                int r = m0 + w * 32 + i * 16 + orow + reg;
                C[(size_t)r * HH + c] = acc[i][j][reg];
            }
        }
}

// ---------------------------------------------------------------------------
// step_p: bf16x6 MFMA, pre-split A/B. 32(M)x64(N), 128 thr.
// psA/psS = plane strides of the A-split input / S-split output buffers.
// ---------------------------------------------------------------------------
__global__ __launch_bounds__(128) void step_p(
    const short* __restrict__ SA, long sab, long sac, long psA,
    const short* __restrict__ SB,
    float* __restrict__ O, long sob, long soc, int add,
    float* __restrict__ P, long spb, long spc,
    short* __restrict__ S, long ssb, long ssc, long psS) {
    const size_t HM = (size_t)HH * HH;
    __shared__ __align__(16) short As[3][32][40];
    __shared__ __align__(16) short Bs[3][64][40];
    const int tid = threadIdx.x;
    const int lane = tid & 63;
    const int w = tid >> 6;
    const int n0 = blockIdx.x * 64;
    const int m0 = blockIdx.y * 32;
    const int ar = tid >> 2;
    const int akc = (tid & 3) * 8;
    const int agr = m0 + ar;
    const short* Arow = SA + (long)(agr & 31) * sab + (long)(agr >> 5) * sac + akc;
    const int bnr = tid & 63;
    const int bkh = (tid >> 6) * 16;
    const short* Brow = SB + (size_t)(n0 + bnr) * HH + bkh;
    const int fr = lane & 15;
    const int fk = (lane >> 4) * 8;

    f32x4 acc00 = 0, acc01 = 0, acc10 = 0, acc11 = 0;

    bf16x8 ra0 = *(const bf16x8*)(Arow);
    bf16x8 ra1 = *(const bf16x8*)(Arow + psA);
    bf16x8 ra2 = *(const bf16x8*)(Arow + 2 * psA);
    bf16x8 rb0 = *(const bf16x8*)(Brow);
    bf16x8 rb1 = *(const bf16x8*)(Brow + 8);
    bf16x8 rb2 = *(const bf16x8*)(Brow + HM);
    bf16x8 rb3 = *(const bf16x8*)(Brow + HM + 8);
    bf16x8 rb4 = *(const bf16x8*)(Brow + 2 * HM);
    bf16x8 rb5 = *(const bf16x8*)(Brow + 2 * HM + 8);

    for (int kt = 0; kt < HH; kt += 32) {
        *(bf16x8*)&As[0][ar][akc] = ra0;
        *(bf16x8*)&As[1][ar][akc] = ra1;
        *(bf16x8*)&As[2][ar][akc] = ra2;
        *(bf16x8*)&Bs[0][bnr][bkh] = rb0;
        *(bf16x8*)&Bs[0][bnr][bkh + 8] = rb1;
        *(bf16x8*)&Bs[1][bnr][bkh] = rb2;
        *(bf16x8*)&Bs[1][bnr][bkh + 8] = rb3;
        *(bf16x8*)&Bs[2][bnr][bkh] = rb4;
        *(bf16x8*)&Bs[2][bnr][bkh + 8] = rb5;
        __syncthreads();
        if (kt + 32 < HH) {
            const short* An = Arow + kt + 32;
            const short* Bn = Brow + kt + 32;
            ra0 = *(const bf16x8*)(An);
            ra1 = *(const bf16x8*)(An + psA);
            ra2 = *(const bf16x8*)(An + 2 * psA);
            rb0 = *(const bf16x8*)(Bn);
            rb1 = *(const bf16x8*)(Bn + 8);
            rb2 = *(const bf16x8*)(Bn + HM);
            rb3 = *(const bf16x8*)(Bn + HM + 8);
            rb4 = *(const bf16x8*)(Bn + 2 * HM);
            rb5 = *(const bf16x8*)(Bn + 2 * HM + 8);
        }
        bf16x8 a00 = *(const bf16x8*)&As[0][fr][fk];
        bf16x8 a01 = *(const bf16x8*)&As[0][16 + fr][fk];
        bf16x8 a10 = *(const bf16x8*)&As[1][fr][fk];
        bf16x8 a11 = *(const bf16x8*)&As[1][16 + fr][fk];
        bf16x8 a20 = *(const bf16x8*)&As[2][fr][fk];
        bf16x8 a21 = *(const bf16x8*)&As[2][16 + fr][fk];
        bf16x8 b00 = *(const bf16x8*)&Bs[0][w * 32 + fr][fk];
        bf16x8 b01 = *(const bf16x8*)&Bs[0][w * 32 + 16 + fr][fk];
        bf16x8 b10 = *(const bf16x8*)&Bs[1][w * 32 + fr][fk];
        bf16x8 b11 = *(const bf16x8*)&Bs[1][w * 32 + 16 + fr][fk];
        bf16x8 b20 = *(const bf16x8*)&Bs[2][w * 32 + fr][fk];
        bf16x8 b21 = *(const bf16x8*)&Bs[2][w * 32 + 16 + fr][fk];
        MFMA6(acc00, a00, a10, a20, b00, b10, b20)
        MFMA6(acc01, a00, a10, a20, b01, b11, b21)
        MFMA6(acc10, a01, a11, a21, b00, b10, b20)
        MFMA6(acc11, a01, a11, a21, b01, b11, b21)
        __syncthreads();
    }
    const int orow = (lane >> 4) * 4;
    #pragma unroll
    for (int mf = 0; mf < 2; ++mf) {
        #pragma unroll
        for (int nf = 0; nf < 2; ++nf) {
            f32x4 v = mf == 0 ? (nf == 0 ? acc00 : acc01) : (nf == 0 ? acc10 : acc11);
            int c = n0 + w * 32 + nf * 16 + fr;
            #pragma unroll
            for (int reg = 0; reg < 4; ++reg) {
                int r = m0 + mf * 16 + orow + reg;
                long rb = (long)(r & 31), rc = (long)(r >> 5);
                float val = v[reg];
                if (O) {
                    float* p = O + rb * sob + rc * soc + c;
                    if (add) val += *p;
                    *p = val;
                }
                if (P) {
                    float* q = P + rb * spb + rc * spc + c;
                    *q += val;
                }
                if (S) {
                    short h, m, l;
                    split3(val, h, m, l);
                    short* s = S + rb * ssb + rc * ssc + c;
                    s[0] = h; s[psS] = m; s[2 * psS] = l;
                }
            }
        }
    }
}

// ---------------------------------------------------------------------------
// step_p64: bf16x6 MFMA, 64x64, 256 thr (2x2 waves), row guard.
// ---------------------------------------------------------------------------
__global__ __launch_bounds__(256) void step_p64(
    const short* __restrict__ SA, long sab, long sac, long psA,
    const short* __restrict__ SB,
    float* __restrict__ O, long sob, long soc, int add,
    float* __restrict__ P, long spb, long spc,
    short* __restrict__ S, long ssb, long ssc, long psS,
    int nrows) {
    const size_t HM = (size_t)HH * HH;
    __shared__ __align__(16) short As[3][64][40];
    __shared__ __align__(16) short Bs[3][64][40];
    const int tid = threadIdx.x;
    const int lane = tid & 63;
    const int w = tid >> 6;
    const int wr = w & 1;
    const int wc = w >> 1;
    const int n0 = blockIdx.x * 64;
    const int m0 = blockIdx.y * 64;
    const int ar = tid >> 2;
    const int akc = (tid & 3) * 8;
    const int agr = m0 + ar;
    const short* Arow = SA + (long)(agr & 31) * sab + (long)(agr >> 5) * sac + akc;
    const short* Brow = SB + (size_t)(n0 + ar) * HH + akc;
    const int fr = lane & 15;
    const int fk = (lane >> 4) * 8;

    f32x4 acc00 = 0, acc01 = 0, acc10 = 0, acc11 = 0;

    bf16x8 ra0 = *(const bf16x8*)(Arow);
    bf16x8 ra1 = *(const bf16x8*)(Arow + psA);
    bf16x8 ra2 = *(const bf16x8*)(Arow + 2 * psA);
    bf16x8 rb0 = *(const bf16x8*)(Brow);
    bf16x8 rb1 = *(const bf16x8*)(Brow + HM);
    bf16x8 rb2 = *(const bf16x8*)(Brow + 2 * HM);

    for (int kt = 0; kt < HH; kt += 32) {
        *(bf16x8*)&As[0][ar][akc] = ra0;
        *(bf16x8*)&As[1][ar][akc] = ra1;
        *(bf16x8*)&As[2][ar][akc] = ra2;
        *(bf16x8*)&Bs[0][ar][akc] = rb0;
        *(bf16x8*)&Bs[1][ar][akc] = rb1;
        *(bf16x8*)&Bs[2][ar][akc] = rb2;
        __syncthreads();
        if (kt + 32 < HH) {
            const short* An = Arow + kt + 32;
            const short* Bn = Brow + kt + 32;
            ra0 = *(const bf16x8*)(An);
            ra1 = *(const bf16x8*)(An + psA);
            ra2 = *(const bf16x8*)(An + 2 * psA);
            rb0 = *(const bf16x8*)(Bn);
            rb1 = *(const bf16x8*)(Bn + HM);
            rb2 = *(const bf16x8*)(Bn + 2 * HM);
        }
        bf16x8 a00 = *(const bf16x8*)&As[0][wr * 32 + fr][fk];
        bf16x8 a01 = *(const bf16x8*)&As[0][wr * 32 + 16 + fr][fk];
        bf16x8 a10 = *(const bf16x8*)&As[1][wr * 32 + fr][fk];
        bf16x8 a11 = *(const bf16x8*)&As[1][wr * 32 + 16 + fr][fk];
        bf16x8 a20 = *(const bf16x8*)&As[2][wr * 32 + fr][fk];
        bf16x8 a21 = *(const bf16x8*)&As[2][wr * 32 + 16 + fr][fk];
        bf16x8 b00 = *(const bf16x8*)&Bs[0][wc * 32 + fr][fk];
        bf16x8 b01 = *(const bf16x8*)&Bs[0][wc * 32 + 16 + fr][fk];
        bf16x8 b10 = *(const bf16x8*)&Bs[1][wc * 32 + fr][fk];
        bf16x8 b11 = *(const bf16x8*)&Bs[1][wc * 32 + 16 + fr][fk];
        bf16x8 b20 = *(const bf16x8*)&Bs[2][wc * 32 + fr][fk];
        bf16x8 b21 = *(const bf16x8*)&Bs[2][wc * 32 + 16 + fr][fk];
        MFMA6(acc00, a00, a10, a20, b00, b10, b20)
        MFMA6(acc01, a00, a10, a20, b01, b11, b21)
        MFMA6(acc10, a01, a11, a21, b00, b10, b20)
        MFMA6(acc11, a01, a11, a21, b01, b11, b21)
        __syncthreads();
    }
    const int orow = (lane >> 4) * 4;
    #pragma unroll
    for (int mf = 0; mf < 2; ++mf) {
        #pragma unroll
        for (int nf = 0; nf < 2; ++nf) {
            f32x4 v = mf == 0 ? (nf == 0 ? acc00 : acc01) : (nf == 0 ? acc10 : acc11);
            int c = n0 + wc * 32 + nf * 16 + fr;
            #pragma unroll
            for (int reg = 0; reg < 4; ++reg) {
                int r = m0 + wr * 32 + mf * 16 + orow + reg;
                if (r >= nrows) continue;
                long rb = (long)(r & 31), rc = (long)(r >> 5);
                float val = v[reg];
                if (O) {
                    float* p = O + rb * sob + rc * soc + c;
                    if (add) val += *p;
                    *p = val;
                }
                if (P) {
                    float* q = P + rb * spb + rc * spc + c;
                    *q += val;
                }
                if (S) {
                    short h, m, l;
                    split3(val, h, m, l);
                    short* s = S + rb * ssb + rc * ssc + c;
                    s[0] = h; s[psS] = m; s[2 * psS] = l;
                }
            }
        }
    }
}

// ---------------------------------------------------------------------------
// step_p128: bf16x6 MFMA, 128(M)x64(N), 512 thr (4x2 waves), row guard.
// ---------------------------------------------------------------------------
__global__ __launch_bounds__(512) void step_p128(
    const short* __restrict__ SA, long sab, long sac, long psA,
    const short* __restrict__ SB,
    float* __restrict__ O, long sob, long soc, int add,
    float* __restrict__ P, long spb, long spc,
    short* __restrict__ S, long ssb, long ssc, long psS,
    int nrows) {
    const size_t HM = (size_t)HH * HH;
    __shared__ __align__(16) short As[3][128][40];
    __shared__ __align__(16) short Bs[3][64][40];
    const int tid = threadIdx.x;
    const int lane = tid & 63;
    const int w = tid >> 6;
    const int wr = w & 3;
    const int wc = w >> 2;
    const int n0 = blockIdx.x * 64;
    const int m0 = blockIdx.y * 128;
    // A staging: 128 rows x 32 k x 3 planes, 1 bf16x8 per plane per thread
    const int ar = tid >> 2;
    const int akc = (tid & 3) * 8;
    const int agr = m0 + ar;
    const short* Arow = SA + (long)(agr & 31) * sab + (long)(agr >> 5) * sac + akc;
    // B staging: threads 0..383, plane tid>>7, 2 bf16x8 each
    const bool bst = (tid < 384);
    const int bp = (tid >> 7) == 3 ? 2 : (tid >> 7);
    const int bt = tid & 127;
    const int bnr = bt >> 1;
    const int bkh = (bt & 1) * 16;
    const short* Brow = SB + (size_t)bp * HM + (size_t)(n0 + bnr) * HH + bkh;
    const int fr = lane & 15;
    const int fk = (lane >> 4) * 8;

    f32x4 acc00 = 0, acc01 = 0, acc10 = 0, acc11 = 0;

    bf16x8 ra0 = *(const bf16x8*)(Arow);
    bf16x8 ra1 = *(const bf16x8*)(Arow + psA);
    bf16x8 ra2 = *(const bf16x8*)(Arow + 2 * psA);
    bf16x8 rb0 = {}, rb1 = {};
    if (bst) { rb0 = *(const bf16x8*)(Brow); rb1 = *(const bf16x8*)(Brow + 8); }

    for (int kt = 0; kt < HH; kt += 32) {
        *(bf16x8*)&As[0][ar][akc] = ra0;
        *(bf16x8*)&As[1][ar][akc] = ra1;
        *(bf16x8*)&As[2][ar][akc] = ra2;
        if (bst) {
            *(bf16x8*)&Bs[bp][bnr][bkh]     = rb0;
            *(bf16x8*)&Bs[bp][bnr][bkh + 8] = rb1;
        }
        __syncthreads();
        if (kt + 32 < HH) {
            const short* An = Arow + kt + 32;
            ra0 = *(const bf16x8*)(An);
            ra1 = *(const bf16x8*)(An + psA);
            ra2 = *(const bf16x8*)(An + 2 * psA);
            if (bst) {
                const short* Bn = Brow + kt + 32;
                rb0 = *(const bf16x8*)(Bn);
                rb1 = *(const bf16x8*)(Bn + 8);
            }
        }
        bf16x8 a00 = *(const bf16x8*)&As[0][wr * 32 + fr][fk];
        bf16x8 a01 = *(const bf16x8*)&As[0][wr * 32 + 16 + fr][fk];
        bf16x8 a10 = *(const bf16x8*)&As[1][wr * 32 + fr][fk];
        bf16x8 a11 = *(const bf16x8*)&As[1][wr * 32 + 16 + fr][fk];
        bf16x8 a20 = *(const bf16x8*)&As[2][wr * 32 + fr][fk];
        bf16x8 a21 = *(const bf16x8*)&As[2][wr * 32 + 16 + fr][fk];
        bf16x8 b00 = *(const bf16x8*)&Bs[0][wc * 32 + fr][fk];
        bf16x8 b01 = *(const bf16x8*)&Bs[0][wc * 32 + 16 + fr][fk];
        bf16x8 b10 = *(const bf16x8*)&Bs[1][wc * 32 + fr][fk];
        bf16x8 b11 = *(const bf16x8*)&Bs[1][wc * 32 + 16 + fr][fk];
        bf16x8 b20 = *(const bf16x8*)&Bs[2][wc * 32 + fr][fk];
        bf16x8 b21 = *(const bf16x8*)&Bs[2][wc * 32 + 16 + fr][fk];
        MFMA6(acc00, a00, a10, a20, b00, b10, b20)
        MFMA6(acc01, a00, a10, a20, b01, b11, b21)
        MFMA6(acc10, a01, a11, a21, b00, b10, b20)
        MFMA6(acc11, a01, a11, a21, b01, b11, b21)
        __syncthreads();
    }
    const int orow = (lane >> 4) * 4;
    #pragma unroll
    for (int mf = 0; mf < 2; ++mf) {
        #pragma unroll
        for (int nf = 0; nf < 2; ++nf) {
            f32x4 v = mf == 0 ? (nf == 0 ? acc00 : acc01) : (nf == 0 ? acc10 : acc11);
            int c = n0 + wc * 32 + nf * 16 + fr;
            #pragma unroll
            for (int reg = 0; reg < 4; ++reg) {
                int r = m0 + wr * 32 + mf * 16 + orow + reg;
                if (r >= nrows) continue;
                long rb = (long)(r & 31), rc = (long)(r >> 5);
                float val = v[reg];
                if (O) {
                    float* p = O + rb * sob + rc * soc + c;
                    if (add) val += *p;
                    *p = val;
                }
                if (P) {
                    float* q = P + rb * spb + rc * spc + c;
                    *q += val;
                }
                if (S) {
                    short h, m, l;
                    split3(val, h, m, l);
                    short* s = S + rb * ssb + rc * ssc + c;
                    s[0] = h; s[psS] = m; s[2 * psS] = l;
                }
            }
        }
    }
}

// ---------------------------------------------------------------------------
// LayerNorm in place over last dim H for B*PRED rows.
// ---------------------------------------------------------------------------
__global__ __launch_bounds__(256) void ln_k(float* __restrict__ y,
                                            const float* __restrict__ w,
                                            const float* __restrict__ bia) {
    __shared__ float red[8];
    int row = blockIdx.x;
    float* p = y + (size_t)row * HH;
    int i4 = threadIdx.x * 4;
    float4 v = *(const float4*)&p[i4];
    float s = v.x + v.y + v.z + v.w;
    #pragma unroll
    for (int o = 32; o > 0; o >>= 1) s += __shfl_down(s, o, 64);
    int wid = threadIdx.x >> 6;
    if ((threadIdx.x & 63) == 0) red[wid] = s;
    __syncthreads();
    if (threadIdx.x == 0) red[4] = (red[0] + red[1] + red[2] + red[3]) * (1.f / HH);
    __syncthreads();
    float mu = red[4];
    float dx = v.x - mu, dy = v.y - mu, dz = v.z - mu, dw = v.w - mu;
    float q = dx * dx + dy * dy + dz * dz + dw * dw;
    #pragma unroll
    for (int o = 32; o > 0; o >>= 1) q += __shfl_down(q, o, 64);
    if ((threadIdx.x & 63) == 0) red[wid] = q;
    __syncthreads();
    if (threadIdx.x == 0) red[5] = (red[0] + red[1] + red[2] + red[3]) * (1.f / HH);
    __syncthreads();
    float rs = rsqrtf(red[5] + LN_EPS);
    float4 o4;
    o4.x = dx * rs * w[i4 + 0] + bia[i4 + 0];
    o4.y = dy * rs * w[i4 + 1] + bia[i4 + 1];
    o4.z = dz * rs * w[i4 + 2] + bia[i4 + 2];
    o4.w = dw * rs * w[i4 + 3] + bia[i4 + 3];
    *(float4*)&p[i4] = o4;
}

// ---------------------------------------------------------------------------
extern "C" void kernel_launch(void* const* d_in, const int* in_sizes, int n_in,
                              void* d_out, int out_size, void* d_ws, size_t ws_size,
                              hipStream_t stream) {
    const float* x    = (const float*)d_in[0];
    const float* Wxh  = (const float*)d_in[1];
    const float* Whh  = (const float*)d_in[2];
    const float* ln_w = (const float*)d_in[3];
    const float* ln_b = (const float*)d_in[4];

    const size_t MiB = 1024 * 1024;
    const long HM = (long)HH * HH;       // plane stride, 1024-row buffers
    const long PS2 = 2048L * HH;         // plane stride, 2048-row buffers
    float* rec  = (float*)d_out;
    float* outp = rec + (size_t)BB * LL * HH;

    const long LH  = (long)LL * HH;      // b-stride in rec
    const long PB  = (long)PRED * HH;    // b-stride in outp
    const long RS  = (long)HH;           // split row stride
    const long RC  = 32L * HH;           // split chunk stride (32 b-rows)
    float* nulf = (float*)nullptr;
    short* nuls = (short*)nullptr;
    char* wsb = (char*)d_ws;

    if (ws_size >= 64 * MiB) {
        // =========== tier NEW: CC=8, Hillis-Steele carry scan (64 MiB) ===========
        const long CH8 = (long)C8 * HH;  // chunk stride in rec
        float* TP   = (float*)(wsb);                 // 4 MiB fp32 power temp
        short* SAP  = (short*)(wsb + 4 * MiB);       // 6 MiB A-splits of power
        short* SA0  = (short*)(wsb + 10 * MiB);      // 12 MiB 2048-row splits
        short* SA1  = (short*)(wsb + 22 * MiB);      // 12 MiB
        short* SBM  = (short*)(wsb + 34 * MiB);      // 6 MiB B-splits of M
        short* SB8  = (short*)(wsb + 40 * MiB);      // 6 MiB M^8
        short* SB16 = (short*)(wsb + 46 * MiB);      // 6 MiB M^16
        short* SBr0 = (short*)(wsb + 52 * MiB);      // 6 MiB rolling
        short* SBr1 = (short*)(wsb + 58 * MiB);      // 6 MiB rolling

        transpose_k<<<dim3(32, 32), dim3(32, 8), 0, stream>>>(Whh, TP);
        split_a<<<dim3(1, HH), 256, 0, stream>>>(Wxh, RS, RC, SBr0, RS, RC, HM);
        gemm_mx<<<dim3(16, 128), 256, 0, stream>>>(x, SBr0, rec);
        split_a<<<dim3(1, HH), 256, 0, stream>>>(TP, RS, RC, SAP, RS, RC, HM);
        split_t<<<dim3(32, 32), dim3(32, 8), 0, stream>>>(TP, SBM);

        // prefix squarings: M^2, M^4, M^8, M^16 (S chains A-splits; SA1 as scratch)
        #define SQ64(SAi, SBi, Sot) \
            step_p64<<<dim3(16, 16), 256, 0, stream>>>(SAi, RS, RC, HM, SBi, \
                TP, RS, RC, 0, nulf, 0, 0, Sot, RS, RC, HM, 1024)
        SQ64(SAP, SBM, SA1);                                            // TP = M^2
        split_t<<<dim3(32, 32), dim3(32, 8), 0, stream>>>(TP, SBr0);
        SQ64(SA1, SBr0, SAP);                                           // TP = M^4
        split_t<<<dim3(32, 32), dim3(32, 8), 0, stream>>>(TP, SBr1);
        SQ64(SAP, SBr1, SA1);                                           // TP = M^8
        split_t<<<dim3(32, 32), dim3(32, 8), 0, stream>>>(TP, SB8);
        SQ64(SA1, SB8, SAP);                                            // TP = M^16
        split_t<<<dim3(32, 32), dim3(32, 8), 0, stream>>>(TP, SB16);
        // SAP = A-splits of M^16

        // stage1 seed: splits of rec offset-0 rows (2048 rows) -> SA0
        split_a<<<dim3(1, 2048), 256, 0, stream>>>(rec, LH, CH8, SA0, RS, RC, PS2);
        // stage1: 7 steps of 2048 rows
        for (int o = 1; o < C8; ++o) {
            short* Ain = (o & 1) ? SA0 : SA1;
            short* Sot = (o & 1) ? SA1 : SA0;
            step_p128<<<dim3(16, 16), 512, 0, stream>>>(Ain, RS, RC, PS2, SBM,
                rec + (size_t)o * HH, LH, CH8, 1, nulf, 0, 0,
                Sot, RS, RC, PS2, 2048);
        }
        // chunk-end splits of h^loc now in SA1

        // Hillis-Steele scan over 64 chunk-ends + interleaved squarings
        #define SCAN(SRC, DST, T, SBpow) do { \
            int rows_ = (NC8 - (T)) * 32; \
            step_p128<<<dim3(16, (rows_ + 127) / 128), 512, 0, stream>>>( \
                SRC, RS, RC, PS2, SBpow, \
                rec + (size_t)((T) * C8 + C8 - 1) * HH, LH, CH8, 1, \
                nulf, 0, 0, DST + (size_t)(T) * RC, RS, RC, PS2, rows_); \
            copy_splits<<<(T) * 32, 256, 0, stream>>>(SRC, DST, PS2); \
        } while (0)
        #define SQI(SBi, SBo, last) do { \
            step_p64<<<dim3(16, 16), 256, 0, stream>>>(SAP, RS, RC, HM, SBi, \
                TP, RS, RC, 0, nulf, 0, 0, nuls, 0, 0, HM, 1024); \
            split_t<<<dim3(32, 32), dim3(32, 8), 0, stream>>>(TP, SBo); \
            if (!(last)) split_a<<<dim3(1, HH), 256, 0, stream>>>(TP, RS, RC, SAP, RS, RC, HM); \
        } while (0)

        SCAN(SA1, SA0, 1, SB8);
        SQI(SB16, SBr0, 0);          // M^32
        SCAN(SA0, SA1, 2, SB16);
        SQI(SBr0, SBr1, 0);          // M^64
        SCAN(SA1, SA0, 4, SBr0);
        SQI(SBr1, SBr0, 0);          // M^128
        SCAN(SA0, SA1, 8, SBr1);
        SQI(SBr0, SBr1, 1);          // M^256
        SCAN(SA1, SA0, 16, SBr0);
        SCAN(SA0, SA1, 32, SBr1);
        // scan-final splits (true chunk-end h) in SA1; chunk 63 = rows 2016..2047

        // stage3: Z-chain over chunks 1..63, 7 steps of 2016 rows
        for (int o = 0; o < C8 - 1; ++o) {
            short* Ain = (o & 1) ? SA0 : SA1;
            short* Sot = (o & 1) ? SA1 : SA0;
            step_p128<<<dim3(16, 16), 512, 0, stream>>>(Ain, RS, RC, PS2, SBM,
                nulf, 0, 0, 0,
                rec + (size_t)(C8 + o) * HH, LH, CH8,
                (o == C8 - 2) ? nuls : Sot, RS, RC, PS2, 2016);
        }

        // prediction via doubling
        step_p<<<dim3(16, 1), 128, 0, stream>>>(SA1 + 63 * RC, RS, 0, PS2, SBM,
            outp, PB, 0, 0, nulf, 0, 0, SA0, RS, 0, PS2);               // P1
        step_p<<<dim3(16, 1), 128, 0, stream>>>(SA0, RS, 0, PS2, SBM,
            outp + HH, PB, 0, 0, nulf, 0, 0, SA0 + RC, RS, 0, PS2);     // P2
        tr_splits<<<dim3(32, 32, 3), dim3(32, 8), 0, stream>>>(SBM, SAP);
        SQ64(SAP, SBM, nuls);                                            // TP = M^2
        split_t<<<dim3(32, 32), dim3(32, 8), 0, stream>>>(TP, SBr0);
        step_p<<<dim3(16, 2), 128, 0, stream>>>(SA0, RS, RC, PS2, SBr0,
            outp + 2 * HH, PB, RS, 0, nulf, 0, 0,
            SA0 + 2 * RC, RS, RC, PS2);                                 // P3:4
        split_a<<<dim3(1, HH), 256, 0, stream>>>(TP, RS, RC, SAP, RS, RC, HM);
        SQ64(SAP, SBr0, nuls);                                           // TP = M^4
        split_t<<<dim3(32, 32), dim3(32, 8), 0, stream>>>(TP, SBr1);
        step_p<<<dim3(16, 4), 128, 0, stream>>>(SA0, RS, RC, PS2, SBr1,
            outp + 4 * HH, PB, RS, 0, nulf, 0, 0,
            SA0 + 4 * RC, RS, RC, PS2);                                 // P5:8
        step_p<<<dim3(16, 8), 128, 0, stream>>>(SA0, RS, RC, PS2, SB8,
            outp + 8 * HH, PB, RS, 0, nulf, 0, 0,
            SA0 + 8 * RC, RS, RC, PS2);                                 // P9:16
        step_p64<<<dim3(16, 8), 256, 0, stream>>>(SA0, RS, RC, PS2, SB16,
            outp + 16 * HH, PB, RS, 0, nulf, 0, 0,
            nuls, 0, 0, PS2, 512);                                      // P17:32
        #undef SQ64
        #undef SCAN
        #undef SQI

        ln_k<<<BB * PRED, 256, 0, stream>>>(outp, ln_w, ln_b);
        return;
    }

    const long CH = (long)CC * HH;
    float* TP   = (float*)(wsb);
    short* SAP  = (short*)(wsb + 4 * MiB);
    short* SA0  = (short*)(wsb + 10 * MiB);
    short* SA1  = (short*)(wsb + 16 * MiB);
    short* SBM  = (short*)(wsb + 22 * MiB);
    short* SBP  = (short*)(wsb + 28 * MiB);

    #define STEP64(SAx, sab, sac, SBx, Ox, sob, soc, addx, Px, spb, spc, Sx, ssb, ssc, NR) \
        step_p64<<<dim3(16, ((NR) + 63) / 64), 256, 0, stream>>>(SAx, sab, sac, HM, SBx, \
            Ox, sob, soc, addx, Px, spb, spc, Sx, ssb, ssc, HM, NR)
    #define STEP32(SAx, sab, sac, SBx, Ox, sob, soc, addx, Px, spb, spc, Sx, ssb, ssc, MG) \
        step_p<<<dim3(16, MG), 128, 0, stream>>>(SAx, sab, sac, HM, SBx, \
            Ox, sob, soc, addx, Px, spb, spc, Sx, ssb, ssc, HM)

    if (ws_size >= 52 * MiB) {
        // ============ tier B: R7 tier-A, CC=16, persisted powers (52 MiB) ============
        short* SB2 = (short*)(wsb + 34 * MiB);
        short* SB4 = (short*)(wsb + 40 * MiB);
        short* SB8b = (short*)(wsb + 46 * MiB);

        transpose_k<<<dim3(32, 32), dim3(32, 8), 0, stream>>>(Whh, TP);
        split_a<<<dim3(1, HH), 256, 0, stream>>>(Wxh, RS, RC, SB2, RS, RC, HM);
        gemm_mx<<<dim3(16, 128), 256, 0, stream>>>(x, SB2, rec);
        split_a<<<dim3(1, HH), 256, 0, stream>>>(TP, RS, RC, SAP, RS, RC, HM);
        split_t<<<dim3(32, 32), dim3(32, 8), 0, stream>>>(TP, SBM);

        STEP64(SAP, RS, RC, SBM, TP, RS, RC, 0, nulf, 0, 0, SA0, RS, RC, 1024);
        split_t<<<dim3(32, 32), dim3(32, 8), 0, stream>>>(TP, SB2);
        STEP64(SA0, RS, RC, SB2, TP, RS, RC, 0, nulf, 0, 0, SAP, RS, RC, 1024);
        split_t<<<dim3(32, 32), dim3(32, 8), 0, stream>>>(TP, SB4);
        STEP64(SAP, RS, RC, SB4, TP, RS, RC, 0, nulf, 0, 0, SA0, RS, RC, 1024);
        split_t<<<dim3(32, 32), dim3(32, 8), 0, stream>>>(TP, SB8b);
        STEP64(SA0, RS, RC, SB8b, TP, RS, RC, 0, nulf, 0, 0, nuls, 0, 0, 1024);
        split_t<<<dim3(32, 32), dim3(32, 8), 0, stream>>>(TP, SBP);

        split_a<<<dim3(1, HH), 256, 0, stream>>>(rec, LH, CH, SA0, RS, RC, HM);
        for (int o = 1; o < CC; ++o) {
            short* Ain = (o & 1) ? SA0 : SA1;
            short* Sot = (o & 1) ? SA1 : SA0;
            STEP64(Ain, RS, RC, SBM,
                   rec + (size_t)o * HH, LH, CH, 1, nulf, 0, 0,
                   Sot, RS, RC, 1024);
        }
        for (int c = 1; c < NC; ++c)
            STEP32(SA1 + (size_t)(c - 1) * 32 * HH, RS, 0, SBP,
                   rec + ((size_t)c * CC + CC - 1) * HH, LH, 0, 1, nulf, 0, 0,
                   SA1 + (size_t)c * 32 * HH, RS, 0, 1);
        for (int o = 0; o < CC - 1; ++o) {
            short* Ain = (o & 1) ? SA0 : SA1;
            short* Sot = (o & 1) ? SA1 : SA0;
            STEP64(Ain, RS, RC, SBM,
                   nulf, 0, 0, 0,
                   rec + (size_t)(CC + o) * HH, LH, CH,
                   (o == CC - 2) ? nuls : Sot, RS, RC, 992);
        }
        STEP32(SA1 + (size_t)992 * HH, RS, 0, SBM, outp, PB, 0, 0, nulf, 0, 0, SA0, RS, 0, 1);
        STEP32(SA0, RS, 0, SBM, outp + HH, PB, 0, 0, nulf, 0, 0, SA0 + (size_t)32 * HH, RS, 0, 1);
        STEP32(SA0, RS, RC, SB2, outp + 2 * HH, PB, RS, 0, nulf, 0, 0, SA0 + (size_t)2 * 32 * HH, RS, RC, 2);
        STEP32(SA0, RS, RC, SB4, outp + 4 * HH, PB, RS, 0, nulf, 0, 0, SA0 + (size_t)4 * 32 * HH, RS, RC, 4);
        STEP32(SA0, RS, RC, SB8b, outp + 8 * HH, PB, RS, 0, nulf, 0, 0, SA0 + (size_t)8 * 32 * HH, RS, RC, 8);
        STEP64(SA0, RS, RC, SBP, outp + 16 * HH, PB, RS, 0, nulf, 0, 0, nuls, 0, 0, 512);

        ln_k<<<BB * PRED, 256, 0, stream>>>(outp, ln_w, ln_b);
        return;
    }

    // ============ tier C: R7 tier-B, CC=16, rolling powers (34 MiB) ============
    transpose_k<<<dim3(32, 32), dim3(32, 8), 0, stream>>>(Whh, TP);
    split_a<<<dim3(1, HH), 256, 0, stream>>>(Wxh, RS, RC, SBP, RS, RC, HM);
    gemm_mx<<<dim3(16, 128), 256, 0, stream>>>(x, SBP, rec);
    split_a<<<dim3(1, HH), 256, 0, stream>>>(TP, RS, RC, SAP, RS, RC, HM);
    split_t<<<dim3(32, 32), dim3(32, 8), 0, stream>>>(TP, SBM);

    STEP64(SAP, RS, RC, SBM, TP, RS, RC, 0, nulf, 0, 0, SA0, RS, RC, 1024);
    split_t<<<dim3(32, 32), dim3(32, 8), 0, stream>>>(TP, SBP);
    STEP64(SA0, RS, RC, SBP, TP, RS, RC, 0, nulf, 0, 0, SAP, RS, RC, 1024);
    split_t<<<dim3(32, 32), dim3(32, 8), 0, stream>>>(TP, SBP);
    STEP64(SAP, RS, RC, SBP, TP, RS, RC, 0, nulf, 0, 0, SA0, RS, RC, 1024);
    split_t<<<dim3(32, 32), dim3(32, 8), 0, stream>>>(TP, SBP);
    STEP64(SA0, RS, RC, SBP, TP, RS, RC, 0, nulf, 0, 0, nuls, 0, 0, 1024);
    split_t<<<dim3(32, 32), dim3(32, 8), 0, stream>>>(TP, SBP);

    split_a<<<dim3(1, HH), 256, 0, stream>>>(rec, LH, CH, SA0, RS, RC, HM);
    for (int o = 1; o < CC; ++o) {
        short* Ain = (o & 1) ? SA0 : SA1;
        short* Sot = (o & 1) ? SA1 : SA0;
        STEP64(Ain, RS, RC, SBM,
               rec + (size_t)o * HH, LH, CH, 1, nulf, 0, 0,
               Sot, RS, RC, 1024);
    }
    for (int c = 1; c < NC; ++c)
        STEP32(SA1 + (size_t)(c - 1) * 32 * HH, RS, 0, SBP,
               rec + ((size_t)c * CC + CC - 1) * HH, LH, 0, 1, nulf, 0, 0,
               SA1 + (size_t)c * 32 * HH, RS, 0, 1);
    for (int o = 0; o < CC - 1; ++o) {
        short* Ain = (o & 1) ? SA0 : SA1;
        short* Sot = (o & 1) ? SA1 : SA0;
        STEP64(Ain, RS, RC, SBM,
               nulf, 0, 0, 0,
               rec + (size_t)(CC + o) * HH, LH, CH,
               (o == CC - 2) ? nuls : Sot, RS, RC, 992);
    }
    STEP32(SA1 + (size_t)992 * HH, RS, 0, SBM, outp, PB, 0, 0, nulf, 0, 0, SA0, RS, 0, 1);
    STEP32(SA0, RS, 0, SBM, outp + HH, PB, 0, 0, nulf, 0, 0, SA0 + (size_t)32 * HH, RS, 0, 1);
    tr_splits<<<dim3(32, 32, 3), dim3(32, 8), 0, stream>>>(SBM, SAP);
    STEP64(SAP, RS, RC, SBM, TP, RS, RC, 0, nulf, 0, 0, SA1, RS, RC, 1024);
    split_t<<<dim3(32, 32), dim3(32, 8), 0, stream>>>(TP, SBP);
    STEP32(SA0, RS, RC, SBP, outp + 2 * HH, PB, RS, 0, nulf, 0, 0, SA0 + (size_t)2 * 32 * HH, RS, RC, 2);
    STEP64(SA1, RS, RC, SBP, TP, RS, RC, 0, nulf, 0, 0, SAP, RS, RC, 1024);
    split_t<<<dim3(32, 32), dim3(32, 8), 0, stream>>>(TP, SBP);
    STEP32(SA0, RS, RC, SBP, outp + 4 * HH, PB, RS, 0, nulf, 0, 0, SA0 + (size_t)4 * 32 * HH, RS, RC, 4);
    STEP64(SAP, RS, RC, SBP, TP, RS, RC, 0, nulf, 0, 0, SA1, RS, RC, 1024);
    split_t<<<dim3(32, 32), dim3(32, 8), 0, stream>>>(TP, SBP);
    STEP32(SA0, RS, RC, SBP, outp + 8 * HH, PB, RS, 0, nulf, 0, 0, SA0 + (size_t)8 * 32 * HH, RS, RC, 8);
    STEP64(SA1, RS, RC, SBP, TP, RS, RC, 0, nulf, 0, 0, nuls, 0, 0, 1024);
    split_t<<<dim3(32, 32), dim3(32, 8), 0, stream>>>(TP, SBP);
    STEP64(SA0, RS, RC, SBP, outp + 16 * HH, PB, RS, 0, nulf, 0, 0, nuls, 0, 0, 512);

    ln_k<<<BB * PRED, 256, 0, stream>>>(outp, ln_w, ln_b);
    #undef STEP64
    #undef STEP32
}

// Round 9
// 1498.304 us; speedup vs baseline: 8.8749x; 1.0024x over previous
//
#include <hip/hip_runtime.h>

#define BB 32
#define LL 512
#define HH 1024
#define PRED 32
#define C8 8             // chunk length
#define NC8 (LL / C8)    // 64 chunks
#define LN_EPS 1e-5f

typedef short bf16x8 __attribute__((ext_vector_type(8)));
typedef short s16x4  __attribute__((ext_vector_type(4)));
typedef float f32x4  __attribute__((ext_vector_type(4)));

static __device__ __forceinline__ void split3(float x, short& h, short& m, short& l) {
    unsigned u = __float_as_uint(x);
    unsigned rh = (u + 0x7fffu + ((u >> 16) & 1u)) & 0xffff0000u;
    h = (short)(rh >> 16);
    float x1 = x - __uint_as_float(rh);
    unsigned u1 = __float_as_uint(x1);
    unsigned rm = (u1 + 0x7fffu + ((u1 >> 16) & 1u)) & 0xffff0000u;
    m = (short)(rm >> 16);
    float x2 = x1 - __uint_as_float(rm);
    unsigned u2 = __float_as_uint(x2);
    unsigned rl = (u2 + 0x7fffu + ((u2 >> 16) & 1u)) & 0xffff0000u;
    l = (short)(rl >> 16);
}

static __device__ __forceinline__ void split2(float x, short& h, short& m) {
    unsigned u = __float_as_uint(x);
    unsigned rh = (u + 0x7fffu + ((u >> 16) & 1u)) & 0xffff0000u;
    h = (short)(rh >> 16);
    float x1 = x - __uint_as_float(rh);
    unsigned u1 = __float_as_uint(x1);
    unsigned rm = (u1 + 0x7fffu + ((u1 >> 16) & 1u)) & 0xffff0000u;
    m = (short)(rm >> 16);
}

#define MFMA6(ACC, AH, AM, AL, BH, BM, BL) \
    ACC = __builtin_amdgcn_mfma_f32_16x16x32_bf16(AL, BH, ACC, 0, 0, 0); \
    ACC = __builtin_amdgcn_mfma_f32_16x16x32_bf16(AH, BL, ACC, 0, 0, 0); \
    ACC = __builtin_amdgcn_mfma_f32_16x16x32_bf16(AM, BM, ACC, 0, 0, 0); \
    ACC = __builtin_amdgcn_mfma_f32_16x16x32_bf16(AM, BH, ACC, 0, 0, 0); \
    ACC = __builtin_amdgcn_mfma_f32_16x16x32_bf16(AH, BM, ACC, 0, 0, 0); \
    ACC = __builtin_amdgcn_mfma_f32_16x16x32_bf16(AH, BH, ACC, 0, 0, 0);

// ---------------------------------------------------------------------------
__global__ __launch_bounds__(256) void transpose_k(const float* __restrict__ in,
                                                   float* __restrict__ out) {
    __shared__ float tile[32][33];
    int bx = blockIdx.x * 32, by = blockIdx.y * 32;
    int tx = threadIdx.x, ty = threadIdx.y;
    #pragma unroll
    for (int i = 0; i < 32; i += 8)
        tile[ty + i][tx] = in[(size_t)(by + ty + i) * HH + bx + tx];
    __syncthreads();
    #pragma unroll
    for (int i = 0; i < 32; i += 8)
        out[(size_t)(bx + ty + i) * HH + by + tx] = tile[tx][ty + i];
}

// ---------------------------------------------------------------------------
__global__ __launch_bounds__(256) void split_a(const float* __restrict__ src, long sb, long sc,
                                               short* __restrict__ dst, long dsb, long dsc,
                                               long ps) {
    int r = blockIdx.y;
    const float* s = src + (long)(r & 31) * sb + (long)(r >> 5) * sc + threadIdx.x * 4;
    short* d = dst + (long)(r & 31) * dsb + (long)(r >> 5) * dsc + threadIdx.x * 4;
    float4 v = *(const float4*)s;
    float xs[4] = {v.x, v.y, v.z, v.w};
    s16x4 vh, vm, vl;
    #pragma unroll
    for (int j = 0; j < 4; ++j) {
        short h, m, l;
        split3(xs[j], h, m, l);
        vh[j] = h; vm[j] = m; vl[j] = l;
    }
    *(s16x4*)(d) = vh;
    *(s16x4*)(d + ps) = vm;
    *(s16x4*)(d + 2 * ps) = vl;
}

// ---------------------------------------------------------------------------
__global__ __launch_bounds__(256) void split_t(const float* __restrict__ in,
                                               short* __restrict__ out) {
    const size_t HM = (size_t)HH * HH;
    __shared__ float tile[32][33];
    int n0 = blockIdx.x * 32, k0 = blockIdx.y * 32;
    int tx = threadIdx.x, ty = threadIdx.y;
    #pragma unroll
    for (int i = 0; i < 32; i += 8)
        tile[ty + i][tx] = in[(size_t)(k0 + ty + i) * HH + n0 + tx];
    __syncthreads();
    #pragma unroll
    for (int i = 0; i < 32; i += 8) {
        float v = tile[tx][ty + i];
        short h, m, l;
        split3(v, h, m, l);
        size_t o = (size_t)(n0 + ty + i) * HH + k0 + tx;
        out[o] = h; out[HM + o] = m; out[2 * HM + o] = l;
    }
}

// ---------------------------------------------------------------------------
__global__ __launch_bounds__(256) void tr_splits(const short* __restrict__ in,
                                                 short* __restrict__ out) {
    const size_t HM = (size_t)HH * HH;
    __shared__ short tile[32][33];
    int p = blockIdx.z;
    int k0 = blockIdx.x * 32, n0 = blockIdx.y * 32;
    int tx = threadIdx.x, ty = threadIdx.y;
    #pragma unroll
    for (int i = 0; i < 32; i += 8)
        tile[ty + i][tx] = in[p * HM + (size_t)(n0 + ty + i) * HH + k0 + tx];
    __syncthreads();
    #pragma unroll
    for (int i = 0; i < 32; i += 8)
        out[p * HM + (size_t)(k0 + ty + i) * HH + n0 + tx] = tile[tx][ty + i];
}

// ---------------------------------------------------------------------------
__global__ __launch_bounds__(256) void copy_splits(const short* __restrict__ src,
                                                   short* __restrict__ dst, long ps) {
    size_t off = (size_t)blockIdx.x * HH + threadIdx.x * 4;
    *(s16x4*)(dst + off)          = *(const s16x4*)(src + off);
    *(s16x4*)(dst + ps + off)     = *(const s16x4*)(src + ps + off);
    *(s16x4*)(dst + 2 * ps + off) = *(const s16x4*)(src + 2 * ps + off);
}

// ---------------------------------------------------------------------------
// gemm_mx: C[m][n] = sum_k x[m][k]*W[n][k], MFMA bf16 2x2 split (proven R7).
// ---------------------------------------------------------------------------
__global__ __launch_bounds__(256) void gemm_mx(const float* __restrict__ A,
                                               const short* __restrict__ SB,
                                               float* __restrict__ C) {
    const size_t HM = (size_t)HH * HH;
    __shared__ __align__(16) short As2[2][128][40];
    __shared__ __align__(16) short Bs2[2][64][40];
    const int tid = threadIdx.x;
    const int lane = tid & 63;
    const int w = tid >> 6;
    const int n0 = blockIdx.x * 64;
    const int m0 = blockIdx.y * 128;
    const int ar = tid >> 1;
    const int akc = (tid & 1) * 16;
    const float* Arow = A + (size_t)(m0 + ar) * HH + akc;
    const int bp = tid >> 7;
    const int bnr = tid & 63;
    const int bkh = ((tid >> 6) & 1) * 16;
    const short* Brow = SB + bp * HM + (size_t)(n0 + bnr) * HH + bkh;
    const int fr = lane & 15;
    const int fk = (lane >> 4) * 8;

    f32x4 acc[2][4] = {};

    float4 av0 = *(const float4*)(Arow);
    float4 av1 = *(const float4*)(Arow + 4);
    float4 av2 = *(const float4*)(Arow + 8);
    float4 av3 = *(const float4*)(Arow + 12);
    bf16x8 rb0 = *(const bf16x8*)(Brow);
    bf16x8 rb1 = *(const bf16x8*)(Brow + 8);

    for (int kt = 0; kt < HH; kt += 32) {
        float xs[16] = {av0.x, av0.y, av0.z, av0.w, av1.x, av1.y, av1.z, av1.w,
                        av2.x, av2.y, av2.z, av2.w, av3.x, av3.y, av3.z, av3.w};
        bf16x8 vh0, vm0, vh1, vm1;
        #pragma unroll
        for (int j = 0; j < 8; ++j) {
            short h, m;
            split2(xs[j], h, m);
            vh0[j] = h; vm0[j] = m;
            split2(xs[j + 8], h, m);
            vh1[j] = h; vm1[j] = m;
        }
        *(bf16x8*)&As2[0][ar][akc]     = vh0;
        *(bf16x8*)&As2[0][ar][akc + 8] = vh1;
        *(bf16x8*)&As2[1][ar][akc]     = vm0;
        *(bf16x8*)&As2[1][ar][akc + 8] = vm1;
        *(bf16x8*)&Bs2[bp][bnr][bkh]     = rb0;
        *(bf16x8*)&Bs2[bp][bnr][bkh + 8] = rb1;
        __syncthreads();
        if (kt + 32 < HH) {
            const float* An = Arow + kt + 32;
            av0 = *(const float4*)(An);
            av1 = *(const float4*)(An + 4);
            av2 = *(const float4*)(An + 8);
            av3 = *(const float4*)(An + 12);
            const short* Bn = Brow + kt + 32;
            rb0 = *(const bf16x8*)(Bn);
            rb1 = *(const bf16x8*)(Bn + 8);
        }
        bf16x8 ah[2], am[2];
        #pragma unroll
        for (int i = 0; i < 2; ++i) {
            ah[i] = *(const bf16x8*)&As2[0][w * 32 + i * 16 + fr][fk];
            am[i] = *(const bf16x8*)&As2[1][w * 32 + i * 16 + fr][fk];
        }
        #pragma unroll
        for (int j = 0; j < 4; ++j) {
            bf16x8 bh = *(const bf16x8*)&Bs2[0][j * 16 + fr][fk];
            bf16x8 bm = *(const bf16x8*)&Bs2[1][j * 16 + fr][fk];
            #pragma unroll
            for (int i = 0; i < 2; ++i) {
                f32x4 a = acc[i][j];
                a = __builtin_amdgcn_mfma_f32_16x16x32_bf16(am[i], bm, a, 0, 0, 0);
                a = __builtin_amdgcn_mfma_f32_16x16x32_bf16(am[i], bh, a, 0, 0, 0);
                a = __builtin_amdgcn_mfma_f32_16x16x32_bf16(ah[i], bm, a, 0, 0, 0);
                a = __builtin_amdgcn_mfma_f32_16x16x32_bf16(ah[i], bh, a, 0, 0, 0);
                acc[i][j] = a;
            }
        }
        __syncthreads();
    }
    const int orow = (lane >> 4) * 4;
    #pragma unroll
    for (int i = 0; i < 2; ++i)
        #pragma unroll
        for (int j = 0; j < 4; ++j) {
            int c = n0 + j * 16 + fr;
            #pragma unroll
            for (int reg = 0; reg < 4; ++reg) {
                int r = m0 + w * 32 + i * 16 + orow + reg;
                C[(size_t)r * HH + c] = acc[i][j][reg];
            }
        }
}

// ---------------------------------------------------------------------------
// step_b: batched multi-descriptor bf16x6 MFMA GEMM.
// 256 thr, 4 waves; block 128(M)x64(N); wave tile 32x64 (18 ds_read : 48 MFMA).
// Group g = blockIdx.y / ypg selects descriptor (A, B, O, P, S pointers).
// Shared strides; row guard r < nrows.
// ---------------------------------------------------------------------------
struct GD  { const short* A; const short* B; float* O; float* P; short* S; };
struct GD8 { GD g[8]; };

__global__ __launch_bounds__(256) void step_b(
    GD8 dsc, int ypg,
    long sab, long sac, long psA,
    long sob, long soc, int add,
    long spb, long spc,
    long ssb, long ssc, long psS,
    int nrows) {
    const size_t HM = (size_t)HH * HH;
    __shared__ __align__(16) short As[3][128][40];
    __shared__ __align__(16) short Bs[3][64][40];
    const int tid = threadIdx.x;
    const int lane = tid & 63;
    const int w = tid >> 6;              // wave owns rows w*32..w*32+31, all 64 cols
    const int grp = blockIdx.y / ypg;
    const int yy  = blockIdx.y % ypg;
    const int n0 = blockIdx.x * 64;
    const int m0 = yy * 128;
    const GD d = dsc.g[grp];
    // A staging: 128 rows x 32k x 3 planes; thread: row tid>>1, k-half (tid&1)*16
    const int ar = tid >> 1;
    const int akh = (tid & 1) * 16;
    const int agr = m0 + ar;
    const short* Arow = d.A + (long)(agr & 31) * sab + (long)(agr >> 5) * sac + akh;
    // B staging: 64 rows x 32k x 3 planes; thread: row tid>>2, k-chunk (tid&3)*8
    const int br = tid >> 2;
    const int bkc = (tid & 3) * 8;
    const short* Brow = d.B + (size_t)(n0 + br) * HH + bkc;
    const int fr = lane & 15;
    const int fk = (lane >> 4) * 8;

    f32x4 acc[2][4] = {};

    bf16x8 ra[6], rb[3];
    #pragma unroll
    for (int p = 0; p < 3; ++p) {
        ra[2 * p]     = *(const bf16x8*)(Arow + p * psA);
        ra[2 * p + 1] = *(const bf16x8*)(Arow + p * psA + 8);
        rb[p]         = *(const bf16x8*)(Brow + p * HM);
    }
    for (int kt = 0; kt < HH; kt += 32) {
        #pragma unroll
        for (int p = 0; p < 3; ++p) {
            *(bf16x8*)&As[p][ar][akh]     = ra[2 * p];
            *(bf16x8*)&As[p][ar][akh + 8] = ra[2 * p + 1];
            *(bf16x8*)&Bs[p][br][bkc]     = rb[p];
        }
        __syncthreads();
        if (kt + 32 < HH) {
            #pragma unroll
            for (int p = 0; p < 3; ++p) {
                ra[2 * p]     = *(const bf16x8*)(Arow + p * psA + kt + 32);
                ra[2 * p + 1] = *(const bf16x8*)(Arow + p * psA + kt + 40);
                rb[p]         = *(const bf16x8*)(Brow + p * HM + kt + 32);
            }
        }
        bf16x8 af[3][2], bfr[3][4];
        #pragma unroll
        for (int p = 0; p < 3; ++p) {
            #pragma unroll
            for (int mf = 0; mf < 2; ++mf)
                af[p][mf] = *(const bf16x8*)&As[p][w * 32 + mf * 16 + fr][fk];
            #pragma unroll
            for (int nf = 0; nf < 4; ++nf)
                bfr[p][nf] = *(const bf16x8*)&Bs[p][nf * 16 + fr][fk];
        }
        #pragma unroll
        for (int mf = 0; mf < 2; ++mf)
            #pragma unroll
            for (int nf = 0; nf < 4; ++nf) {
                MFMA6(acc[mf][nf], af[0][mf], af[1][mf], af[2][mf],
                      bfr[0][nf], bfr[1][nf], bfr[2][nf])
            }
        __syncthreads();
    }
    const int orow = (lane >> 4) * 4;
    #pragma unroll
    for (int mf = 0; mf < 2; ++mf)
        #pragma unroll
        for (int nf = 0; nf < 4; ++nf) {
            int c = n0 + nf * 16 + fr;
            #pragma unroll
            for (int reg = 0; reg < 4; ++reg) {
                int r = m0 + w * 32 + mf * 16 + orow + reg;
                if (r >= nrows) continue;
                long rb_ = (long)(r & 31), rc_ = (long)(r >> 5);
                float val = acc[mf][nf][reg];
                if (d.O) {
                    float* p = d.O + rb_ * sob + rc_ * soc + c;
                    if (add) val += *p;
                    *p = val;
                }
                if (d.P) {
                    float* q = d.P + rb_ * spb + rc_ * spc + c;
                    *q += val;
                }
                if (d.S) {
                    short h, m, l;
                    split3(val, h, m, l);
                    short* s = d.S + rb_ * ssb + rc_ * ssc + c;
                    s[0] = h; s[psS] = m; s[2 * psS] = l;
                }
            }
        }
}

// ---------------------------------------------------------------------------
// step_p: bf16x6 MFMA, pre-split A/B. 32x64, 128 thr. (proven; fallback)
// ---------------------------------------------------------------------------
__global__ __launch_bounds__(128) void step_p(
    const short* __restrict__ SA, long sab, long sac, long psA,
    const short* __restrict__ SB,
    float* __restrict__ O, long sob, long soc, int add,
    float* __restrict__ P, long spb, long spc,
    short* __restrict__ S, long ssb, long ssc, long psS) {
    const size_t HM = (size_t)HH * HH;
    __shared__ __align__(16) short As[3][32][40];
    __shared__ __align__(16) short Bs[3][64][40];
    const int tid = threadIdx.x;
    const int lane = tid & 63;
    const int w = tid >> 6;
    const int n0 = blockIdx.x * 64;
    const int m0 = blockIdx.y * 32;
    const int ar = tid >> 2;
    const int akc = (tid & 3) * 8;
    const int agr = m0 + ar;
    const short* Arow = SA + (long)(agr & 31) * sab + (long)(agr >> 5) * sac + akc;
    const int bnr = tid & 63;
    const int bkh = (tid >> 6) * 16;
    const short* Brow = SB + (size_t)(n0 + bnr) * HH + bkh;
    const int fr = lane & 15;
    const int fk = (lane >> 4) * 8;
    f32x4 acc00 = 0, acc01 = 0, acc10 = 0, acc11 = 0;
    bf16x8 ra0 = *(const bf16x8*)(Arow);
    bf16x8 ra1 = *(const bf16x8*)(Arow + psA);
    bf16x8 ra2 = *(const bf16x8*)(Arow + 2 * psA);
    bf16x8 rb0 = *(const bf16x8*)(Brow);
    bf16x8 rb1 = *(const bf16x8*)(Brow + 8);
    bf16x8 rb2 = *(const bf16x8*)(Brow + HM);
    bf16x8 rb3 = *(const bf16x8*)(Brow + HM + 8);
    bf16x8 rb4 = *(const bf16x8*)(Brow + 2 * HM);
    bf16x8 rb5 = *(const bf16x8*)(Brow + 2 * HM + 8);
    for (int kt = 0; kt < HH; kt += 32) {
        *(bf16x8*)&As[0][ar][akc] = ra0;
        *(bf16x8*)&As[1][ar][akc] = ra1;
        *(bf16x8*)&As[2][ar][akc] = ra2;
        *(bf16x8*)&Bs[0][bnr][bkh] = rb0;
        *(bf16x8*)&Bs[0][bnr][bkh + 8] = rb1;
        *(bf16x8*)&Bs[1][bnr][bkh] = rb2;
        *(bf16x8*)&Bs[1][bnr][bkh + 8] = rb3;
        *(bf16x8*)&Bs[2][bnr][bkh] = rb4;
        *(bf16x8*)&Bs[2][bnr][bkh + 8] = rb5;
        __syncthreads();
        if (kt + 32 < HH) {
            const short* An = Arow + kt + 32;
            const short* Bn = Brow + kt + 32;
            ra0 = *(const bf16x8*)(An);
            ra1 = *(const bf16x8*)(An + psA);
            ra2 = *(const bf16x8*)(An + 2 * psA);
            rb0 = *(const bf16x8*)(Bn);
            rb1 = *(const bf16x8*)(Bn + 8);
            rb2 = *(const bf16x8*)(Bn + HM);
            rb3 = *(const bf16x8*)(Bn + HM + 8);
            rb4 = *(const bf16x8*)(Bn + 2 * HM);
            rb5 = *(const bf16x8*)(Bn + 2 * HM + 8);
        }
        bf16x8 a00 = *(const bf16x8*)&As[0][fr][fk];
        bf16x8 a01 = *(const bf16x8*)&As[0][16 + fr][fk];
        bf16x8 a10 = *(const bf16x8*)&As[1][fr][fk];
        bf16x8 a11 = *(const bf16x8*)&As[1][16 + fr][fk];
        bf16x8 a20 = *(const bf16x8*)&As[2][fr][fk];
        bf16x8 a21 = *(const bf16x8*)&As[2][16 + fr][fk];
        bf16x8 b00 = *(const bf16x8*)&Bs[0][w * 32 + fr][fk];
        bf16x8 b01 = *(const bf16x8*)&Bs[0][w * 32 + 16 + fr][fk];
        bf16x8 b10 = *(const bf16x8*)&Bs[1][w * 32 + fr][fk];
        bf16x8 b11 = *(const bf16x8*)&Bs[1][w * 32 + 16 + fr][fk];
        bf16x8 b20 = *(const bf16x8*)&Bs[2][w * 32 + fr][fk];
        bf16x8 b21 = *(const bf16x8*)&Bs[2][w * 32 + 16 + fr][fk];
        MFMA6(acc00, a00, a10, a20, b00, b10, b20)
        MFMA6(acc01, a00, a10, a20, b01, b11, b21)
        MFMA6(acc10, a01, a11, a21, b00, b10, b20)
        MFMA6(acc11, a01, a11, a21, b01, b11, b21)
        __syncthreads();
    }
    const int orow = (lane >> 4) * 4;
    #pragma unroll
    for (int mf = 0; mf < 2; ++mf) {
        #pragma unroll
        for (int nf = 0; nf < 2; ++nf) {
            f32x4 v = mf == 0 ? (nf == 0 ? acc00 : acc01) : (nf == 0 ? acc10 : acc11);
            int c = n0 + w * 32 + nf * 16 + fr;
            #pragma unroll
            for (int reg = 0; reg < 4; ++reg) {
                int r = m0 + mf * 16 + orow + reg;
                long rb = (long)(r & 31), rc = (long)(r >> 5);
                float val = v[reg];
                if (O) {
                    float* p = O + rb * sob + rc * soc + c;
                    if (add) val += *p;
                    *p = val;
                }
                if (P) { float* q = P + rb * spb + rc * spc + c; *q += val; }
                if (S) {
                    short h, m, l;
                    split3(val, h, m, l);
                    short* s = S + rb * ssb + rc * ssc + c;
                    s[0] = h; s[psS] = m; s[2 * psS] = l;
                }
            }
        }
    }
}

// ---------------------------------------------------------------------------
// step_p64: bf16x6 MFMA, 64x64, 256 thr (2x2 waves), row guard. (fallback)
// ---------------------------------------------------------------------------
__global__ __launch_bounds__(256) void step_p64(
    const short* __restrict__ SA, long sab, long sac, long psA,
    const short* __restrict__ SB,
    float* __restrict__ O, long sob, long soc, int add,
    float* __restrict__ P, long spb, long spc,
    short* __restrict__ S, long ssb, long ssc, long psS,
    int nrows) {
    const size_t HM = (size_t)HH * HH;
    __shared__ __align__(16) short As[3][64][40];
    __shared__ __align__(16) short Bs[3][64][40];
    const int tid = threadIdx.x;
    const int lane = tid & 63;
    const int w = tid >> 6;
    const int wr = w & 1;
    const int wc = w >> 1;
    const int n0 = blockIdx.x * 64;
    const int m0 = blockIdx.y * 64;
    const int ar = tid >> 2;
    const int akc = (tid & 3) * 8;
    const int agr = m0 + ar;
    const short* Arow = SA + (long)(agr & 31) * sab + (long)(agr >> 5) * sac + akc;
    const short* Brow = SB + (size_t)(n0 + ar) * HH + akc;
    const int fr = lane & 15;
    const int fk = (lane >> 4) * 8;
    f32x4 acc00 = 0, acc01 = 0, acc10 = 0, acc11 = 0;
    bf16x8 ra0 = *(const bf16x8*)(Arow);
    bf16x8 ra1 = *(const bf16x8*)(Arow + psA);
    bf16x8 ra2 = *(const bf16x8*)(Arow + 2 * psA);
    bf16x8 rb0 = *(const bf16x8*)(Brow);
    bf16x8 rb1 = *(const bf16x8*)(Brow + HM);
    bf16x8 rb2 = *(const bf16x8*)(Brow + 2 * HM);
    for (int kt = 0; kt < HH; kt += 32) {
        *(bf16x8*)&As[0][ar][akc] = ra0;
        *(bf16x8*)&As[1][ar][akc] = ra1;
        *(bf16x8*)&As[2][ar][akc] = ra2;
        *(bf16x8*)&Bs[0][ar][akc] = rb0;
        *(bf16x8*)&Bs[1][ar][akc] = rb1;
        *(bf16x8*)&Bs[2][ar][akc] = rb2;
        __syncthreads();
        if (kt + 32 < HH) {
            const short* An = Arow + kt + 32;
            const short* Bn = Brow + kt + 32;
            ra0 = *(const bf16x8*)(An);
            ra1 = *(const bf16x8*)(An + psA);
            ra2 = *(const bf16x8*)(An + 2 * psA);
            rb0 = *(const bf16x8*)(Bn);
            rb1 = *(const bf16x8*)(Bn + HM);
            rb2 = *(const bf16x8*)(Bn + 2 * HM);
        }
        bf16x8 a00 = *(const bf16x8*)&As[0][wr * 32 + fr][fk];
        bf16x8 a01 = *(const bf16x8*)&As[0][wr * 32 + 16 + fr][fk];
        bf16x8 a10 = *(const bf16x8*)&As[1][wr * 32 + fr][fk];
        bf16x8 a11 = *(const bf16x8*)&As[1][wr * 32 + 16 + fr][fk];
        bf16x8 a20 = *(const bf16x8*)&As[2][wr * 32 + fr][fk];
        bf16x8 a21 = *(const bf16x8*)&As[2][wr * 32 + 16 + fr][fk];
        bf16x8 b00 = *(const bf16x8*)&Bs[0][wc * 32 + fr][fk];
        bf16x8 b01 = *(const bf16x8*)&Bs[0][wc * 32 + 16 + fr][fk];
        bf16x8 b10 = *(const bf16x8*)&Bs[1][wc * 32 + fr][fk];
        bf16x8 b11 = *(const bf16x8*)&Bs[1][wc * 32 + 16 + fr][fk];
        bf16x8 b20 = *(const bf16x8*)&Bs[2][wc * 32 + fr][fk];
        bf16x8 b21 = *(const bf16x8*)&Bs[2][wc * 32 + 16 + fr][fk];
        MFMA6(acc00, a00, a10, a20, b00, b10, b20)
        MFMA6(acc01, a00, a10, a20, b01, b11, b21)
        MFMA6(acc10, a01, a11, a21, b00, b10, b20)
        MFMA6(acc11, a01, a11, a21, b01, b11, b21)
        __syncthreads();
    }
    const int orow = (lane >> 4) * 4;
    #pragma unroll
    for (int mf = 0; mf < 2; ++mf) {
        #pragma unroll
        for (int nf = 0; nf < 2; ++nf) {
            f32x4 v = mf == 0 ? (nf == 0 ? acc00 : acc01) : (nf == 0 ? acc10 : acc11);
            int c = n0 + wc * 32 + nf * 16 + fr;
            #pragma unroll
            for (int reg = 0; reg < 4; ++reg) {
                int r = m0 + wr * 32 + mf * 16 + orow + reg;
                if (r >= nrows) continue;
                long rb = (long)(r & 31), rc = (long)(r >> 5);
                float val = v[reg];
                if (O) {
                    float* p = O + rb * sob + rc * soc + c;
                    if (add) val += *p;
                    *p = val;
                }
                if (P) { float* q = P + rb * spb + rc * spc + c; *q += val; }
                if (S) {
                    short h, m, l;
                    split3(val, h, m, l);
                    short* s = S + rb * ssb + rc * ssc + c;
                    s[0] = h; s[psS] = m; s[2 * psS] = l;
                }
            }
        }
    }
}

// ---------------------------------------------------------------------------
// step_p128: bf16x6 MFMA, 128x64, 512 thr (4x2 waves), row guard. (proven)
// ---------------------------------------------------------------------------
__global__ __launch_bounds__(512) void step_p128(
    const short* __restrict__ SA, long sab, long sac, long psA,
    const short* __restrict__ SB,
    float* __restrict__ O, long sob, long soc, int add,
    float* __restrict__ P, long spb, long spc,
    short* __restrict__ S, long ssb, long ssc, long psS,
    int nrows) {
    const size_t HM = (size_t)HH * HH;
    __shared__ __align__(16) short As[3][128][40];
    __shared__ __align__(16) short Bs[3][64][40];
    const int tid = threadIdx.x;
    const int lane = tid & 63;
    const int w = tid >> 6;
    const int wr = w & 3;
    const int wc = w >> 2;
    const int n0 = blockIdx.x * 64;
    const int m0 = blockIdx.y * 128;
    const int ar = tid >> 2;
    const int akc = (tid & 3) * 8;
    const int agr = m0 + ar;
    const short* Arow = SA + (long)(agr & 31) * sab + (long)(agr >> 5) * sac + akc;
    const bool bst = (tid < 384);
    const int bp = (tid >> 7) == 3 ? 2 : (tid >> 7);
    const int bt = tid & 127;
    const int bnr = bt >> 1;
    const int bkh = (bt & 1) * 16;
    const short* Brow = SB + (size_t)bp * HM + (size_t)(n0 + bnr) * HH + bkh;
    const int fr = lane & 15;
    const int fk = (lane >> 4) * 8;
    f32x4 acc00 = 0, acc01 = 0, acc10 = 0, acc11 = 0;
    bf16x8 ra0 = *(const bf16x8*)(Arow);
    bf16x8 ra1 = *(const bf16x8*)(Arow + psA);
    bf16x8 ra2 = *(const bf16x8*)(Arow + 2 * psA);
    bf16x8 rb0 = {}, rb1 = {};
    if (bst) { rb0 = *(const bf16x8*)(Brow); rb1 = *(const bf16x8*)(Brow + 8); }
    for (int kt = 0; kt < HH; kt += 32) {
        *(bf16x8*)&As[0][ar][akc] = ra0;
        *(bf16x8*)&As[1][ar][akc] = ra1;
        *(bf16x8*)&As[2][ar][akc] = ra2;
        if (bst) {
            *(bf16x8*)&Bs[bp][bnr][bkh]     = rb0;
            *(bf16x8*)&Bs[bp][bnr][bkh + 8] = rb1;
        }
        __syncthreads();
        if (kt + 32 < HH) {
            const short* An = Arow + kt + 32;
            ra0 = *(const bf16x8*)(An);
            ra1 = *(const bf16x8*)(An + psA);
            ra2 = *(const bf16x8*)(An + 2 * psA);
            if (bst) {
                const short* Bn = Brow + kt + 32;
                rb0 = *(const bf16x8*)(Bn);
                rb1 = *(const bf16x8*)(Bn + 8);
            }
        }
        bf16x8 a00 = *(const bf16x8*)&As[0][wr * 32 + fr][fk];
        bf16x8 a01 = *(const bf16x8*)&As[0][wr * 32 + 16 + fr][fk];
        bf16x8 a10 = *(const bf16x8*)&As[1][wr * 32 + fr][fk];
        bf16x8 a11 = *(const bf16x8*)&As[1][wr * 32 + 16 + fr][fk];
        bf16x8 a20 = *(const bf16x8*)&As[2][wr * 32 + fr][fk];
        bf16x8 a21 = *(const bf16x8*)&As[2][wr * 32 + 16 + fr][fk];
        bf16x8 b00 = *(const bf16x8*)&Bs[0][wc * 32 + fr][fk];
        bf16x8 b01 = *(const bf16x8*)&Bs[0][wc * 32 + 16 + fr][fk];
        bf16x8 b10 = *(const bf16x8*)&Bs[1][wc * 32 + fr][fk];
        bf16x8 b11 = *(const bf16x8*)&Bs[1][wc * 32 + 16 + fr][fk];
        bf16x8 b20 = *(const bf16x8*)&Bs[2][wc * 32 + fr][fk];
        bf16x8 b21 = *(const bf16x8*)&Bs[2][wc * 32 + 16 + fr][fk];
        MFMA6(acc00, a00, a10, a20, b00, b10, b20)
        MFMA6(acc01, a00, a10, a20, b01, b11, b21)
        MFMA6(acc10, a01, a11, a21, b00, b10, b20)
        MFMA6(acc11, a01, a11, a21, b01, b11, b21)
        __syncthreads();
    }
    const int orow = (lane >> 4) * 4;
    #pragma unroll
    for (int mf = 0; mf < 2; ++mf) {
        #pragma unroll
        for (int nf = 0; nf < 2; ++nf) {
            f32x4 v = mf == 0 ? (nf == 0 ? acc00 : acc01) : (nf == 0 ? acc10 : acc11);
            int c = n0 + wc * 32 + nf * 16 + fr;
            #pragma unroll
            for (int reg = 0; reg < 4; ++reg) {
                int r = m0 + wr * 32 + mf * 16 + orow + reg;
                if (r >= nrows) continue;
                long rb = (long)(r & 31), rc = (long)(r >> 5);
                float val = v[reg];
                if (O) {
                    float* p = O + rb * sob + rc * soc + c;
                    if (add) val += *p;
                    *p = val;
                }
                if (P) { float* q = P + rb * spb + rc * spc + c; *q += val; }
                if (S) {
                    short h, m, l;
                    split3(val, h, m, l);
                    short* s = S + rb * ssb + rc * ssc + c;
                    s[0] = h; s[psS] = m; s[2 * psS] = l;
                }
            }
        }
    }
}

// ---------------------------------------------------------------------------
__global__ __launch_bounds__(256) void ln_k(float* __restrict__ y,
                                            const float* __restrict__ w,
                                            const float* __restrict__ bia) {
    __shared__ float red[8];
    int row = blockIdx.x;
    float* p = y + (size_t)row * HH;
    int i4 = threadIdx.x * 4;
    float4 v = *(const float4*)&p[i4];
    float s = v.x + v.y + v.z + v.w;
    #pragma unroll
    for (int o = 32; o > 0; o >>= 1) s += __shfl_down(s, o, 64);
    int wid = threadIdx.x >> 6;
    if ((threadIdx.x & 63) == 0) red[wid] = s;
    __syncthreads();
    if (threadIdx.x == 0) red[4] = (red[0] + red[1] + red[2] + red[3]) * (1.f / HH);
    __syncthreads();
    float mu = red[4];
    float dx = v.x - mu, dy = v.y - mu, dz = v.z - mu, dw = v.w - mu;
    float q = dx * dx + dy * dy + dz * dz + dw * dw;
    #pragma unroll
    for (int o = 32; o > 0; o >>= 1) q += __shfl_down(q, o, 64);
    if ((threadIdx.x & 63) == 0) red[wid] = q;
    __syncthreads();
    if (threadIdx.x == 0) red[5] = (red[0] + red[1] + red[2] + red[3]) * (1.f / HH);
    __syncthreads();
    float rs = rsqrtf(red[5] + LN_EPS);
    float4 o4;
    o4.x = dx * rs * w[i4 + 0] + bia[i4 + 0];
    o4.y = dy * rs * w[i4 + 1] + bia[i4 + 1];
    o4.z = dz * rs * w[i4 + 2] + bia[i4 + 2];
    o4.w = dw * rs * w[i4 + 3] + bia[i4 + 3];
    *(float4*)&p[i4] = o4;
}

// ---------------------------------------------------------------------------
extern "C" void kernel_launch(void* const* d_in, const int* in_sizes, int n_in,
                              void* d_out, int out_size, void* d_ws, size_t ws_size,
                              hipStream_t stream) {
    const float* x    = (const float*)d_in[0];
    const float* Wxh  = (const float*)d_in[1];
    const float* Whh  = (const float*)d_in[2];
    const float* ln_w = (const float*)d_in[3];
    const float* ln_b = (const float*)d_in[4];

    const size_t MiB = 1024 * 1024;
    const long HM  = (long)HH * HH;
    const long PS2 = 2048L * HH;
    float* rec  = (float*)d_out;
    float* outp = rec + (size_t)BB * LL * HH;

    const long LH  = (long)LL * HH;
    const long CH8 = (long)C8 * HH;
    const long PB  = (long)PRED * HH;
    const long RS  = (long)HH;
    const long RC  = 32L * HH;
    float* nulf = (float*)nullptr;
    short* nuls = (short*)nullptr;
    char* wsb = (char*)d_ws;

    if (ws_size >= 124 * MiB) {
        // ================= tier NEW: batched stage3/pred (124 MiB) =================
        float* TP   = (float*)(wsb);                  // 4 MiB fp32 power temp
        short* SBW  = (short*)(wsb + 4  * MiB);       // B-splits of Wxh (early)
        float* T3a  = (float*)(wsb + 4  * MiB);       // M^3 fp32 (after gemm)
        float* T3c  = (float*)(wsb + 8  * MiB);       // M^5 fp32
        float* T3e  = (float*)(wsb + 12 * MiB);       // M^6 fp32
        short* PW   = (short*)(wsb + 16 * MiB);       // 8 x 6 MiB: B-splits M^1..M^8
        const size_t PWs = 3 * (size_t)HH * HH;
        short* SB16 = (short*)(wsb + 64 * MiB);
        short* SC32 = (short*)(wsb + 70 * MiB);
        short* SC64 = (short*)(wsb + 76 * MiB);
        short* SC128= (short*)(wsb + 82 * MiB);
        short* SC256= (short*)(wsb + 88 * MiB);
        short* SA0  = (short*)(wsb + 94 * MiB);       // 12 MiB (2048-row splits)
        short* SA1  = (short*)(wsb + 106 * MiB);      // 12 MiB
        // prep-phase A-split temps overlap SA0/SA1 (freed before stage1 seed)
        short* SAP = (short*)(wsb + 94 * MiB);
        short* SA2 = (short*)(wsb + 100 * MiB);
        short* SA4 = (short*)(wsb + 106 * MiB);
        short* SA6 = (short*)(wsb + 112 * MiB);

        GD8 D{};
        #define LAUNCH_B(NG, YPG, SAB, SAC, PSA, SOB, SOC, ADD, SPB, SPC, SSB, SSC, PSS, NR) \
            step_b<<<dim3(16, (NG) * (YPG)), 256, 0, stream>>>(D, YPG, \
                SAB, SAC, PSA, SOB, SOC, ADD, SPB, SPC, SSB, SSC, PSS, NR)
        #define G1(AA, BS, OO, SS) do { D.g[0] = {AA, BS, OO, nulf, SS}; } while (0)

        // ---- inputs / xw GEMM
        transpose_k<<<dim3(32, 32), dim3(32, 8), 0, stream>>>(Whh, TP);
        split_a<<<dim3(1, HH), 256, 0, stream>>>(Wxh, RS, RC, SBW, RS, RC, HM);
        gemm_mx<<<dim3(16, 128), 256, 0, stream>>>(x, SBW, rec);
        split_a<<<dim3(1, HH), 256, 0, stream>>>(TP, RS, RC, SAP, RS, RC, HM);
        split_t<<<dim3(32, 32), dim3(32, 8), 0, stream>>>(TP, PW);     // PW[0]=M

        // ---- power prep: M^2..M^8, M^16, M^32..M^256
        G1(SAP, PW, TP, SA2);  LAUNCH_B(1, 8, RS, RC, HM, RS, RC, 0, 0, 0, RS, RC, HM, 1024);    // M^2
        split_t<<<dim3(32, 32), dim3(32, 8), 0, stream>>>(TP, PW + 1 * PWs);
        G1(SA2, PW + 1 * PWs, TP, SA4);  LAUNCH_B(1, 8, RS, RC, HM, RS, RC, 0, 0, 0, RS, RC, HM, 1024); // M^4
        split_t<<<dim3(32, 32), dim3(32, 8), 0, stream>>>(TP, PW + 3 * PWs);
        // batch: M^3 = A(M^2)B(M), M^5 = A(M^4)B(M), M^6 = A(M^4)B(M^2)
        D.g[0] = {SA2, PW, T3a, nulf, nuls};
        D.g[1] = {SA4, PW, T3c, nulf, nuls};
        D.g[2] = {SA4, PW + 1 * PWs, T3e, nulf, SA6};
        LAUNCH_B(3, 8, RS, RC, HM, RS, RC, 0, 0, 0, RS, RC, HM, 1024);
        split_t<<<dim3(32, 32), dim3(32, 8), 0, stream>>>(T3a, PW + 2 * PWs);
        split_t<<<dim3(32, 32), dim3(32, 8), 0, stream>>>(T3c, PW + 4 * PWs);
        split_t<<<dim3(32, 32), dim3(32, 8), 0, stream>>>(T3e, PW + 5 * PWs);
        G1(SA6, PW, TP, nuls);  LAUNCH_B(1, 8, RS, RC, HM, RS, RC, 0, 0, 0, RS, RC, HM, 1024);   // M^7
        split_t<<<dim3(32, 32), dim3(32, 8), 0, stream>>>(TP, PW + 6 * PWs);
        G1(SA4, PW + 3 * PWs, TP, SAP);  LAUNCH_B(1, 8, RS, RC, HM, RS, RC, 0, 0, 0, RS, RC, HM, 1024); // M^8
        split_t<<<dim3(32, 32), dim3(32, 8), 0, stream>>>(TP, PW + 7 * PWs);
        G1(SAP, PW + 7 * PWs, TP, SA2);  LAUNCH_B(1, 8, RS, RC, HM, RS, RC, 0, 0, 0, RS, RC, HM, 1024); // M^16
        split_t<<<dim3(32, 32), dim3(32, 8), 0, stream>>>(TP, SB16);
        G1(SA2, SB16, TP, SA4);  LAUNCH_B(1, 8, RS, RC, HM, RS, RC, 0, 0, 0, RS, RC, HM, 1024);  // M^32
        split_t<<<dim3(32, 32), dim3(32, 8), 0, stream>>>(TP, SC32);
        G1(SA4, SC32, TP, SA2);  LAUNCH_B(1, 8, RS, RC, HM, RS, RC, 0, 0, 0, RS, RC, HM, 1024);  // M^64
        split_t<<<dim3(32, 32), dim3(32, 8), 0, stream>>>(TP, SC64);
        G1(SA2, SC64, TP, SA4);  LAUNCH_B(1, 8, RS, RC, HM, RS, RC, 0, 0, 0, RS, RC, HM, 1024);  // M^128
        split_t<<<dim3(32, 32), dim3(32, 8), 0, stream>>>(TP, SC128);
        G1(SA4, SC128, TP, nuls);  LAUNCH_B(1, 8, RS, RC, HM, RS, RC, 0, 0, 0, RS, RC, HM, 1024); // M^256
        split_t<<<dim3(32, 32), dim3(32, 8), 0, stream>>>(TP, SC256);

        // ---- stage1: 7 sequential steps of 2048 rows (proven step_p128)
        split_a<<<dim3(1, 2048), 256, 0, stream>>>(rec, LH, CH8, SA0, RS, RC, PS2);
        for (int o = 1; o < C8; ++o) {
            short* Ain = (o & 1) ? SA0 : SA1;
            short* Sot = (o & 1) ? SA1 : SA0;
            step_p128<<<dim3(16, 16), 512, 0, stream>>>(Ain, RS, RC, PS2, PW,
                rec + (size_t)o * HH, LH, CH8, 1, nulf, 0, 0,
                Sot, RS, RC, PS2, 2048);
        }
        // chunk-end splits in SA1

        // ---- Hillis-Steele scan over 64 chunk-ends (powers precomputed)
        const short* SPOW[6] = {PW + 7 * PWs, SB16, SC32, SC64, SC128, SC256};
        short* SRC = SA1; short* DST = SA0;
        for (int s = 0; s < 6; ++s) {
            int T = 1 << s;
            int rows_ = (NC8 - T) * 32;
            step_p128<<<dim3(16, (rows_ + 127) / 128), 512, 0, stream>>>(
                SRC, RS, RC, PS2, SPOW[s],
                rec + (size_t)(T * C8 + C8 - 1) * HH, LH, CH8, 1,
                nulf, 0, 0, DST + (size_t)T * RC, RS, RC, PS2, rows_);
            copy_splits<<<T * 32, 256, 0, stream>>>(SRC, DST, PS2);
            short* t = SRC; SRC = DST; DST = t;
        }
        // final scan splits in SRC (= SA1 after 6 swaps)
        short* SFIN = SRC;
        short* SFREE = DST;

        // ---- stage3: ONE batched launch, 7 groups x 2016 rows
        for (int g = 0; g < 7; ++g)
            D.g[g] = {SFIN, PW + (size_t)g * PWs, nulf, rec + (size_t)(C8 + g) * HH, nuls};
        LAUNCH_B(7, 16, RS, RC, PS2, 0, 0, 0, LH, CH8, 0, 0, PS2, 2016);

        // ---- pred: P1:8 batched, then x M^8, x M^16
        for (int g = 0; g < 8; ++g)
            D.g[g] = {SFIN + 63 * RC, PW + (size_t)g * PWs, outp + (size_t)g * HH,
                      nulf, SFREE + (size_t)g * RC};
        LAUNCH_B(8, 1, RS, 0, PS2, PB, 0, 0, 0, 0, RS, 0, PS2, 32);
        G1(SFREE, PW + 7 * PWs, outp + 8 * HH, SFREE + 8 * RC);
        LAUNCH_B(1, 2, RS, RC, PS2, PB, (long)HH, 0, 0, 0, RS, RC, PS2, 256);
        G1(SFREE, SB16, outp + 16 * HH, nuls);
        LAUNCH_B(1, 4, RS, RC, PS2, PB, (long)HH, 0, 0, 0, 0, 0, PS2, 512);
        #undef LAUNCH_B
        #undef G1

        ln_k<<<BB * PRED, 256, 0, stream>>>(outp, ln_w, ln_b);
        return;
    }

    // ================= fallback: proven R8 64-MiB tier =================
    {
        float* TP   = (float*)(wsb);
        short* SAP  = (short*)(wsb + 4 * MiB);
        short* SA0  = (short*)(wsb + 10 * MiB);
        short* SA1  = (short*)(wsb + 22 * MiB);
        short* SBM  = (short*)(wsb + 34 * MiB);
        short* SB8  = (short*)(wsb + 40 * MiB);
        short* SB16 = (short*)(wsb + 46 * MiB);
        short* SBr0 = (short*)(wsb + 52 * MiB);
        short* SBr1 = (short*)(wsb + 58 * MiB);

        transpose_k<<<dim3(32, 32), dim3(32, 8), 0, stream>>>(Whh, TP);
        split_a<<<dim3(1, HH), 256, 0, stream>>>(Wxh, RS, RC, SBr0, RS, RC, HM);
        gemm_mx<<<dim3(16, 128), 256, 0, stream>>>(x, SBr0, rec);
        split_a<<<dim3(1, HH), 256, 0, stream>>>(TP, RS, RC, SAP, RS, RC, HM);
        split_t<<<dim3(32, 32), dim3(32, 8), 0, stream>>>(TP, SBM);

        #define SQ64(SAi, SBi, Sot) \
            step_p64<<<dim3(16, 16), 256, 0, stream>>>(SAi, RS, RC, HM, SBi, \
                TP, RS, RC, 0, nulf, 0, 0, Sot, RS, RC, HM, 1024)
        SQ64(SAP, SBM, SA1);
        split_t<<<dim3(32, 32), dim3(32, 8), 0, stream>>>(TP, SBr0);
        SQ64(SA1, SBr0, SAP);
        split_t<<<dim3(32, 32), dim3(32, 8), 0, stream>>>(TP, SBr1);
        SQ64(SAP, SBr1, SA1);
        split_t<<<dim3(32, 32), dim3(32, 8), 0, stream>>>(TP, SB8);
        SQ64(SA1, SB8, SAP);
        split_t<<<dim3(32, 32), dim3(32, 8), 0, stream>>>(TP, SB16);

        split_a<<<dim3(1, 2048), 256, 0, stream>>>(rec, LH, CH8, SA0, RS, RC, PS2);
        for (int o = 1; o < C8; ++o) {
            short* Ain = (o & 1) ? SA0 : SA1;
            short* Sot = (o & 1) ? SA1 : SA0;
            step_p128<<<dim3(16, 16), 512, 0, stream>>>(Ain, RS, RC, PS2, SBM,
                rec + (size_t)o * HH, LH, CH8, 1, nulf, 0, 0,
                Sot, RS, RC, PS2, 2048);
        }
        #define SCAN(SRC, DST, T, SBpow) do { \
            int rows_ = (NC8 - (T)) * 32; \
            step_p128<<<dim3(16, (rows_ + 127) / 128), 512, 0, stream>>>( \
                SRC, RS, RC, PS2, SBpow, \
                rec + (size_t)((T) * C8 + C8 - 1) * HH, LH, CH8, 1, \
                nulf, 0, 0, DST + (size_t)(T) * RC, RS, RC, PS2, rows_); \
            copy_splits<<<(T) * 32, 256, 0, stream>>>(SRC, DST, PS2); \
        } while (0)
        #define SQI(SBi, SBo, last) do { \
            step_p64<<<dim3(16, 16), 256, 0, stream>>>(SAP, RS, RC, HM, SBi, \
                TP, RS, RC, 0, nulf, 0, 0, nuls, 0, 0, HM, 1024); \
            split_t<<<dim3(32, 32), dim3(32, 8), 0, stream>>>(TP, SBo); \
            if (!(last)) split_a<<<dim3(1, HH), 256, 0, stream>>>(TP, RS, RC, SAP, RS, RC, HM); \
        } while (0)
        SCAN(SA1, SA0, 1, SB8);
        SQI(SB16, SBr0, 0);
        SCAN(SA0, SA1, 2, SB16);
        SQI(SBr0, SBr1, 0);
        SCAN(SA1, SA0, 4, SBr0);
        SQI(SBr1, SBr0, 0);
        SCAN(SA0, SA1, 8, SBr1);
        SQI(SBr0, SBr1, 1);
        SCAN(SA1, SA0, 16, SBr0);
        SCAN(SA0, SA1, 32, SBr1);
        for (int o = 0; o < C8 - 1; ++o) {
            short* Ain = (o & 1) ? SA0 : SA1;
            short* Sot = (o & 1) ? SA1 : SA0;
            step_p128<<<dim3(16, 16), 512, 0, stream>>>(Ain, RS, RC, PS2, SBM,
                nulf, 0, 0, 0,
                rec + (size_t)(C8 + o) * HH, LH, CH8,
                (o == C8 - 2) ? nuls : Sot, RS, RC, PS2, 2016);
        }
        step_p<<<dim3(16, 1), 128, 0, stream>>>(SA1 + 63 * RC, RS, 0, PS2, SBM,
            outp, PB, 0, 0, nulf, 0, 0, SA0, RS, 0, PS2);
        step_p<<<dim3(16, 1), 128, 0, stream>>>(SA0, RS, 0, PS2, SBM,
            outp + HH, PB, 0, 0, nulf, 0, 0, SA0 + RC, RS, 0, PS2);
        tr_splits<<<dim3(32, 32, 3), dim3(32, 8), 0, stream>>>(SBM, SAP);
        SQ64(SAP, SBM, nuls);
        split_t<<<dim3(32, 32), dim3(32, 8), 0, stream>>>(TP, SBr0);
        step_p<<<dim3(16, 2), 128, 0, stream>>>(SA0, RS, RC, PS2, SBr0,
            outp + 2 * HH, PB, RS, 0, nulf, 0, 0,
            SA0 + 2 * RC, RS, RC, PS2);
        split_a<<<dim3(1, HH), 256, 0, stream>>>(TP, RS, RC, SAP, RS, RC, HM);
        SQ64(SAP, SBr0, nuls);
        split_t<<<dim3(32, 32), dim3(32, 8), 0, stream>>>(TP, SBr1);
        step_p<<<dim3(16, 4), 128, 0, stream>>>(SA0, RS, RC, PS2, SBr1,
            outp + 4 * HH, PB, RS, 0, nulf, 0, 0,
            SA0 + 4 * RC, RS, RC, PS2);
        step_p<<<dim3(16, 8), 128, 0, stream>>>(SA0, RS, RC, PS2, SB8,
            outp + 8 * HH, PB, RS, 0, nulf, 0, 0,
            SA0 + 8 * RC, RS, RC, PS2);
        step_p64<<<dim3(16, 8), 256, 0, stream>>>(SA0, RS, RC, PS2, SB16,
            outp + 16 * HH, PB, RS, 0, nulf, 0, 0,
            nuls, 0, 0, PS2, 512);
        #undef SQ64
        #undef SCAN
        #undef SQI

        ln_k<<<BB * PRED, 256, 0, stream>>>(outp, ln_w, ln_b);
    }
}

// Round 10
// 1323.359 us; speedup vs baseline: 10.0482x; 1.1322x over previous
//
#include <hip/hip_runtime.h>

#define BB 32
#define LL 512
#define HH 1024
#define PRED 32
#define C8 8             // chunk length
#define NC8 (LL / C8)    // 64 chunks
#define LN_EPS 1e-5f

typedef short bf16x8 __attribute__((ext_vector_type(8)));
typedef short s16x4  __attribute__((ext_vector_type(4)));
typedef float f32x4  __attribute__((ext_vector_type(4)));

static __device__ __forceinline__ void split3(float x, short& h, short& m, short& l) {
    unsigned u = __float_as_uint(x);
    unsigned rh = (u + 0x7fffu + ((u >> 16) & 1u)) & 0xffff0000u;
    h = (short)(rh >> 16);
    float x1 = x - __uint_as_float(rh);
    unsigned u1 = __float_as_uint(x1);
    unsigned rm = (u1 + 0x7fffu + ((u1 >> 16) & 1u)) & 0xffff0000u;
    m = (short)(rm >> 16);
    float x2 = x1 - __uint_as_float(rm);
    unsigned u2 = __float_as_uint(x2);
    unsigned rl = (u2 + 0x7fffu + ((u2 >> 16) & 1u)) & 0xffff0000u;
    l = (short)(rl >> 16);
}

static __device__ __forceinline__ void split2(float x, short& h, short& m) {
    unsigned u = __float_as_uint(x);
    unsigned rh = (u + 0x7fffu + ((u >> 16) & 1u)) & 0xffff0000u;
    h = (short)(rh >> 16);
    float x1 = x - __uint_as_float(rh);
    unsigned u1 = __float_as_uint(x1);
    unsigned rm = (u1 + 0x7fffu + ((u1 >> 16) & 1u)) & 0xffff0000u;
    m = (short)(rm >> 16);
}

#define MFMA6(ACC, AH, AM, AL, BH, BM, BL) \
    ACC = __builtin_amdgcn_mfma_f32_16x16x32_bf16(AL, BH, ACC, 0, 0, 0); \
    ACC = __builtin_amdgcn_mfma_f32_16x16x32_bf16(AH, BL, ACC, 0, 0, 0); \
    ACC = __builtin_amdgcn_mfma_f32_16x16x32_bf16(AM, BM, ACC, 0, 0, 0); \
    ACC = __builtin_amdgcn_mfma_f32_16x16x32_bf16(AM, BH, ACC, 0, 0, 0); \
    ACC = __builtin_amdgcn_mfma_f32_16x16x32_bf16(AH, BM, ACC, 0, 0, 0); \
    ACC = __builtin_amdgcn_mfma_f32_16x16x32_bf16(AH, BH, ACC, 0, 0, 0);

// ---------------------------------------------------------------------------
__global__ __launch_bounds__(256) void transpose_k(const float* __restrict__ in,
                                                   float* __restrict__ out) {
    __shared__ float tile[32][33];
    int bx = blockIdx.x * 32, by = blockIdx.y * 32;
    int tx = threadIdx.x, ty = threadIdx.y;
    #pragma unroll
    for (int i = 0; i < 32; i += 8)
        tile[ty + i][tx] = in[(size_t)(by + ty + i) * HH + bx + tx];
    __syncthreads();
    #pragma unroll
    for (int i = 0; i < 32; i += 8)
        out[(size_t)(bx + ty + i) * HH + by + tx] = tile[tx][ty + i];
}

// ---------------------------------------------------------------------------
__global__ __launch_bounds__(256) void split_a(const float* __restrict__ src, long sb, long sc,
                                               short* __restrict__ dst, long dsb, long dsc,
                                               long ps) {
    int r = blockIdx.y;
    const float* s = src + (long)(r & 31) * sb + (long)(r >> 5) * sc + threadIdx.x * 4;
    short* d = dst + (long)(r & 31) * dsb + (long)(r >> 5) * dsc + threadIdx.x * 4;
    float4 v = *(const float4*)s;
    float xs[4] = {v.x, v.y, v.z, v.w};
    s16x4 vh, vm, vl;
    #pragma unroll
    for (int j = 0; j < 4; ++j) {
        short h, m, l;
        split3(xs[j], h, m, l);
        vh[j] = h; vm[j] = m; vl[j] = l;
    }
    *(s16x4*)(d) = vh;
    *(s16x4*)(d + ps) = vm;
    *(s16x4*)(d + 2 * ps) = vl;
}

// ---------------------------------------------------------------------------
__global__ __launch_bounds__(256) void split_t(const float* __restrict__ in,
                                               short* __restrict__ out) {
    const size_t HM = (size_t)HH * HH;
    __shared__ float tile[32][33];
    int n0 = blockIdx.x * 32, k0 = blockIdx.y * 32;
    int tx = threadIdx.x, ty = threadIdx.y;
    #pragma unroll
    for (int i = 0; i < 32; i += 8)
        tile[ty + i][tx] = in[(size_t)(k0 + ty + i) * HH + n0 + tx];
    __syncthreads();
    #pragma unroll
    for (int i = 0; i < 32; i += 8) {
        float v = tile[tx][ty + i];
        short h, m, l;
        split3(v, h, m, l);
        size_t o = (size_t)(n0 + ty + i) * HH + k0 + tx;
        out[o] = h; out[HM + o] = m; out[2 * HM + o] = l;
    }
}

// ---------------------------------------------------------------------------
__global__ __launch_bounds__(256) void tr_splits(const short* __restrict__ in,
                                                 short* __restrict__ out) {
    const size_t HM = (size_t)HH * HH;
    __shared__ short tile[32][33];
    int p = blockIdx.z;
    int k0 = blockIdx.x * 32, n0 = blockIdx.y * 32;
    int tx = threadIdx.x, ty = threadIdx.y;
    #pragma unroll
    for (int i = 0; i < 32; i += 8)
        tile[ty + i][tx] = in[p * HM + (size_t)(n0 + ty + i) * HH + k0 + tx];
    __syncthreads();
    #pragma unroll
    for (int i = 0; i < 32; i += 8)
        out[p * HM + (size_t)(k0 + ty + i) * HH + n0 + tx] = tile[tx][ty + i];
}

// ---------------------------------------------------------------------------
__global__ __launch_bounds__(256) void copy_splits(const short* __restrict__ src,
                                                   short* __restrict__ dst, long ps) {
    size_t off = (size_t)blockIdx.x * HH + threadIdx.x * 4;
    *(s16x4*)(dst + off)          = *(const s16x4*)(src + off);
    *(s16x4*)(dst + ps + off)     = *(const s16x4*)(src + ps + off);
    *(s16x4*)(dst + 2 * ps + off) = *(const s16x4*)(src + 2 * ps + off);
}

// ---------------------------------------------------------------------------
// gemm_mx: C[m][n] = sum_k x[m][k]*W[n][k], MFMA bf16 2x2 split (proven R7).
// ---------------------------------------------------------------------------
__global__ __launch_bounds__(256) void gemm_mx(const float* __restrict__ A,
                                               const short* __restrict__ SB,
                                               float* __restrict__ C) {
    const size_t HM = (size_t)HH * HH;
    __shared__ __align__(16) short As2[2][128][40];
    __shared__ __align__(16) short Bs2[2][64][40];
    const int tid = threadIdx.x;
    const int lane = tid & 63;
    const int w = tid >> 6;
    const int n0 = blockIdx.x * 64;
    const int m0 = blockIdx.y * 128;
    const int ar = tid >> 1;
    const int akc = (tid & 1) * 16;
    const float* Arow = A + (size_t)(m0 + ar) * HH + akc;
    const int bp = tid >> 7;
    const int bnr = tid & 63;
    const int bkh = ((tid >> 6) & 1) * 16;
    const short* Brow = SB + bp * HM + (size_t)(n0 + bnr) * HH + bkh;
    const int fr = lane & 15;
    const int fk = (lane >> 4) * 8;

    f32x4 acc[2][4] = {};

    float4 av0 = *(const float4*)(Arow);
    float4 av1 = *(const float4*)(Arow + 4);
    float4 av2 = *(const float4*)(Arow + 8);
    float4 av3 = *(const float4*)(Arow + 12);
    bf16x8 rb0 = *(const bf16x8*)(Brow);
    bf16x8 rb1 = *(const bf16x8*)(Brow + 8);

    for (int kt = 0; kt < HH; kt += 32) {
        float xs[16] = {av0.x, av0.y, av0.z, av0.w, av1.x, av1.y, av1.z, av1.w,
                        av2.x, av2.y, av2.z, av2.w, av3.x, av3.y, av3.z, av3.w};
        bf16x8 vh0, vm0, vh1, vm1;
        #pragma unroll
        for (int j = 0; j < 8; ++j) {
            short h, m;
            split2(xs[j], h, m);
            vh0[j] = h; vm0[j] = m;
            split2(xs[j + 8], h, m);
            vh1[j] = h; vm1[j] = m;
        }
        *(bf16x8*)&As2[0][ar][akc]     = vh0;
        *(bf16x8*)&As2[0][ar][akc + 8] = vh1;
        *(bf16x8*)&As2[1][ar][akc]     = vm0;
        *(bf16x8*)&As2[1][ar][akc + 8] = vm1;
        *(bf16x8*)&Bs2[bp][bnr][bkh]     = rb0;
        *(bf16x8*)&Bs2[bp][bnr][bkh + 8] = rb1;
        __syncthreads();
        if (kt + 32 < HH) {
            const float* An = Arow + kt + 32;
            av0 = *(const float4*)(An);
            av1 = *(const float4*)(An + 4);
            av2 = *(const float4*)(An + 8);
            av3 = *(const float4*)(An + 12);
            const short* Bn = Brow + kt + 32;
            rb0 = *(const bf16x8*)(Bn);
            rb1 = *(const bf16x8*)(Bn + 8);
        }
        bf16x8 ah[2], am[2];
        #pragma unroll
        for (int i = 0; i < 2; ++i) {
            ah[i] = *(const bf16x8*)&As2[0][w * 32 + i * 16 + fr][fk];
            am[i] = *(const bf16x8*)&As2[1][w * 32 + i * 16 + fr][fk];
        }
        #pragma unroll
        for (int j = 0; j < 4; ++j) {
            bf16x8 bh = *(const bf16x8*)&Bs2[0][j * 16 + fr][fk];
            bf16x8 bm = *(const bf16x8*)&Bs2[1][j * 16 + fr][fk];
            #pragma unroll
            for (int i = 0; i < 2; ++i) {
                f32x4 a = acc[i][j];
                a = __builtin_amdgcn_mfma_f32_16x16x32_bf16(am[i], bm, a, 0, 0, 0);
                a = __builtin_amdgcn_mfma_f32_16x16x32_bf16(am[i], bh, a, 0, 0, 0);
                a = __builtin_amdgcn_mfma_f32_16x16x32_bf16(ah[i], bm, a, 0, 0, 0);
                a = __builtin_amdgcn_mfma_f32_16x16x32_bf16(ah[i], bh, a, 0, 0, 0);
                acc[i][j] = a;
            }
        }
        __syncthreads();
    }
    const int orow = (lane >> 4) * 4;
    #pragma unroll
    for (int i = 0; i < 2; ++i)
        #pragma unroll
        for (int j = 0; j < 4; ++j) {
            int c = n0 + j * 16 + fr;
            #pragma unroll
            for (int reg = 0; reg < 4; ++reg) {
                int r = m0 + w * 32 + i * 16 + orow + reg;
                C[(size_t)r * HH + c] = acc[i][j][reg];
            }
        }
}

// ---------------------------------------------------------------------------
// step_g: batched multi-descriptor bf16x6 MFMA GEMM, FULL per-group descriptors.
// 256 thr, 4 waves; block 128(M)x64(N); wave tile 32x64.
// Group chosen by blockIdx.y >= g.ybeg (ascending). B plane stride fixed = H*H.
// ---------------------------------------------------------------------------
struct GDv {
    const short* A; const short* B; float* O; float* P; short* S;
    int sab, sac, psA, sob, soc, spb, spc, ssb, ssc, psS, add, nrows, ybeg;
};
struct GDv8 { GDv g[8]; };

__global__ __launch_bounds__(256) void step_g(GDv8 dsc, int ng) {
    const size_t HM = (size_t)HH * HH;
    __shared__ __align__(16) short As[3][128][40];
    __shared__ __align__(16) short Bs[3][64][40];
    const int tid = threadIdx.x;
    const int lane = tid & 63;
    const int w = tid >> 6;
    const int yy = blockIdx.y;
    int gi = 0;
    for (int i = 1; i < ng; ++i)
        if (yy >= dsc.g[i].ybeg) gi = i;
    const GDv d = dsc.g[gi];
    const int n0 = blockIdx.x * 64;
    const int m0 = (yy - d.ybeg) * 128;
    // A staging: 128 rows x 32k x 3 planes; thread: row tid>>1, k-half (tid&1)*16
    const int ar = tid >> 1;
    const int akh = (tid & 1) * 16;
    const int agr = m0 + ar;
    const short* Arow = d.A + (long)(agr & 31) * d.sab + (long)(agr >> 5) * d.sac + akh;
    // B staging: 64 rows x 32k x 3 planes; thread: row tid>>2, k-chunk (tid&3)*8
    const int br = tid >> 2;
    const int bkc = (tid & 3) * 8;
    const short* Brow = d.B + (size_t)(n0 + br) * HH + bkc;
    const int fr = lane & 15;
    const int fk = (lane >> 4) * 8;
    const long psA = d.psA;

    f32x4 acc[2][4] = {};

    bf16x8 ra[6], rb[3];
    #pragma unroll
    for (int p = 0; p < 3; ++p) {
        ra[2 * p]     = *(const bf16x8*)(Arow + p * psA);
        ra[2 * p + 1] = *(const bf16x8*)(Arow + p * psA + 8);
        rb[p]         = *(const bf16x8*)(Brow + p * HM);
    }
    for (int kt = 0; kt < HH; kt += 32) {
        #pragma unroll
        for (int p = 0; p < 3; ++p) {
            *(bf16x8*)&As[p][ar][akh]     = ra[2 * p];
            *(bf16x8*)&As[p][ar][akh + 8] = ra[2 * p + 1];
            *(bf16x8*)&Bs[p][br][bkc]     = rb[p];
        }
        __syncthreads();
        if (kt + 32 < HH) {
            #pragma unroll
            for (int p = 0; p < 3; ++p) {
                ra[2 * p]     = *(const bf16x8*)(Arow + p * psA + kt + 32);
                ra[2 * p + 1] = *(const bf16x8*)(Arow + p * psA + kt + 40);
                rb[p]         = *(const bf16x8*)(Brow + p * HM + kt + 32);
            }
        }
        bf16x8 af[3][2], bfr[3][4];
        #pragma unroll
        for (int p = 0; p < 3; ++p) {
            #pragma unroll
            for (int mf = 0; mf < 2; ++mf)
                af[p][mf] = *(const bf16x8*)&As[p][w * 32 + mf * 16 + fr][fk];
            #pragma unroll
            for (int nf = 0; nf < 4; ++nf)
                bfr[p][nf] = *(const bf16x8*)&Bs[p][nf * 16 + fr][fk];
        }
        #pragma unroll
        for (int mf = 0; mf < 2; ++mf)
            #pragma unroll
            for (int nf = 0; nf < 4; ++nf) {
                MFMA6(acc[mf][nf], af[0][mf], af[1][mf], af[2][mf],
                      bfr[0][nf], bfr[1][nf], bfr[2][nf])
            }
        __syncthreads();
    }
    const int orow = (lane >> 4) * 4;
    #pragma unroll
    for (int mf = 0; mf < 2; ++mf)
        #pragma unroll
        for (int nf = 0; nf < 4; ++nf) {
            int c = n0 + nf * 16 + fr;
            #pragma unroll
            for (int reg = 0; reg < 4; ++reg) {
                int r = m0 + w * 32 + mf * 16 + orow + reg;
                if (r >= d.nrows) continue;
                long rb_ = (long)(r & 31), rc_ = (long)(r >> 5);
                float val = acc[mf][nf][reg];
                if (d.O) {
                    float* p = d.O + rb_ * d.sob + rc_ * d.soc + c;
                    if (d.add) val += *p;
                    *p = val;
                }
                if (d.P) {
                    float* q = d.P + rb_ * d.spb + rc_ * d.spc + c;
                    *q += val;
                }
                if (d.S) {
                    short h, m, l;
                    split3(val, h, m, l);
                    short* s = d.S + rb_ * d.ssb + rc_ * d.ssc + c;
                    s[0] = h; s[d.psS] = m; s[2 * (long)d.psS] = l;
                }
            }
        }
}

// ---------------------------------------------------------------------------
// step_p / step_p64 / step_p128: proven kernels kept for the 64-MiB fallback.
// ---------------------------------------------------------------------------
__global__ __launch_bounds__(128) void step_p(
    const short* __restrict__ SA, long sab, long sac, long psA,
    const short* __restrict__ SB,
    float* __restrict__ O, long sob, long soc, int add,
    float* __restrict__ P, long spb, long spc,
    short* __restrict__ S, long ssb, long ssc, long psS) {
    const size_t HM = (size_t)HH * HH;
    __shared__ __align__(16) short As[3][32][40];
    __shared__ __align__(16) short Bs[3][64][40];
    const int tid = threadIdx.x;
    const int lane = tid & 63;
    const int w = tid >> 6;
    const int n0 = blockIdx.x * 64;
    const int m0 = blockIdx.y * 32;
    const int ar = tid >> 2;
    const int akc = (tid & 3) * 8;
    const int agr = m0 + ar;
    const short* Arow = SA + (long)(agr & 31) * sab + (long)(agr >> 5) * sac + akc;
    const int bnr = tid & 63;
    const int bkh = (tid >> 6) * 16;
    const short* Brow = SB + (size_t)(n0 + bnr) * HH + bkh;
    const int fr = lane & 15;
    const int fk = (lane >> 4) * 8;
    f32x4 acc00 = 0, acc01 = 0, acc10 = 0, acc11 = 0;
    bf16x8 ra0 = *(const bf16x8*)(Arow);
    bf16x8 ra1 = *(const bf16x8*)(Arow + psA);
    bf16x8 ra2 = *(const bf16x8*)(Arow + 2 * psA);
    bf16x8 rb0 = *(const bf16x8*)(Brow);
    bf16x8 rb1 = *(const bf16x8*)(Brow + 8);
    bf16x8 rb2 = *(const bf16x8*)(Brow + HM);
    bf16x8 rb3 = *(const bf16x8*)(Brow + HM + 8);
    bf16x8 rb4 = *(const bf16x8*)(Brow + 2 * HM);
    bf16x8 rb5 = *(const bf16x8*)(Brow + 2 * HM + 8);
    for (int kt = 0; kt < HH; kt += 32) {
        *(bf16x8*)&As[0][ar][akc] = ra0;
        *(bf16x8*)&As[1][ar][akc] = ra1;
        *(bf16x8*)&As[2][ar][akc] = ra2;
        *(bf16x8*)&Bs[0][bnr][bkh] = rb0;
        *(bf16x8*)&Bs[0][bnr][bkh + 8] = rb1;
        *(bf16x8*)&Bs[1][bnr][bkh] = rb2;
        *(bf16x8*)&Bs[1][bnr][bkh + 8] = rb3;
        *(bf16x8*)&Bs[2][bnr][bkh] = rb4;
        *(bf16x8*)&Bs[2][bnr][bkh + 8] = rb5;
        __syncthreads();
        if (kt + 32 < HH) {
            const short* An = Arow + kt + 32;
            const short* Bn = Brow + kt + 32;
            ra0 = *(const bf16x8*)(An);
            ra1 = *(const bf16x8*)(An + psA);
            ra2 = *(const bf16x8*)(An + 2 * psA);
            rb0 = *(const bf16x8*)(Bn);
            rb1 = *(const bf16x8*)(Bn + 8);
            rb2 = *(const bf16x8*)(Bn + HM);
            rb3 = *(const bf16x8*)(Bn + HM + 8);
            rb4 = *(const bf16x8*)(Bn + 2 * HM);
            rb5 = *(const bf16x8*)(Bn + 2 * HM + 8);
        }
        bf16x8 a00 = *(const bf16x8*)&As[0][fr][fk];
        bf16x8 a01 = *(const bf16x8*)&As[0][16 + fr][fk];
        bf16x8 a10 = *(const bf16x8*)&As[1][fr][fk];
        bf16x8 a11 = *(const bf16x8*)&As[1][16 + fr][fk];
        bf16x8 a20 = *(const bf16x8*)&As[2][fr][fk];
        bf16x8 a21 = *(const bf16x8*)&As[2][16 + fr][fk];
        bf16x8 b00 = *(const bf16x8*)&Bs[0][w * 32 + fr][fk];
        bf16x8 b01 = *(const bf16x8*)&Bs[0][w * 32 + 16 + fr][fk];
        bf16x8 b10 = *(const bf16x8*)&Bs[1][w * 32 + fr][fk];
        bf16x8 b11 = *(const bf16x8*)&Bs[1][w * 32 + 16 + fr][fk];
        bf16x8 b20 = *(const bf16x8*)&Bs[2][w * 32 + fr][fk];
        bf16x8 b21 = *(const bf16x8*)&Bs[2][w * 32 + 16 + fr][fk];
        MFMA6(acc00, a00, a10, a20, b00, b10, b20)
        MFMA6(acc01, a00, a10, a20, b01, b11, b21)
        MFMA6(acc10, a01, a11, a21, b00, b10, b20)
        MFMA6(acc11, a01, a11, a21, b01, b11, b21)
        __syncthreads();
    }
    const int orow = (lane >> 4) * 4;
    #pragma unroll
    for (int mf = 0; mf < 2; ++mf) {
        #pragma unroll
        for (int nf = 0; nf < 2; ++nf) {
            f32x4 v = mf == 0 ? (nf == 0 ? acc00 : acc01) : (nf == 0 ? acc10 : acc11);
            int c = n0 + w * 32 + nf * 16 + fr;
            #pragma unroll
            for (int reg = 0; reg < 4; ++reg) {
                int r = m0 + mf * 16 + orow + reg;
                long rb = (long)(r & 31), rc = (long)(r >> 5);
                float val = v[reg];
                if (O) {
                    float* p = O + rb * sob + rc * soc + c;
                    if (add) val += *p;
                    *p = val;
                }
                if (P) { float* q = P + rb * spb + rc * spc + c; *q += val; }
                if (S) {
                    short h, m, l;
                    split3(val, h, m, l);
                    short* s = S + rb * ssb + rc * ssc + c;
                    s[0] = h; s[psS] = m; s[2 * psS] = l;
                }
            }
        }
    }
}

__global__ __launch_bounds__(256) void step_p64(
    const short* __restrict__ SA, long sab, long sac, long psA,
    const short* __restrict__ SB,
    float* __restrict__ O, long sob, long soc, int add,
    float* __restrict__ P, long spb, long spc,
    short* __restrict__ S, long ssb, long ssc, long psS,
    int nrows) {
    const size_t HM = (size_t)HH * HH;
    __shared__ __align__(16) short As[3][64][40];
    __shared__ __align__(16) short Bs[3][64][40];
    const int tid = threadIdx.x;
    const int lane = tid & 63;
    const int w = tid >> 6;
    const int wr = w & 1;
    const int wc = w >> 1;
    const int n0 = blockIdx.x * 64;
    const int m0 = blockIdx.y * 64;
    const int ar = tid >> 2;
    const int akc = (tid & 3) * 8;
    const int agr = m0 + ar;
    const short* Arow = SA + (long)(agr & 31) * sab + (long)(agr >> 5) * sac + akc;
    const short* Brow = SB + (size_t)(n0 + ar) * HH + akc;
    const int fr = lane & 15;
    const int fk = (lane >> 4) * 8;
    f32x4 acc00 = 0, acc01 = 0, acc10 = 0, acc11 = 0;
    bf16x8 ra0 = *(const bf16x8*)(Arow);
    bf16x8 ra1 = *(const bf16x8*)(Arow + psA);
    bf16x8 ra2 = *(const bf16x8*)(Arow + 2 * psA);
    bf16x8 rb0 = *(const bf16x8*)(Brow);
    bf16x8 rb1 = *(const bf16x8*)(Brow + HM);
    bf16x8 rb2 = *(const bf16x8*)(Brow + 2 * HM);
    for (int kt = 0; kt < HH; kt += 32) {
        *(bf16x8*)&As[0][ar][akc] = ra0;
        *(bf16x8*)&As[1][ar][akc] = ra1;
        *(bf16x8*)&As[2][ar][akc] = ra2;
        *(bf16x8*)&Bs[0][ar][akc] = rb0;
        *(bf16x8*)&Bs[1][ar][akc] = rb1;
        *(bf16x8*)&Bs[2][ar][akc] = rb2;
        __syncthreads();
        if (kt + 32 < HH) {
            const short* An = Arow + kt + 32;
            const short* Bn = Brow + kt + 32;
            ra0 = *(const bf16x8*)(An);
            ra1 = *(const bf16x8*)(An + psA);
            ra2 = *(const bf16x8*)(An + 2 * psA);
            rb0 = *(const bf16x8*)(Bn);
            rb1 = *(const bf16x8*)(Bn + HM);
            rb2 = *(const bf16x8*)(Bn + 2 * HM);
        }
        bf16x8 a00 = *(const bf16x8*)&As[0][wr * 32 + fr][fk];
        bf16x8 a01 = *(const bf16x8*)&As[0][wr * 32 + 16 + fr][fk];
        bf16x8 a10 = *(const bf16x8*)&As[1][wr * 32 + fr][fk];
        bf16x8 a11 = *(const bf16x8*)&As[1][wr * 32 + 16 + fr][fk];
        bf16x8 a20 = *(const bf16x8*)&As[2][wr * 32 + fr][fk];
        bf16x8 a21 = *(const bf16x8*)&As[2][wr * 32 + 16 + fr][fk];
        bf16x8 b00 = *(const bf16x8*)&Bs[0][wc * 32 + fr][fk];
        bf16x8 b01 = *(const bf16x8*)&Bs[0][wc * 32 + 16 + fr][fk];
        bf16x8 b10 = *(const bf16x8*)&Bs[1][wc * 32 + fr][fk];
        bf16x8 b11 = *(const bf16x8*)&Bs[1][wc * 32 + 16 + fr][fk];
        bf16x8 b20 = *(const bf16x8*)&Bs[2][wc * 32 + fr][fk];
        bf16x8 b21 = *(const bf16x8*)&Bs[2][wc * 32 + 16 + fr][fk];
        MFMA6(acc00, a00, a10, a20, b00, b10, b20)
        MFMA6(acc01, a00, a10, a20, b01, b11, b21)
        MFMA6(acc10, a01, a11, a21, b00, b10, b20)
        MFMA6(acc11, a01, a11, a21, b01, b11, b21)
        __syncthreads();
    }
    const int orow = (lane >> 4) * 4;
    #pragma unroll
    for (int mf = 0; mf < 2; ++mf) {
        #pragma unroll
        for (int nf = 0; nf < 2; ++nf) {
            f32x4 v = mf == 0 ? (nf == 0 ? acc00 : acc01) : (nf == 0 ? acc10 : acc11);
            int c = n0 + wc * 32 + nf * 16 + fr;
            #pragma unroll
            for (int reg = 0; reg < 4; ++reg) {
                int r = m0 + wr * 32 + mf * 16 + orow + reg;
                if (r >= nrows) continue;
                long rb = (long)(r & 31), rc = (long)(r >> 5);
                float val = v[reg];
                if (O) {
                    float* p = O + rb * sob + rc * soc + c;
                    if (add) val += *p;
                    *p = val;
                }
                if (P) { float* q = P + rb * spb + rc * spc + c; *q += val; }
                if (S) {
                    short h, m, l;
                    split3(val, h, m, l);
                    short* s = S + rb * ssb + rc * ssc + c;
                    s[0] = h; s[psS] = m; s[2 * psS] = l;
                }
            }
        }
    }
}

__global__ __launch_bounds__(512) void step_p128(
    const short* __restrict__ SA, long sab, long sac, long psA,
    const short* __restrict__ SB,
    float* __restrict__ O, long sob, long soc, int add,
    float* __restrict__ P, long spb, long spc,
    short* __restrict__ S, long ssb, long ssc, long psS,
    int nrows) {
    const size_t HM = (size_t)HH * HH;
    __shared__ __align__(16) short As[3][128][40];
    __shared__ __align__(16) short Bs[3][64][40];
    const int tid = threadIdx.x;
    const int lane = tid & 63;
    const int w = tid >> 6;
    const int wr = w & 3;
    const int wc = w >> 2;
    const int n0 = blockIdx.x * 64;
    const int m0 = blockIdx.y * 128;
    const int ar = tid >> 2;
    const int akc = (tid & 3) * 8;
    const int agr = m0 + ar;
    const short* Arow = SA + (long)(agr & 31) * sab + (long)(agr >> 5) * sac + akc;
    const bool bst = (tid < 384);
    const int bp = (tid >> 7) == 3 ? 2 : (tid >> 7);
    const int bt = tid & 127;
    const int bnr = bt >> 1;
    const int bkh = (bt & 1) * 16;
    const short* Brow = SB + (size_t)bp * HM + (size_t)(n0 + bnr) * HH + bkh;
    const int fr = lane & 15;
    const int fk = (lane >> 4) * 8;
    f32x4 acc00 = 0, acc01 = 0, acc10 = 0, acc11 = 0;
    bf16x8 ra0 = *(const bf16x8*)(Arow);
    bf16x8 ra1 = *(const bf16x8*)(Arow + psA);
    bf16x8 ra2 = *(const bf16x8*)(Arow + 2 * psA);
    bf16x8 rb0 = {}, rb1 = {};
    if (bst) { rb0 = *(const bf16x8*)(Brow); rb1 = *(const bf16x8*)(Brow + 8); }
    for (int kt = 0; kt < HH; kt += 32) {
        *(bf16x8*)&As[0][ar][akc] = ra0;
        *(bf16x8*)&As[1][ar][akc] = ra1;
        *(bf16x8*)&As[2][ar][akc] = ra2;
        if (bst) {
            *(bf16x8*)&Bs[bp][bnr][bkh]     = rb0;
            *(bf16x8*)&Bs[bp][bnr][bkh + 8] = rb1;
        }
        __syncthreads();
        if (kt + 32 < HH) {
            const short* An = Arow + kt + 32;
            ra0 = *(const bf16x8*)(An);
            ra1 = *(const bf16x8*)(An + psA);
            ra2 = *(const bf16x8*)(An + 2 * psA);
            if (bst) {
                const short* Bn = Brow + kt + 32;
                rb0 = *(const bf16x8*)(Bn);
                rb1 = *(const bf16x8*)(Bn + 8);
            }
        }
        bf16x8 a00 = *(const bf16x8*)&As[0][wr * 32 + fr][fk];
        bf16x8 a01 = *(const bf16x8*)&As[0][wr * 32 + 16 + fr][fk];
        bf16x8 a10 = *(const bf16x8*)&As[1][wr * 32 + fr][fk];
        bf16x8 a11 = *(const bf16x8*)&As[1][wr * 32 + 16 + fr][fk];
        bf16x8 a20 = *(const bf16x8*)&As[2][wr * 32 + fr][fk];
        bf16x8 a21 = *(const bf16x8*)&As[2][wr * 32 + 16 + fr][fk];
        bf16x8 b00 = *(const bf16x8*)&Bs[0][wc * 32 + fr][fk];
        bf16x8 b01 = *(const bf16x8*)&Bs[0][wc * 32 + 16 + fr][fk];
        bf16x8 b10 = *(const bf16x8*)&Bs[1][wc * 32 + fr][fk];
        bf16x8 b11 = *(const bf16x8*)&Bs[1][wc * 32 + 16 + fr][fk];
        bf16x8 b20 = *(const bf16x8*)&Bs[2][wc * 32 + fr][fk];
        bf16x8 b21 = *(const bf16x8*)&Bs[2][wc * 32 + 16 + fr][fk];
        MFMA6(acc00, a00, a10, a20, b00, b10, b20)
        MFMA6(acc01, a00, a10, a20, b01, b11, b21)
        MFMA6(acc10, a01, a11, a21, b00, b10, b20)
        MFMA6(acc11, a01, a11, a21, b01, b11, b21)
        __syncthreads();
    }
    const int orow = (lane >> 4) * 4;
    #pragma unroll
    for (int mf = 0; mf < 2; ++mf) {
        #pragma unroll
        for (int nf = 0; nf < 2; ++nf) {
            f32x4 v = mf == 0 ? (nf == 0 ? acc00 : acc01) : (nf == 0 ? acc10 : acc11);
            int c = n0 + wc * 32 + nf * 16 + fr;
            #pragma unroll
            for (int reg = 0; reg < 4; ++reg) {
                int r = m0 + wr * 32 + mf * 16 + orow + reg;
                if (r >= nrows) continue;
                long rb = (long)(r & 31), rc = (long)(r >> 5);
                float val = v[reg];
                if (O) {
                    float* p = O + rb * sob + rc * soc + c;
                    if (add) val += *p;
                    *p = val;
                }
                if (P) { float* q = P + rb * spb + rc * spc + c; *q += val; }
                if (S) {
                    short h, m, l;
                    split3(val, h, m, l);
                    short* s = S + rb * ssb + rc * ssc + c;
                    s[0] = h; s[psS] = m; s[2 * psS] = l;
                }
            }
        }
    }
}

// ---------------------------------------------------------------------------
__global__ __launch_bounds__(256) void ln_k(float* __restrict__ y,
                                            const float* __restrict__ w,
                                            const float* __restrict__ bia) {
    __shared__ float red[8];
    int row = blockIdx.x;
    float* p = y + (size_t)row * HH;
    int i4 = threadIdx.x * 4;
    float4 v = *(const float4*)&p[i4];
    float s = v.x + v.y + v.z + v.w;
    #pragma unroll
    for (int o = 32; o > 0; o >>= 1) s += __shfl_down(s, o, 64);
    int wid = threadIdx.x >> 6;
    if ((threadIdx.x & 63) == 0) red[wid] = s;
    __syncthreads();
    if (threadIdx.x == 0) red[4] = (red[0] + red[1] + red[2] + red[3]) * (1.f / HH);
    __syncthreads();
    float mu = red[4];
    float dx = v.x - mu, dy = v.y - mu, dz = v.z - mu, dw = v.w - mu;
    float q = dx * dx + dy * dy + dz * dz + dw * dw;
    #pragma unroll
    for (int o = 32; o > 0; o >>= 1) q += __shfl_down(q, o, 64);
    if ((threadIdx.x & 63) == 0) red[wid] = q;
    __syncthreads();
    if (threadIdx.x == 0) red[5] = (red[0] + red[1] + red[2] + red[3]) * (1.f / HH);
    __syncthreads();
    float rs = rsqrtf(red[5] + LN_EPS);
    float4 o4;
    o4.x = dx * rs * w[i4 + 0] + bia[i4 + 0];
    o4.y = dy * rs * w[i4 + 1] + bia[i4 + 1];
    o4.z = dz * rs * w[i4 + 2] + bia[i4 + 2];
    o4.w = dw * rs * w[i4 + 3] + bia[i4 + 3];
    *(float4*)&p[i4] = o4;
}

// ---------------------------------------------------------------------------
extern "C" void kernel_launch(void* const* d_in, const int* in_sizes, int n_in,
                              void* d_out, int out_size, void* d_ws, size_t ws_size,
                              hipStream_t stream) {
    const float* x    = (const float*)d_in[0];
    const float* Wxh  = (const float*)d_in[1];
    const float* Whh  = (const float*)d_in[2];
    const float* ln_w = (const float*)d_in[3];
    const float* ln_b = (const float*)d_in[4];

    const size_t MiB = 1024 * 1024;
    const long HM  = (long)HH * HH;
    const long PS2 = 2048L * HH;
    float* rec  = (float*)d_out;
    float* outp = rec + (size_t)BB * LL * HH;

    const long LH  = (long)LL * HH;
    const long CH8 = (long)C8 * HH;
    const long PB  = (long)PRED * HH;
    const long RS  = (long)HH;
    const long RC  = 32L * HH;
    float* nulf = (float*)nullptr;
    short* nuls = (short*)nullptr;
    char* wsb = (char*)d_ws;

    if (ws_size >= 124 * MiB) {
        // ======== tier NEW: dual-chain powers riding stage1/scan (120 MiB) ========
        // Layout (6-MiB units of 3*HM shorts):
        //   idx 0..7  : NA1..NA8   (A-splits of N^c = B-operand for ·M^c)
        //   idx 8..12 : NA16, NA32, NA64, NA128, NA256
        auto NA = [&](int idx) -> short* { return (short*)wsb + (size_t)idx * 3 * HM; };
        short* MAs[3] = {(short*)(wsb + 78 * MiB), (short*)(wsb + 84 * MiB),
                         (short*)(wsb + 90 * MiB)};
        short* SA0 = (short*)(wsb + 96 * MiB);    // 12 MiB (2048-row splits)
        short* SA1 = (short*)(wsb + 108 * MiB);   // 12 MiB
        short* SBW = SA0;                         // alias, consumed before SA0 live
        float* TPf = (float*)SA1;                 // alias, consumed before SA1 live

        GDv8 D{};
        auto launch = [&](int ng, int ytot) {
            step_g<<<dim3(16, ytot), 256, 0, stream>>>(D, ng);
        };
        // squaring-group descriptor (1024-row, splits->splits only)
        auto g_sq = [&](const short* A_, const short* B_, short* S_, int ybeg) -> GDv {
            GDv v{};
            v.A = A_; v.B = B_; v.O = nullptr; v.P = nullptr; v.S = S_;
            v.sab = HH; v.sac = 32 * HH; v.psA = (int)HM;
            v.ssb = HH; v.ssc = 32 * HH; v.psS = (int)HM;
            v.add = 0; v.nrows = 1024; v.ybeg = ybeg;
            return v;
        };

        // ---- seeds: NA1 = splits(Whh) (= B-splits of M), MA1 = splits(Whh^T)
        transpose_k<<<dim3(32, 32), dim3(32, 8), 0, stream>>>(Whh, TPf);
        split_a<<<dim3(1, HH), 256, 0, stream>>>(Whh, RS, RC, NA(0), RS, RC, HM);
        split_a<<<dim3(1, HH), 256, 0, stream>>>(TPf, RS, RC, MAs[0], RS, RC, HM);
        split_a<<<dim3(1, HH), 256, 0, stream>>>(Wxh, RS, RC, SBW, RS, RC, HM);
        gemm_mx<<<dim3(16, 128), 256, 0, stream>>>(x, SBW, rec);

        // ---- stage1 (7 sequential steps of 2048 rows) + carried power groups
        split_a<<<dim3(1, 2048), 256, 0, stream>>>(rec, LH, CH8, SA0, RS, RC, PS2);
        short* SAc = SA0;
        short* SAn = SA1;
        for (int o = 1; o < C8; ++o) {
            GDv mn{};
            mn.A = SAc; mn.B = NA(0);
            mn.O = rec + (size_t)o * HH; mn.sob = (int)LH; mn.soc = (int)CH8; mn.add = 1;
            mn.P = nullptr; mn.S = SAn;
            mn.sab = HH; mn.sac = 32 * HH; mn.psA = (int)PS2;
            mn.ssb = HH; mn.ssc = 32 * HH; mn.psS = (int)PS2;
            mn.nrows = 2048; mn.ybeg = 0;
            D.g[0] = mn;
            int ng = 1, yt = 16;
            auto add_sq = [&](const short* A_, const short* B_, short* S_) {
                D.g[ng++] = g_sq(A_, B_, S_, yt); yt += 8;
            };
            switch (o) {
                case 1:  // M2 = M·M ; N2 = N·N
                    add_sq(MAs[0], NA(0), MAs[1]);
                    add_sq(NA(0), MAs[0], NA(1));
                    break;
                case 2:  // M4 = M2·M2 ; N3 = N2·N ; N4 = N2·N2
                    add_sq(MAs[1], NA(1), MAs[2]);
                    add_sq(NA(1), MAs[0], NA(2));
                    add_sq(NA(1), MAs[1], NA(3));
                    break;
                case 3:  // N5 = N4·N ; N6 = N4·N2 ; N8 = N4·N4
                    add_sq(NA(3), MAs[0], NA(4));
                    add_sq(NA(3), MAs[1], NA(5));
                    add_sq(NA(3), MAs[2], NA(7));
                    break;
                case 4:  // N7 = N3·N4 ; M8 = M4·M4 (MA1 dead -> slot0)
                    add_sq(NA(2), MAs[2], NA(6));
                    add_sq(MAs[2], NA(3), MAs[0]);
                    break;
                case 5:  // N16 = N8·N8 ; M16 = M8·M8 (MA2 dead -> slot1)
                    add_sq(NA(7), MAs[0], NA(8));
                    add_sq(MAs[0], NA(7), MAs[1]);
                    break;
                case 6:  // N32 ; M32 (MA4 dead -> slot2)
                    add_sq(NA(8), MAs[1], NA(9));
                    add_sq(MAs[1], NA(8), MAs[2]);
                    break;
                case 7:  // N64 ; M64 (M8 dead -> slot0)
                    add_sq(NA(9), MAs[2], NA(10));
                    add_sq(MAs[2], NA(9), MAs[0]);
                    break;
            }
            launch(ng, yt);
            short* t = SAc; SAc = SAn; SAn = t;
        }
        // chunk-end splits now in SAc (= SA1)

        // ---- Hillis-Steele scan over 64 chunk-ends; N128/M128/N256 ride s=0,1
        short* SRC = SAc;
        short* DST = SAn;
        for (int s = 0; s < 6; ++s) {
            int T = 1 << s;
            int rows_ = (NC8 - T) * 32;
            int yb = (rows_ + 127) / 128;
            GDv mn{};
            mn.A = SRC; mn.B = NA(s == 0 ? 7 : 7 + s);
            mn.O = rec + (size_t)(T * C8 + C8 - 1) * HH;
            mn.sob = (int)LH; mn.soc = (int)CH8; mn.add = 1;
            mn.P = nullptr; mn.S = DST + (size_t)T * RC;
            mn.sab = HH; mn.sac = 32 * HH; mn.psA = (int)PS2;
            mn.ssb = HH; mn.ssc = 32 * HH; mn.psS = (int)PS2;
            mn.nrows = rows_; mn.ybeg = 0;
            D.g[0] = mn;
            int ng = 1, yt = yb;
            if (s == 0) {  // N128 = N64·N64 ; M128 = M64·M64 (M16 dead -> slot1)
                D.g[ng++] = g_sq(NA(10), MAs[0], NA(11), yt); yt += 8;
                D.g[ng++] = g_sq(MAs[0], NA(10), MAs[1], yt); yt += 8;
            } else if (s == 1) {  // N256 = N128·N128
                D.g[ng++] = g_sq(NA(11), MAs[1], NA(12), yt); yt += 8;
            }
            launch(ng, yt);
            copy_splits<<<T * 32, 256, 0, stream>>>(SRC, DST, PS2);
            short* t = SRC; SRC = DST; DST = t;
        }
        short* SFIN = SRC;   // true chunk-end splits (chunk 63 = rows 2016..2047)
        short* SFREE = DST;

        // ---- stage3: ONE batched launch, 7 groups x 2016 rows (P += carry·M^(g+1))
        for (int g = 0; g < 7; ++g) {
            GDv v{};
            v.A = SFIN; v.B = NA(g);
            v.O = nullptr; v.S = nullptr;
            v.P = rec + (size_t)(C8 + g) * HH;
            v.spb = (int)LH; v.spc = (int)CH8;
            v.sab = HH; v.sac = 32 * HH; v.psA = (int)PS2;
            v.nrows = 2016; v.ybeg = g * 16;
            D.g[g] = v;
        }
        launch(7, 112);

        // ---- pred: P1..8 batched (8 groups), then ·M^8, ·M^16
        for (int g = 0; g < 8; ++g) {
            GDv v{};
            v.A = SFIN + 63 * RC; v.B = NA(g);
            v.O = outp + (size_t)g * HH; v.sob = (int)PB; v.soc = 0; v.add = 0;
            v.P = nullptr;
            v.S = SFREE + (size_t)g * RC; v.ssb = HH; v.ssc = 0; v.psS = (int)PS2;
            v.sab = HH; v.sac = 0; v.psA = (int)PS2;
            v.nrows = 32; v.ybeg = g;
            D.g[g] = v;
        }
        launch(8, 8);
        {
            GDv v{};
            v.A = SFREE; v.B = NA(7);
            v.O = outp + 8 * HH; v.sob = (int)PB; v.soc = HH; v.add = 0;
            v.P = nullptr;
            v.S = SFREE + 8 * RC; v.ssb = HH; v.ssc = 32 * HH; v.psS = (int)PS2;
            v.sab = HH; v.sac = 32 * HH; v.psA = (int)PS2;
            v.nrows = 256; v.ybeg = 0;
            D.g[0] = v;
            launch(1, 2);
            v.B = NA(8);
            v.O = outp + 16 * HH;
            v.S = nullptr;
            v.nrows = 512;
            D.g[0] = v;
            launch(1, 4);
        }

        ln_k<<<BB * PRED, 256, 0, stream>>>(outp, ln_w, ln_b);
        return;
    }

    // ================= fallback: proven R8 64-MiB tier =================
    {
        float* TP   = (float*)(wsb);
        short* SAP  = (short*)(wsb + 4 * MiB);
        short* SA0  = (short*)(wsb + 10 * MiB);
        short* SA1  = (short*)(wsb + 22 * MiB);
        short* SBM  = (short*)(wsb + 34 * MiB);
        short* SB8  = (short*)(wsb + 40 * MiB);
        short* SB16 = (short*)(wsb + 46 * MiB);
        short* SBr0 = (short*)(wsb + 52 * MiB);
        short* SBr1 = (short*)(wsb + 58 * MiB);

        transpose_k<<<dim3(32, 32), dim3(32, 8), 0, stream>>>(Whh, TP);
        split_a<<<dim3(1, HH), 256, 0, stream>>>(Wxh, RS, RC, SBr0, RS, RC, HM);
        gemm_mx<<<dim3(16, 128), 256, 0, stream>>>(x, SBr0, rec);
        split_a<<<dim3(1, HH), 256, 0, stream>>>(TP, RS, RC, SAP, RS, RC, HM);
        split_t<<<dim3(32, 32), dim3(32, 8), 0, stream>>>(TP, SBM);

        #define SQ64(SAi, SBi, Sot) \
            step_p64<<<dim3(16, 16), 256, 0, stream>>>(SAi, RS, RC, HM, SBi, \
                TP, RS, RC, 0, nulf, 0, 0, Sot, RS, RC, HM, 1024)
        SQ64(SAP, SBM, SA1);
        split_t<<<dim3(32, 32), dim3(32, 8), 0, stream>>>(TP, SBr0);
        SQ64(SA1, SBr0, SAP);
        split_t<<<dim3(32, 32), dim3(32, 8), 0, stream>>>(TP, SBr1);
        SQ64(SAP, SBr1, SA1);
        split_t<<<dim3(32, 32), dim3(32, 8), 0, stream>>>(TP, SB8);
        SQ64(SA1, SB8, SAP);
        split_t<<<dim3(32, 32), dim3(32, 8), 0, stream>>>(TP, SB16);

        split_a<<<dim3(1, 2048), 256, 0, stream>>>(rec, LH, CH8, SA0, RS, RC, PS2);
        for (int o = 1; o < C8; ++o) {
            short* Ain = (o & 1) ? SA0 : SA1;
            short* Sot = (o & 1) ? SA1 : SA0;
            step_p128<<<dim3(16, 16), 512, 0, stream>>>(Ain, RS, RC, PS2, SBM,
                rec + (size_t)o * HH, LH, CH8, 1, nulf, 0, 0,
                Sot, RS, RC, PS2, 2048);
        }
        #define SCAN(SRC, DST, T, SBpow) do { \
            int rows_ = (NC8 - (T)) * 32; \
            step_p128<<<dim3(16, (rows_ + 127) / 128), 512, 0, stream>>>( \
                SRC, RS, RC, PS2, SBpow, \
                rec + (size_t)((T) * C8 + C8 - 1) * HH, LH, CH8, 1, \
                nulf, 0, 0, DST + (size_t)(T) * RC, RS, RC, PS2, rows_); \
            copy_splits<<<(T) * 32, 256, 0, stream>>>(SRC, DST, PS2); \
        } while (0)
        #define SQI(SBi, SBo, last) do { \
            step_p64<<<dim3(16, 16), 256, 0, stream>>>(SAP, RS, RC, HM, SBi, \
                TP, RS, RC, 0, nulf, 0, 0, nuls, 0, 0, HM, 1024); \
            split_t<<<dim3(32, 32), dim3(32, 8), 0, stream>>>(TP, SBo); \
            if (!(last)) split_a<<<dim3(1, HH), 256, 0, stream>>>(TP, RS, RC, SAP, RS, RC, HM); \
        } while (0)
        SCAN(SA1, SA0, 1, SB8);
        SQI(SB16, SBr0, 0);
        SCAN(SA0, SA1, 2, SB16);
        SQI(SBr0, SBr1, 0);
        SCAN(SA1, SA0, 4, SBr0);
        SQI(SBr1, SBr0, 0);
        SCAN(SA0, SA1, 8, SBr1);
        SQI(SBr0, SBr1, 1);
        SCAN(SA1, SA0, 16, SBr0);
        SCAN(SA0, SA1, 32, SBr1);
        for (int o = 0; o < C8 - 1; ++o) {
            short* Ain = (o & 1) ? SA0 : SA1;
            short* Sot = (o & 1) ? SA1 : SA0;
            step_p128<<<dim3(16, 16), 512, 0, stream>>>(Ain, RS, RC, PS2, SBM,
                nulf, 0, 0, 0,
                rec + (size_t)(C8 + o) * HH, LH, CH8,
                (o == C8 - 2) ? nuls : Sot, RS, RC, PS2, 2016);
        }
        step_p<<<dim3(16, 1), 128, 0, stream>>>(SA1 + 63 * RC, RS, 0, PS2, SBM,
            outp, PB, 0, 0, nulf, 0, 0, SA0, RS, 0, PS2);
        step_p<<<dim3(16, 1), 128, 0, stream>>>(SA0, RS, 0, PS2, SBM,
            outp + HH, PB, 0, 0, nulf, 0, 0, SA0 + RC, RS, 0, PS2);
        tr_splits<<<dim3(32, 32, 3), dim3(32, 8), 0, stream>>>(SBM, SAP);
        SQ64(SAP, SBM, nuls);
        split_t<<<dim3(32, 32), dim3(32, 8), 0, stream>>>(TP, SBr0);
        step_p<<<dim3(16, 2), 128, 0, stream>>>(SA0, RS, RC, PS2, SBr0,
            outp + 2 * HH, PB, RS, 0, nulf, 0, 0,
            SA0 + 2 * RC, RS, RC, PS2);
        split_a<<<dim3(1, HH), 256, 0, stream>>>(TP, RS, RC, SAP, RS, RC, HM);
        SQ64(SAP, SBr0, nuls);
        split_t<<<dim3(32, 32), dim3(32, 8), 0, stream>>>(TP, SBr1);
        step_p<<<dim3(16, 4), 128, 0, stream>>>(SA0, RS, RC, PS2, SBr1,
            outp + 4 * HH, PB, RS, 0, nulf, 0, 0,
            SA0 + 4 * RC, RS, RC, PS2);
        step_p<<<dim3(16, 8), 128, 0, stream>>>(SA0, RS, RC, PS2, SB8,
            outp + 8 * HH, PB, RS, 0, nulf, 0, 0,
            SA0 + 8 * RC, RS, RC, PS2);
        step_p64<<<dim3(16, 8), 256, 0, stream>>>(SA0, RS, RC, PS2, SB16,
            outp + 16 * HH, PB, RS, 0, nulf, 0, 0,
            nuls, 0, 0, PS2, 512);
        #undef SQ64
        #undef SCAN
        #undef SQI

        ln_k<<<BB * PRED, 256, 0, stream>>>(outp, ln_w, ln_b);
    }
}